// Round 9
// baseline (708.472 us; speedup 1.0000x reference)
//
#include <hip/hip_runtime.h>

typedef __attribute__((ext_vector_type(8))) _Float16 f16x8;
typedef __attribute__((ext_vector_type(4))) float f32x4;

#define NN   50000
#define EE   300000
#define TWOE 600000
#define TWOQ 200000
#define SCB  98     // scan blocks of 1024 ints covering 2*NN=100000

// ---- workspace layout (bytes), total 184,064,704 (<= proven 184,089,664) ----
static constexpr size_t O_XH   = 0;            // xh f16 [50048,256]; AGGh f16 [50048,288] aliases
static constexpr size_t O_XHAT = 28827648;     // f16 [50048,288]
static constexpr size_t O_YH   = 57655296;     // f16 [100096,288] per-direction Yhat
static constexpr size_t O_OPRE = 115310592;    // f16 [50048,256]
static constexpr size_t O_FR   = 166559744;    // f16 [384,256]
static constexpr size_t O_FI2  = O_FR   + 196608;   // f16 [384,256]
static constexpr size_t O_T1   = O_FI2  + 196608;   // f16 [384,256]
static constexpr size_t O_G    = O_T1   + 196608;   // f16 [384,288]
static constexpr size_t O_WB   = O_G    + 221184;   // f16 [256,832]
static constexpr size_t O_WQN  = O_WB   + 425984;   // f16 [256,256]
static constexpr size_t O_WINT = O_WQN  + 131072;   // f16 [256,256]
static constexpr size_t O_WOUT = O_WINT + 131072;   // f16 [256,256]
static constexpr size_t O_RAL16= O_WOUT + 131072;   // f16 [512,256]
static constexpr size_t O_RAL32= O_RAL16+ 262144;   // f32 [501,256]
static constexpr size_t O_RHAT = O_RAL32+ 513024;   // f16 [512,288]
static constexpr size_t O_DEG  = O_RHAT + 294912;   // int [2,N]
static constexpr size_t O_DINV = O_DEG  + 400000;   // f32 [2,N]
static constexpr size_t O_BNS  = O_DINV + 400000;   // f32 [1024]
static constexpr size_t O_CNT  = O_BNS  + 4096;     // int [2N]
static constexpr size_t O_PTR  = O_CNT  + 400000;   // int [2N+1]
static constexpr size_t O_CUR  = O_PTR  + 400064;   // int [2N]
static constexpr size_t O_BSUM = O_CUR  + 400000;   // int [128]
static constexpr size_t O_RECS = O_BSUM + 512;      // int4 [800000] = 12.8MB
static constexpr size_t WS_NEED= O_RECS + 12800000;

__device__ __forceinline__ float sanit(float v){
  v = (v == v) ? v : 0.f;
  return fminf(60000.f, fmaxf(-60000.f, v));
}
__device__ __forceinline__ _Float16 sat16(float v){ return (_Float16)sanit(v); }
__device__ __forceinline__ int iclamp(int v, int lo, int hi){
  return v < lo ? lo : (v > hi ? hi : v);
}
__device__ __forceinline__ void atomAddF(float* p, float v){
  __hip_atomic_fetch_add(p, v, __ATOMIC_RELAXED, __HIP_MEMORY_SCOPE_AGENT);
}
union HU { unsigned int u; _Float16 h[2]; };

__device__ __forceinline__ unsigned int cmulh(unsigned int ua, unsigned int ub){
  HU a, b, o; a.u = ua; b.u = ub;
  float ax=(float)a.h[0], ay=(float)a.h[1], bx=(float)b.h[0], by=(float)b.h[1];
  o.h[0] = (_Float16)(ax*bx + ay*by);
  o.h[1] = (_Float16)(ax*by - ay*bx);
  return o.u;
}

// ---- fused prologue: block-range dispatch over 6 independent jobs ----
__global__ void k_pro(_Float16* __restrict__ FR, _Float16* __restrict__ FI2,
                      const float* __restrict__ w_in, const float* __restrict__ w_out,
                      const float* __restrict__ w_q, const float* __restrict__ rel_embed,
                      const float* __restrict__ loop_rel, const float* __restrict__ w_loop,
                      _Float16* __restrict__ wqn, _Float16* __restrict__ wint,
                      _Float16* __restrict__ woutt,
                      float* __restrict__ ral32, _Float16* __restrict__ ral16,
                      _Float16* __restrict__ WB,
                      const float* __restrict__ x, _Float16* __restrict__ xh,
                      const int* __restrict__ ei, const int* __restrict__ quals,
                      int* __restrict__ deg, int* __restrict__ cnt){
  int b = blockIdx.x, tid = threadIdx.x;
  if (b < 288){
    int t = b*256 + tid;
    const float step = 0.024543692606170259f; // 2*pi/256
    {
      int f = t >> 8, tt = t & 255;
      float v = 0.f;
      if (f < 258){
        int m = f >> 1;
        float ang = (float)((tt*m) & 255) * step;
        v = (f & 1) ? -sinf(ang) : cosf(ang);
      }
      FR[t] = (_Float16)v;
    }
    {
      int k = t >> 8, j = t & 255;
      float v = 0.f;
      if (k < 258){
        int m = k >> 1;
        float w = (m==0 || m==128) ? (1.f/256.f) : (2.f/256.f);
        float ang = (float)((j*m) & 255) * step;
        v = (k & 1) ? -w*sinf(ang) : w*cosf(ang);
      }
      FI2[t] = (_Float16)v;
    }
  } else if (b < 789){
    int t = (b - 288)*256 + tid;
    if (t < 65536){
      int j = t >> 8, n = t & 255;
      wqn[t] = sat16(w_q[t]);
      wint[n*256 + j]  = sat16(w_in[t]);
      woutt[n*256 + j] = sat16(w_out[t]);
    }
    if (t < 128256){
      float rv = (t < 128000) ? rel_embed[t] : loop_rel[t - 128000];
      rv = sanit(rv);
      ral32[t] = rv; ral16[t] = (_Float16)rv;
    }
  } else if (b < 1045){
    int t = (b - 789)*256 + tid;   // < 65536
    int j = t >> 8, n = t & 255;
    float acc = 0.f;
    for (int m = 0; m < 256; ++m)
      acc += loop_rel[(j+m) & 255] * w_loop[m*256 + n];
    WB[n*832 + 576 + j] = sat16(acc);
  } else if (b < 7295){
    int t = (b - 1045)*256 + tid;  // < 1,600,000 exactly
    const float4* p = (const float4*)x + (size_t)t*2;
    float4 v0 = p[0], v1 = p[1];
    f16x8 o;
    o[0]=sat16(v0.x); o[1]=sat16(v0.y); o[2]=sat16(v0.z); o[3]=sat16(v0.w);
    o[4]=sat16(v1.x); o[5]=sat16(v1.y); o[6]=sat16(v1.z); o[7]=sat16(v1.w);
    ((f16x8*)xh)[t] = o;
  } else if (b < 9639){
    int t = (b - 7295)*256 + tid;
    if (t < TWOE){
      int d = (t >= EE) ? 1 : 0;
      atomicAdd(&deg[d*NN + iclamp(ei[t], 0, NN-1)], 1);
    }
  } else {
    int t = (b - 9639)*256 + tid;  // < 800,000 exactly
    if (t < TWOE){
      int d = (t >= EE) ? 1 : 0;
      atomicAdd(&cnt[d*NN + iclamp(ei[TWOE + t], 0, NN-1)], 1);
    } else {
      int qg = t - TWOE;
      int d = (qg >= 100000) ? 1 : 0;
      int e = iclamp(quals[2*TWOQ + qg], 0, EE-1);
      int j = d*EE + e;
      atomicAdd(&cnt[d*NN + iclamp(ei[TWOE + j], 0, NN-1)], 1);
    }
  }
}

// fused: blocks [0,391) dinv ; [391,489) scan1
__global__ void k_dinv_scan1(const int* __restrict__ deg, float* __restrict__ dinv,
                             const int* __restrict__ cnt, int* __restrict__ bsum){
  int b = blockIdx.x, t = threadIdx.x;
  if (b < 391){
    int i = b*256 + t;
    if (i < 2*NN){
      int c = deg[i];
      dinv[i] = (c > 0) ? rsqrtf((float)c) : 0.f;
    }
  } else {
    __shared__ int sh[256];
    int blk = b - 391;
    int base = blk*1024 + t*4;
    int s = 0;
    #pragma unroll
    for (int i = 0; i < 4; ++i){ int idx = base + i; if (idx < 2*NN) s += cnt[idx]; }
    sh[t] = s; __syncthreads();
    for (int off = 128; off > 0; off >>= 1){
      if (t < off) sh[t] += sh[t + off];
      __syncthreads();
    }
    if (t == 0) bsum[blk] = sh[0];
  }
}

__global__ void k_scan2(int* __restrict__ bsum, int* __restrict__ ptr){
  if (threadIdx.x == 0){
    int run = 0;
    for (int i = 0; i < SCB; ++i){ int v = bsum[i]; bsum[i] = run; run += v; }
    ptr[2*NN] = run;
  }
}

__global__ void k_scan3(const int* __restrict__ cnt, const int* __restrict__ bsum,
                        int* __restrict__ ptr, int* __restrict__ cur){
  __shared__ int sh[256];
  int b = blockIdx.x, t = threadIdx.x;
  int base = b*1024 + t*4;
  int v[4];
  int s = 0;
  #pragma unroll
  for (int i = 0; i < 4; ++i){
    int idx = base + i;
    v[i] = (idx < 2*NN) ? cnt[idx] : 0;
    s += v[i];
  }
  sh[t] = s; __syncthreads();
  for (int off = 1; off < 256; off <<= 1){
    int add = (t >= off) ? sh[t - off] : 0;
    __syncthreads();
    sh[t] += add;
    __syncthreads();
  }
  int off0 = bsum[b] + sh[t] - s;
  #pragma unroll
  for (int i = 0; i < 4; ++i){
    int idx = base + i;
    if (idx < 2*NN){ ptr[idx] = off0; cur[idx] = off0; }
    off0 += v[i];
  }
}

// per-item records: {xhat_byte_off, b_byte_off, coef_bits, 0}
__global__ void k_fillrec(const int* __restrict__ ei, const int* __restrict__ et,
                          const int* __restrict__ quals, const float* __restrict__ dinv,
                          int* __restrict__ cursor, int4* __restrict__ recs){
  int t = blockIdx.x*256 + threadIdx.x;
  if (t >= TWOE + TWOQ) return;
  int d, j, boff; float w;
  if (t < TWOE){
    d = (t >= EE) ? 1 : 0;
    j = t;
    boff = (int)O_RHAT + iclamp(et[j], 0, 500)*576;
    w = 0.8f;
  } else {
    int qg = t - TWOE;
    d = (qg >= 100000) ? 1 : 0;
    int e = iclamp(quals[2*TWOQ + qg], 0, EE-1);
    j = d*EE + e;
    boff = (int)O_YH + (qg - d*100000)*576;
    w = 0.2f;
  }
  int src = iclamp(ei[j], 0, NN-1);
  int dst = iclamp(ei[TWOE + j], 0, NN-1);
  float coef = w * dinv[d*NN + src] * dinv[d*NN + dst];
  int pos = atomicAdd(&cursor[d*NN + dst], 1);
  pos = iclamp(pos, 0, 800000-1);
  int4 rc;
  rc.x = (int)O_XHAT + src*576;
  rc.y = boff;
  rc.z = __float_as_int(coef);
  rc.w = 0;
  recs[pos] = rc;
}

// C[M,N](ldc) = A[.,K](lda) @ Bt[.,K](ldb)^T; fp32 accum; UNGUARDED loads
template<typename OT, bool ACC>
__global__ __launch_bounds__(256) void k_gemm(const _Float16* __restrict__ A, int lda,
                                              const _Float16* __restrict__ Bt, int ldb,
                                              OT* __restrict__ C, int ldc,
                                              int N, int K){
  __shared__ __align__(16) _Float16 Ash[128*40];
  __shared__ __align__(16) _Float16 Bsh[128*40];
  const int tid = threadIdx.x;
  const int lane = tid & 63;
  const int wv = tid >> 6;
  const int bm = blockIdx.x*128, bn = blockIdx.y*128;
  const int wm = (wv >> 1)*64, wn = (wv & 1)*64;
  const int sr = tid >> 1;
  const int sc = (tid & 1)*16;
  const int fr = lane & 15;
  const int fk = (lane >> 4)*8;
  const _Float16* pa = A + (size_t)(bm+sr)*lda + sc;
  const _Float16* pb = Bt + (size_t)(bn+sr)*ldb + sc;
  f32x4 acc[4][4] = {};
  for (int kt = 0; kt < K; kt += 32){
    float4 a0 = *(const float4*)(pa);
    float4 a1 = *(const float4*)(pa + 8);
    float4 b0 = *(const float4*)(pb);
    float4 b1 = *(const float4*)(pb + 8);
    pa += 32; pb += 32;
    __syncthreads();
    *(float4*)&Ash[sr*40 + sc]     = a0;
    *(float4*)&Ash[sr*40 + sc + 8] = a1;
    *(float4*)&Bsh[sr*40 + sc]     = b0;
    *(float4*)&Bsh[sr*40 + sc + 8] = b1;
    __syncthreads();
    f16x8 af[4], bf_[4];
    #pragma unroll
    for (int i = 0; i < 4; ++i) af[i]  = *(const f16x8*)&Ash[(wm + i*16 + fr)*40 + fk];
    #pragma unroll
    for (int j = 0; j < 4; ++j) bf_[j] = *(const f16x8*)&Bsh[(wn + j*16 + fr)*40 + fk];
    #pragma unroll
    for (int i = 0; i < 4; ++i)
      #pragma unroll
      for (int j = 0; j < 4; ++j)
        acc[i][j] = __builtin_amdgcn_mfma_f32_16x16x32_f16(af[i], bf_[j], acc[i][j], 0, 0, 0);
  }
  const int cr = (lane >> 4)*4;
  const int cc = lane & 15;
  #pragma unroll
  for (int i = 0; i < 4; ++i)
    #pragma unroll
    for (int j = 0; j < 4; ++j){
      int col = bn + wn + j*16 + cc;
      if (col < N){
        #pragma unroll
        for (int r = 0; r < 4; ++r){
          size_t idx = (size_t)(bm + wm + i*16 + cr + r)*ldc + col;
          float v = acc[i][j][r];
          if (ACC) v += (float)C[idx];
          C[idx] = (OT)sanit(v);
        }
      }
    }
}

// Fused qual GEMM v2: 64-row blocks, A gathered ONCE into LDS, all 288 cols in acc.
// Yhat[q] = (conj(Xhat[ent_q]) .* Rhat[rel_q]) @ G^T
__global__ __launch_bounds__(256) void k_qgemm(const _Float16* __restrict__ Xhat,
                                               const _Float16* __restrict__ Rhat,
                                               const int* __restrict__ quals, int d,
                                               const _Float16* __restrict__ G,
                                               _Float16* __restrict__ Yhat){
  __shared__ __align__(16) _Float16 Ash[64*296];
  __shared__ __align__(16) _Float16 Bsh[288*40];
  const int tid = threadIdx.x;
  const int lane = tid & 63;
  const int wv = tid >> 6;
  const int bm = blockIdx.x*64;
  const int wm = (wv >> 1)*32;       // wave row base (2 row-groups of 32)
  const int wnh = (wv & 1)*144;      // wave col base (2 col-halves of 144)
  const int fr = lane & 15;
  const int fk = (lane >> 4)*8;
  // gather + cmul A-panel once: 64 rows x 288
  {
    int r = tid >> 2, seg = tid & 3;   // 4 threads/row, 144B segments
    int gq = bm + r; if (gq > 99999) gq = 99999;
    int qi = d*100000 + gq;
    int rel = iclamp(quals[qi], 0, 500);
    int ent = iclamp(quals[TWOQ + qi], 0, NN-1);
    const uint4* xs = (const uint4*)(Xhat + (size_t)ent*288) + seg*9;
    const uint4* rs = (const uint4*)(Rhat + (size_t)rel*288) + seg*9;
    uint4* dst = (uint4*)(Ash + r*296 + seg*72);
    #pragma unroll
    for (int u = 0; u < 9; ++u){
      uint4 xa = xs[u], ra = rs[u], o;
      o.x = cmulh(xa.x, ra.x); o.y = cmulh(xa.y, ra.y);
      o.z = cmulh(xa.z, ra.z); o.w = cmulh(xa.w, ra.w);
      dst[u] = o;
    }
  }
  f32x4 acc[2][9] = {};
  for (int kt = 0; kt < 288; kt += 32){
    __syncthreads();   // A/B-prev reads done; first iter: A writes visible after this
    // stage B: G rows 0..288 x k-slice [kt,kt+32)
    for (int u = tid; u < 1152; u += 256){
      int row = u >> 2, part = u & 3;
      *(uint4*)(Bsh + row*40 + part*8) = *(const uint4*)(G + (size_t)row*288 + kt + part*8);
    }
    __syncthreads();
    f16x8 af0 = *(const f16x8*)&Ash[(wm + fr)*296 + kt + fk];
    f16x8 af1 = *(const f16x8*)&Ash[(wm + 16 + fr)*296 + kt + fk];
    #pragma unroll
    for (int j = 0; j < 9; ++j){
      f16x8 bf_ = *(const f16x8*)&Bsh[(wnh + j*16 + fr)*40 + fk];
      acc[0][j] = __builtin_amdgcn_mfma_f32_16x16x32_f16(af0, bf_, acc[0][j], 0, 0, 0);
      acc[1][j] = __builtin_amdgcn_mfma_f32_16x16x32_f16(af1, bf_, acc[1][j], 0, 0, 0);
    }
  }
  const int cr = (lane >> 4)*4;
  const int cc = lane & 15;
  #pragma unroll
  for (int i = 0; i < 2; ++i)
    #pragma unroll
    for (int j = 0; j < 9; ++j)
      #pragma unroll
      for (int r = 0; r < 4; ++r){
        int row = bm + wm + i*16 + cr + r;     // < 100,032 <= padded 100,096
        int col = wnh + j*16 + cc;
        Yhat[(size_t)row*288 + col] = sat16(acc[i][j][r]);
      }
}

// ---- gather-aggregate via records, depth-2 software pipeline ----
__global__ __launch_bounds__(128) void k_agg(const char* __restrict__ Wb,
                                             const int* __restrict__ ptr,
                                             const int4* __restrict__ recs,
                                             int d, _Float16* __restrict__ AGGh){
  int node = blockIdx.x;
  int t = threadIdx.x;
  int gnode = d*NN + node;
  int beg = ptr[gnode], end = ptr[gnode+1];
  unsigned int* orow = (unsigned int*)(AGGh + (size_t)node*288);
  if (end <= beg){
    orow[t] = 0;
    if (t < 16) orow[128 + t] = 0;
    return;
  }
  int last = end - 1;
  auto ld = [&](int idx, unsigned& va, unsigned& vb, float& ah, float& bh, float& cf){
    int ic = idx < last ? idx : last;
    int4 rc = recs[ic];
    const unsigned* xr = (const unsigned*)(Wb + rc.x);
    const unsigned* br = (const unsigned*)(Wb + rc.y);
    va = xr[t]; vb = br[t];
    ah = (float)((const _Float16*)xr)[256];
    bh = (float)((const _Float16*)br)[256];
    cf = (idx <= last) ? __int_as_float(rc.z) : 0.f;
  };
  float ax_ = 0.f, ay_ = 0.f, ex = 0.f;
  unsigned va0, vb0, va1, vb1; float ah0, bh0, ah1, bh1, cf0, cf1;
  ld(beg,     va0, vb0, ah0, bh0, cf0);
  ld(beg + 1, va1, vb1, ah1, bh1, cf1);
  for (int k = beg; k < end; k += 2){
    unsigned ta0, tb0, ta1, tb1; float th0, tg0, th1, tg1, tc0, tc1;
    ld(k + 2, ta0, tb0, th0, tg0, tc0);
    ld(k + 3, ta1, tb1, th1, tg1, tc1);
    {
      HU a, b; a.u = va0; b.u = vb0;
      float axv=(float)a.h[0], ayv=(float)a.h[1], bxv=(float)b.h[0], byv=(float)b.h[1];
      ax_ += cf0*(axv*bxv + ayv*byv);
      ay_ += cf0*(axv*byv - ayv*bxv);
      ex  += cf0*ah0*bh0;
    }
    {
      HU a, b; a.u = va1; b.u = vb1;
      float axv=(float)a.h[0], ayv=(float)a.h[1], bxv=(float)b.h[0], byv=(float)b.h[1];
      ax_ += cf1*(axv*bxv + ayv*byv);
      ay_ += cf1*(axv*byv - ayv*bxv);
      ex  += cf1*ah1*bh1;
    }
    va0=ta0; vb0=tb0; ah0=th0; bh0=tg0; cf0=tc0;
    va1=ta1; vb1=tb1; ah1=th1; bh1=tg1; cf1=tc1;
  }
  HU o; o.h[0] = sat16(ax_); o.h[1] = sat16(ay_);
  orow[t] = o.u;
  if (t < 16){
    HU o2; o2.h[0] = (t == 0) ? sat16(ex) : (_Float16)0.f; o2.h[1] = (_Float16)0.f;
    orow[128 + t] = o2.u;
  }
}

__global__ void k_bnstats(const _Float16* __restrict__ opre, float* __restrict__ bns){
  int col = threadIdx.x;
  int r0 = blockIdx.x*64, r1 = r0 + 64; if (r1 > NN) r1 = NN;
  float s1 = 0.f, s2 = 0.f;
  for (int r = r0; r < r1; ++r){
    float v = (float)opre[(size_t)r*256 + col];
    s1 += v; s2 += v*v;
  }
  atomAddF(&bns[col], s1);
  atomAddF(&bns[256 + col], s2);
}

__global__ void k_bnfinal(float* __restrict__ bns, const float* __restrict__ gamma,
                          const float* __restrict__ beta){
  int col = threadIdx.x;
  float mean = bns[col] * (1.f/NN);
  float var  = bns[256 + col] * (1.f/NN) - mean*mean;
  var = fmaxf(var, 0.f);
  // BN of (acc/3 + bias) == (acc-mean_acc)/sqrt(var_acc + 9*eps); bias cancels
  float g = gamma[col] * rsqrtf(var + 9e-5f);
  float b = beta[col] - mean*g;
  bns[512 + col] = sanit(g);
  bns[768 + col] = sanit(b);
}

// fused epilogue: blocks [0,6250) ent-BN-tanh ; [6250,6750) rel_out
__global__ void k_epi(const _Float16* __restrict__ opre, const float* __restrict__ bns,
                      const float* __restrict__ ral32, const float* __restrict__ w_rel,
                      float* __restrict__ out){
  int b = blockIdx.x;
  if (b < 6250){
    int t = b*256 + threadIdx.x;     // < NN*32 exactly
    f16x8 v = ((const f16x8*)opre)[t];
    int col = (t & 31)*8;
    float4 o0, o1;
    o0.x = sanit(tanhf((float)v[0]*bns[512+col+0] + bns[768+col+0]));
    o0.y = sanit(tanhf((float)v[1]*bns[512+col+1] + bns[768+col+1]));
    o0.z = sanit(tanhf((float)v[2]*bns[512+col+2] + bns[768+col+2]));
    o0.w = sanit(tanhf((float)v[3]*bns[512+col+3] + bns[768+col+3]));
    o1.x = sanit(tanhf((float)v[4]*bns[512+col+4] + bns[768+col+4]));
    o1.y = sanit(tanhf((float)v[5]*bns[512+col+5] + bns[768+col+5]));
    o1.z = sanit(tanhf((float)v[6]*bns[512+col+6] + bns[768+col+6]));
    o1.w = sanit(tanhf((float)v[7]*bns[512+col+7] + bns[768+col+7]));
    ((float4*)out)[(size_t)t*2]     = o0;
    ((float4*)out)[(size_t)t*2 + 1] = o1;
  } else {
    int r = b - 6250, n = threadIdx.x;
    float acc = 0.f;
    for (int k = 0; k < 256; ++k)
      acc += ral32[r*256 + k] * w_rel[k*256 + n];
    out[12800000 + r*256 + n] = sanit(acc);
  }
}

extern "C" void kernel_launch(void* const* d_in, const int* in_sizes, int n_in,
                              void* d_out, int out_size, void* d_ws, size_t ws_size,
                              hipStream_t stream){
  (void)in_sizes; (void)n_in;
  if (ws_size < WS_NEED){
    hipMemsetAsync(d_out, 0, (size_t)out_size*4, stream);
    return;
  }
  const float* x        = (const float*)d_in[0];
  const float* rel_emb  = (const float*)d_in[1];
  const float* w_in     = (const float*)d_in[2];
  const float* w_out_   = (const float*)d_in[3];
  const float* w_loop   = (const float*)d_in[4];
  const float* w_rel    = (const float*)d_in[5];
  const float* w_q      = (const float*)d_in[6];
  const float* loop_rel = (const float*)d_in[7];
  const float* gamma    = (const float*)d_in[9];
  const float* beta     = (const float*)d_in[10];
  const int* ei    = (const int*)d_in[11];
  const int* et    = (const int*)d_in[12];
  const int* quals = (const int*)d_in[13];
  float* out = (float*)d_out;
  char* W = (char*)d_ws;
  _Float16* xh    = (_Float16*)(W + O_XH);
  _Float16* AGGh  = (_Float16*)(W + O_XH);
  _Float16* Xhat  = (_Float16*)(W + O_XHAT);
  _Float16* Yhat  = (_Float16*)(W + O_YH);
  _Float16* opre  = (_Float16*)(W + O_OPRE);
  _Float16* FR    = (_Float16*)(W + O_FR);
  _Float16* FI2   = (_Float16*)(W + O_FI2);
  _Float16* T1    = (_Float16*)(W + O_T1);
  _Float16* G     = (_Float16*)(W + O_G);
  _Float16* WB    = (_Float16*)(W + O_WB);
  _Float16* wqn   = (_Float16*)(W + O_WQN);
  _Float16* wint  = (_Float16*)(W + O_WINT);
  _Float16* woutt = (_Float16*)(W + O_WOUT);
  _Float16* ral16 = (_Float16*)(W + O_RAL16);
  float*    ral32 = (float*)(W + O_RAL32);
  _Float16* Rhat  = (_Float16*)(W + O_RHAT);
  int*      deg   = (int*)(W + O_DEG);
  float*    dinv  = (float*)(W + O_DINV);
  float*    bns   = (float*)(W + O_BNS);
  int*      cnt   = (int*)(W + O_CNT);
  int*      ptr   = (int*)(W + O_PTR);
  int*      cur   = (int*)(W + O_CUR);
  int*      bsum  = (int*)(W + O_BSUM);
  int4*     recs  = (int4*)(W + O_RECS);

  hipMemsetAsync(deg, 0, 400000, stream);
  hipMemsetAsync(cnt, 0, 400000, stream);
  hipMemsetAsync(bns, 0, 4096, stream);

  k_pro<<<12764, 256, 0, stream>>>(FR, FI2, w_in, w_out_, w_q, rel_emb, loop_rel, w_loop,
                                   wqn, wint, woutt, ral32, ral16, WB, x, xh,
                                   ei, quals, deg, cnt);
  k_dinv_scan1<<<391 + SCB, 256, 0, stream>>>(deg, dinv, cnt, bsum);
  k_scan2<<<1, 64, 0, stream>>>(bsum, ptr);
  k_scan3<<<SCB, 256, 0, stream>>>(cnt, bsum, ptr, cur);
  k_fillrec<<<3125, 256, 0, stream>>>(ei, et, quals, dinv, cur, recs);

  // T1 = FR @ wqn^T ; G = T1 @ FI2^T   (G = Fr.Wq^T.Fi^T)
  k_gemm<_Float16,false><<<dim3(3,2), 256, 0, stream>>>(FR, 256, wqn, 256, T1, 256, 256, 256);
  k_gemm<_Float16,false><<<dim3(3,3), 256, 0, stream>>>(T1, 256, FI2, 256, G, 288, 288, 256);
  // WB[:,0:288] = (Fi.W_in)^T-pack ; WB[:,288:576] for w_out
  k_gemm<_Float16,false><<<dim3(2,3), 256, 0, stream>>>(wint, 256, FI2, 256, WB, 832, 288, 256);
  k_gemm<_Float16,false><<<dim3(2,3), 256, 0, stream>>>(woutt, 256, FI2, 256, WB + 288, 832, 288, 256);

  // Xhat = x @ FR^T ; Rhat = rel_all @ FR^T
  k_gemm<_Float16,false><<<dim3(391,3), 256, 0, stream>>>(xh, 256, FR, 256, Xhat, 288, 288, 256);
  k_gemm<_Float16,false><<<dim3(4,3),  256, 0, stream>>>(ral16, 256, FR, 256, Rhat, 288, 288, 256);

  // opre = x @ BW (self-loop); f16 output
  k_gemm<_Float16,false><<<dim3(391,2), 256, 0, stream>>>(xh, 256, WB + 576, 832, opre, 256, 256, 256);

  for (int d = 0; d < 2; ++d){
    k_qgemm<<<1563, 256, 0, stream>>>(Xhat, Rhat, quals, d, G, Yhat);
    k_agg<<<NN, 128, 0, stream>>>(W, ptr, recs, d, AGGh);
    k_gemm<_Float16,true><<<dim3(391,2), 256, 0, stream>>>(AGGh, 288, WB + (size_t)d*288, 832,
                                                           opre, 256, 256, 288);
  }

  k_bnstats<<<782, 256, 0, stream>>>(opre, bns);
  k_bnfinal<<<1, 256, 0, stream>>>(bns, gamma, beta);
  k_epi<<<6750, 256, 0, stream>>>(opre, bns, ral32, w_rel, out);
}

// Round 10
// 656.545 us; speedup vs baseline: 1.0791x; 1.0791x over previous
//
#include <hip/hip_runtime.h>

typedef __attribute__((ext_vector_type(8))) _Float16 f16x8;
typedef __attribute__((ext_vector_type(4))) float f32x4;

#define NN   50000
#define EE   300000
#define TWOE 600000
#define TWOQ 200000
#define SCB  98     // scan blocks of 1024 ints covering 2*NN=100000

// ---- workspace layout (bytes), total 184,064,704 (<= proven 184,089,664) ----
static constexpr size_t O_XH   = 0;            // xh f16 [50048,256]; AGGh f16 [50048,288] aliases
static constexpr size_t O_XHAT = 28827648;     // f16 [50048,288]
static constexpr size_t O_YH   = 57655296;     // f16 [100096,288] per-direction Yhat
static constexpr size_t O_OPRE = 115310592;    // f16 [50048,256]
static constexpr size_t O_FR   = 166559744;    // f16 [384,256]
static constexpr size_t O_FI2  = O_FR   + 196608;   // f16 [384,256]
static constexpr size_t O_T1   = O_FI2  + 196608;   // f16 [384,256]
static constexpr size_t O_G    = O_T1   + 196608;   // f16 [384,288]
static constexpr size_t O_WB   = O_G    + 221184;   // f16 [256,832]
static constexpr size_t O_WQN  = O_WB   + 425984;   // f16 [256,256]
static constexpr size_t O_WINT = O_WQN  + 131072;   // f16 [256,256]
static constexpr size_t O_WOUT = O_WINT + 131072;   // f16 [256,256]
static constexpr size_t O_RAL16= O_WOUT + 131072;   // f16 [512,256]
static constexpr size_t O_RAL32= O_RAL16+ 262144;   // f32 [501,256]
static constexpr size_t O_RHAT = O_RAL32+ 513024;   // f16 [512,288]
static constexpr size_t O_DEG  = O_RHAT + 294912;   // int [2,N]
static constexpr size_t O_DINV = O_DEG  + 400000;   // f32 [2,N]
static constexpr size_t O_BNS  = O_DINV + 400000;   // f32 [1024]
static constexpr size_t O_CNT  = O_BNS  + 4096;     // int [2N]
static constexpr size_t O_PTR  = O_CNT  + 400000;   // int [2N+1]
static constexpr size_t O_CUR  = O_PTR  + 400064;   // int [2N]
static constexpr size_t O_BSUM = O_CUR  + 400000;   // int [128]
static constexpr size_t O_RECS = O_BSUM + 512;      // int4 [800000] = 12.8MB
static constexpr size_t WS_NEED= O_RECS + 12800000;

__device__ __forceinline__ float sanit(float v){
  v = (v == v) ? v : 0.f;
  return fminf(60000.f, fmaxf(-60000.f, v));
}
__device__ __forceinline__ _Float16 sat16(float v){ return (_Float16)sanit(v); }
__device__ __forceinline__ int iclamp(int v, int lo, int hi){
  return v < lo ? lo : (v > hi ? hi : v);
}
__device__ __forceinline__ void atomAddF(float* p, float v){
  __hip_atomic_fetch_add(p, v, __ATOMIC_RELAXED, __HIP_MEMORY_SCOPE_AGENT);
}
union HU { unsigned int u; _Float16 h[2]; };

// native-f16 complex multiply (conj(a)*b), packed-math friendly
__device__ __forceinline__ unsigned int cmulh(unsigned int ua, unsigned int ub){
  HU a, b, o; a.u = ua; b.u = ub;
  o.h[0] = a.h[0]*b.h[0] + a.h[1]*b.h[1];
  o.h[1] = a.h[0]*b.h[1] - a.h[1]*b.h[0];
  return o.u;
}

// ---- fused prologue: block-range dispatch over 6 independent jobs ----
__global__ void k_pro(_Float16* __restrict__ FR, _Float16* __restrict__ FI2,
                      const float* __restrict__ w_in, const float* __restrict__ w_out,
                      const float* __restrict__ w_q, const float* __restrict__ rel_embed,
                      const float* __restrict__ loop_rel, const float* __restrict__ w_loop,
                      _Float16* __restrict__ wqn, _Float16* __restrict__ wint,
                      _Float16* __restrict__ woutt,
                      float* __restrict__ ral32, _Float16* __restrict__ ral16,
                      _Float16* __restrict__ WB,
                      const float* __restrict__ x, _Float16* __restrict__ xh,
                      const int* __restrict__ ei, const int* __restrict__ quals,
                      int* __restrict__ deg, int* __restrict__ cnt){
  int b = blockIdx.x, tid = threadIdx.x;
  if (b < 288){
    int t = b*256 + tid;
    const float step = 0.024543692606170259f; // 2*pi/256
    {
      int f = t >> 8, tt = t & 255;
      float v = 0.f;
      if (f < 258){
        int m = f >> 1;
        float ang = (float)((tt*m) & 255) * step;
        v = (f & 1) ? -sinf(ang) : cosf(ang);
      }
      FR[t] = (_Float16)v;
    }
    {
      int k = t >> 8, j = t & 255;
      float v = 0.f;
      if (k < 258){
        int m = k >> 1;
        float w = (m==0 || m==128) ? (1.f/256.f) : (2.f/256.f);
        float ang = (float)((j*m) & 255) * step;
        v = (k & 1) ? -w*sinf(ang) : w*cosf(ang);
      }
      FI2[t] = (_Float16)v;
    }
  } else if (b < 789){
    int t = (b - 288)*256 + tid;
    if (t < 65536){
      int j = t >> 8, n = t & 255;
      wqn[t] = sat16(w_q[t]);
      wint[n*256 + j]  = sat16(w_in[t]);
      woutt[n*256 + j] = sat16(w_out[t]);
    }
    if (t < 128256){
      float rv = (t < 128000) ? rel_embed[t] : loop_rel[t - 128000];
      rv = sanit(rv);
      ral32[t] = rv; ral16[t] = (_Float16)rv;
    }
  } else if (b < 1045){
    int t = (b - 789)*256 + tid;   // < 65536
    int j = t >> 8, n = t & 255;
    float acc = 0.f;
    for (int m = 0; m < 256; ++m)
      acc += loop_rel[(j+m) & 255] * w_loop[m*256 + n];
    WB[n*832 + 576 + j] = sat16(acc);
  } else if (b < 7295){
    int t = (b - 1045)*256 + tid;  // < 1,600,000 exactly
    const float4* p = (const float4*)x + (size_t)t*2;
    float4 v0 = p[0], v1 = p[1];
    f16x8 o;
    o[0]=sat16(v0.x); o[1]=sat16(v0.y); o[2]=sat16(v0.z); o[3]=sat16(v0.w);
    o[4]=sat16(v1.x); o[5]=sat16(v1.y); o[6]=sat16(v1.z); o[7]=sat16(v1.w);
    ((f16x8*)xh)[t] = o;
  } else if (b < 9639){
    int t = (b - 7295)*256 + tid;
    if (t < TWOE){
      int d = (t >= EE) ? 1 : 0;
      atomicAdd(&deg[d*NN + iclamp(ei[t], 0, NN-1)], 1);
    }
  } else {
    int t = (b - 9639)*256 + tid;  // < 800,000 exactly
    if (t < TWOE){
      int d = (t >= EE) ? 1 : 0;
      atomicAdd(&cnt[d*NN + iclamp(ei[TWOE + t], 0, NN-1)], 1);
    } else {
      int qg = t - TWOE;
      int d = (qg >= 100000) ? 1 : 0;
      int e = iclamp(quals[2*TWOQ + qg], 0, EE-1);
      int j = d*EE + e;
      atomicAdd(&cnt[d*NN + iclamp(ei[TWOE + j], 0, NN-1)], 1);
    }
  }
}

// fused: blocks [0,391) dinv ; [391,489) scan1
__global__ void k_dinv_scan1(const int* __restrict__ deg, float* __restrict__ dinv,
                             const int* __restrict__ cnt, int* __restrict__ bsum){
  int b = blockIdx.x, t = threadIdx.x;
  if (b < 391){
    int i = b*256 + t;
    if (i < 2*NN){
      int c = deg[i];
      dinv[i] = (c > 0) ? rsqrtf((float)c) : 0.f;
    }
  } else {
    __shared__ int sh[256];
    int blk = b - 391;
    int base = blk*1024 + t*4;
    int s = 0;
    #pragma unroll
    for (int i = 0; i < 4; ++i){ int idx = base + i; if (idx < 2*NN) s += cnt[idx]; }
    sh[t] = s; __syncthreads();
    for (int off = 128; off > 0; off >>= 1){
      if (t < off) sh[t] += sh[t + off];
      __syncthreads();
    }
    if (t == 0) bsum[blk] = sh[0];
  }
}

__global__ void k_scan2(int* __restrict__ bsum, int* __restrict__ ptr){
  if (threadIdx.x == 0){
    int run = 0;
    for (int i = 0; i < SCB; ++i){ int v = bsum[i]; bsum[i] = run; run += v; }
    ptr[2*NN] = run;
  }
}

__global__ void k_scan3(const int* __restrict__ cnt, const int* __restrict__ bsum,
                        int* __restrict__ ptr, int* __restrict__ cur){
  __shared__ int sh[256];
  int b = blockIdx.x, t = threadIdx.x;
  int base = b*1024 + t*4;
  int v[4];
  int s = 0;
  #pragma unroll
  for (int i = 0; i < 4; ++i){
    int idx = base + i;
    v[i] = (idx < 2*NN) ? cnt[idx] : 0;
    s += v[i];
  }
  sh[t] = s; __syncthreads();
  for (int off = 1; off < 256; off <<= 1){
    int add = (t >= off) ? sh[t - off] : 0;
    __syncthreads();
    sh[t] += add;
    __syncthreads();
  }
  int off0 = bsum[b] + sh[t] - s;
  #pragma unroll
  for (int i = 0; i < 4; ++i){
    int idx = base + i;
    if (idx < 2*NN){ ptr[idx] = off0; cur[idx] = off0; }
    off0 += v[i];
  }
}

// per-item records: {xhat_byte_off, b_byte_off, coef_bits, 0}
__global__ void k_fillrec(const int* __restrict__ ei, const int* __restrict__ et,
                          const int* __restrict__ quals, const float* __restrict__ dinv,
                          int* __restrict__ cursor, int4* __restrict__ recs){
  int t = blockIdx.x*256 + threadIdx.x;
  if (t >= TWOE + TWOQ) return;
  int d, j, boff; float w;
  if (t < TWOE){
    d = (t >= EE) ? 1 : 0;
    j = t;
    boff = (int)O_RHAT + iclamp(et[j], 0, 500)*576;
    w = 0.8f;
  } else {
    int qg = t - TWOE;
    d = (qg >= 100000) ? 1 : 0;
    int e = iclamp(quals[2*TWOQ + qg], 0, EE-1);
    j = d*EE + e;
    boff = (int)O_YH + (qg - d*100000)*576;
    w = 0.2f;
  }
  int src = iclamp(ei[j], 0, NN-1);
  int dst = iclamp(ei[TWOE + j], 0, NN-1);
  float coef = w * dinv[d*NN + src] * dinv[d*NN + dst];
  int pos = atomicAdd(&cursor[d*NN + dst], 1);
  pos = iclamp(pos, 0, 800000-1);
  int4 rc;
  rc.x = (int)O_XHAT + src*576;
  rc.y = boff;
  rc.z = __float_as_int(coef);
  rc.w = 0;
  recs[pos] = rc;
}

// C[M,N](ldc) = A[.,K](lda) @ Bt[.,K](ldb)^T; fp32 accum; UNGUARDED loads
template<typename OT, bool ACC>
__global__ __launch_bounds__(256) void k_gemm(const _Float16* __restrict__ A, int lda,
                                              const _Float16* __restrict__ Bt, int ldb,
                                              OT* __restrict__ C, int ldc,
                                              int N, int K){
  __shared__ __align__(16) _Float16 Ash[128*40];
  __shared__ __align__(16) _Float16 Bsh[128*40];
  const int tid = threadIdx.x;
  const int lane = tid & 63;
  const int wv = tid >> 6;
  const int bm = blockIdx.x*128, bn = blockIdx.y*128;
  const int wm = (wv >> 1)*64, wn = (wv & 1)*64;
  const int sr = tid >> 1;
  const int sc = (tid & 1)*16;
  const int fr = lane & 15;
  const int fk = (lane >> 4)*8;
  const _Float16* pa = A + (size_t)(bm+sr)*lda + sc;
  const _Float16* pb = Bt + (size_t)(bn+sr)*ldb + sc;
  f32x4 acc[4][4] = {};
  for (int kt = 0; kt < K; kt += 32){
    float4 a0 = *(const float4*)(pa);
    float4 a1 = *(const float4*)(pa + 8);
    float4 b0 = *(const float4*)(pb);
    float4 b1 = *(const float4*)(pb + 8);
    pa += 32; pb += 32;
    __syncthreads();
    *(float4*)&Ash[sr*40 + sc]     = a0;
    *(float4*)&Ash[sr*40 + sc + 8] = a1;
    *(float4*)&Bsh[sr*40 + sc]     = b0;
    *(float4*)&Bsh[sr*40 + sc + 8] = b1;
    __syncthreads();
    f16x8 af[4], bf_[4];
    #pragma unroll
    for (int i = 0; i < 4; ++i) af[i]  = *(const f16x8*)&Ash[(wm + i*16 + fr)*40 + fk];
    #pragma unroll
    for (int j = 0; j < 4; ++j) bf_[j] = *(const f16x8*)&Bsh[(wn + j*16 + fr)*40 + fk];
    #pragma unroll
    for (int i = 0; i < 4; ++i)
      #pragma unroll
      for (int j = 0; j < 4; ++j)
        acc[i][j] = __builtin_amdgcn_mfma_f32_16x16x32_f16(af[i], bf_[j], acc[i][j], 0, 0, 0);
  }
  const int cr = (lane >> 4)*4;
  const int cc = lane & 15;
  #pragma unroll
  for (int i = 0; i < 4; ++i)
    #pragma unroll
    for (int j = 0; j < 4; ++j){
      int col = bn + wn + j*16 + cc;
      if (col < N){
        #pragma unroll
        for (int r = 0; r < 4; ++r){
          size_t idx = (size_t)(bm + wm + i*16 + cr + r)*ldc + col;
          float v = acc[i][j][r];
          if (ACC) v += (float)C[idx];
          C[idx] = (OT)sanit(v);
        }
      }
    }
}

// Fused qual GEMM (r8 structure): Yhat[q] = (conj(Xhat[ent_q]) .* Rhat[rel_q]) @ G^T
// A-tile computed in-register during staging (no CM buffer); grid (782,3).
__global__ __launch_bounds__(256) void k_qgemm(const _Float16* __restrict__ Xhat,
                                               const _Float16* __restrict__ Rhat,
                                               const int* __restrict__ quals, int d,
                                               const _Float16* __restrict__ G,
                                               _Float16* __restrict__ Yhat){
  __shared__ __align__(16) _Float16 Ash[128*40];
  __shared__ __align__(16) _Float16 Bsh[128*40];
  const int tid = threadIdx.x;
  const int lane = tid & 63;
  const int wv = tid >> 6;
  const int bm = blockIdx.x*128, bn = blockIdx.y*128;
  const int wm = (wv >> 1)*64, wn = (wv & 1)*64;
  const int sr = tid >> 1;
  const int h  = tid & 1;
  const int fr = lane & 15;
  const int fk = (lane >> 4)*8;
  int q = bm + sr; if (q > 99999) q = 99999;
  int qi = d*100000 + q;
  int rel = iclamp(quals[qi], 0, 500);
  int ent = iclamp(quals[TWOQ + qi], 0, NN-1);
  const unsigned int* xr = (const unsigned int*)(Xhat + (size_t)ent*288);
  const unsigned int* rr = (const unsigned int*)(Rhat + (size_t)rel*288);
  const _Float16* pb = G + (size_t)(bn+sr)*288 + h*16;
  f32x4 acc[4][4] = {};
  for (int kt = 0; kt < 288; kt += 32){
    int kb = (kt >> 1) + h*8;
    uint4 xa0 = *(const uint4*)(xr + kb);
    uint4 xa1 = *(const uint4*)(xr + kb + 4);
    uint4 ra0 = *(const uint4*)(rr + kb);
    uint4 ra1 = *(const uint4*)(rr + kb + 4);
    float4 b0 = *(const float4*)(pb);
    float4 b1 = *(const float4*)(pb + 8);
    pb += 32;
    uint4 oa0, oa1;
    oa0.x = cmulh(xa0.x, ra0.x); oa0.y = cmulh(xa0.y, ra0.y);
    oa0.z = cmulh(xa0.z, ra0.z); oa0.w = cmulh(xa0.w, ra0.w);
    oa1.x = cmulh(xa1.x, ra1.x); oa1.y = cmulh(xa1.y, ra1.y);
    oa1.z = cmulh(xa1.z, ra1.z); oa1.w = cmulh(xa1.w, ra1.w);
    __syncthreads();
    *(uint4*)&Ash[sr*40 + h*16]     = oa0;
    *(uint4*)&Ash[sr*40 + h*16 + 8] = oa1;
    *(float4*)&Bsh[sr*40 + h*16]     = b0;
    *(float4*)&Bsh[sr*40 + h*16 + 8] = b1;
    __syncthreads();
    f16x8 af[4], bf_[4];
    #pragma unroll
    for (int i = 0; i < 4; ++i) af[i]  = *(const f16x8*)&Ash[(wm + i*16 + fr)*40 + fk];
    #pragma unroll
    for (int j = 0; j < 4; ++j) bf_[j] = *(const f16x8*)&Bsh[(wn + j*16 + fr)*40 + fk];
    #pragma unroll
    for (int i = 0; i < 4; ++i)
      #pragma unroll
      for (int j = 0; j < 4; ++j)
        acc[i][j] = __builtin_amdgcn_mfma_f32_16x16x32_f16(af[i], bf_[j], acc[i][j], 0, 0, 0);
  }
  const int cr = (lane >> 4)*4;
  const int cc = lane & 15;
  #pragma unroll
  for (int i = 0; i < 4; ++i)
    #pragma unroll
    for (int j = 0; j < 4; ++j){
      int col = bn + wn + j*16 + cc;
      if (col < 288){
        #pragma unroll
        for (int r = 0; r < 4; ++r){
          size_t idx = (size_t)(bm + wm + i*16 + cr + r)*288 + col;
          Yhat[idx] = sat16(acc[i][j][r]);
        }
      }
    }
}

// ---- gather-aggregate via records, depth-2 software pipeline ----
__global__ __launch_bounds__(128) void k_agg(const char* __restrict__ Wb,
                                             const int* __restrict__ ptr,
                                             const int4* __restrict__ recs,
                                             int d, _Float16* __restrict__ AGGh){
  int node = blockIdx.x;
  int t = threadIdx.x;
  int gnode = d*NN + node;
  int beg = ptr[gnode], end = ptr[gnode+1];
  unsigned int* orow = (unsigned int*)(AGGh + (size_t)node*288);
  if (end <= beg){
    orow[t] = 0;
    if (t < 16) orow[128 + t] = 0;
    return;
  }
  int last = end - 1;
  auto ld = [&](int idx, unsigned& va, unsigned& vb, float& ah, float& bh, float& cf){
    int ic = idx < last ? idx : last;
    int4 rc = recs[ic];
    const unsigned* xr = (const unsigned*)(Wb + rc.x);
    const unsigned* br = (const unsigned*)(Wb + rc.y);
    va = xr[t]; vb = br[t];
    ah = (float)((const _Float16*)xr)[256];
    bh = (float)((const _Float16*)br)[256];
    cf = (idx <= last) ? __int_as_float(rc.z) : 0.f;
  };
  float ax_ = 0.f, ay_ = 0.f, ex = 0.f;
  unsigned va0, vb0, va1, vb1; float ah0, bh0, ah1, bh1, cf0, cf1;
  ld(beg,     va0, vb0, ah0, bh0, cf0);
  ld(beg + 1, va1, vb1, ah1, bh1, cf1);
  for (int k = beg; k < end; k += 2){
    unsigned ta0, tb0, ta1, tb1; float th0, tg0, th1, tg1, tc0, tc1;
    ld(k + 2, ta0, tb0, th0, tg0, tc0);
    ld(k + 3, ta1, tb1, th1, tg1, tc1);
    {
      HU a, b; a.u = va0; b.u = vb0;
      float axv=(float)a.h[0], ayv=(float)a.h[1], bxv=(float)b.h[0], byv=(float)b.h[1];
      ax_ += cf0*(axv*bxv + ayv*byv);
      ay_ += cf0*(axv*byv - ayv*bxv);
      ex  += cf0*ah0*bh0;
    }
    {
      HU a, b; a.u = va1; b.u = vb1;
      float axv=(float)a.h[0], ayv=(float)a.h[1], bxv=(float)b.h[0], byv=(float)b.h[1];
      ax_ += cf1*(axv*bxv + ayv*byv);
      ay_ += cf1*(axv*byv - ayv*bxv);
      ex  += cf1*ah1*bh1;
    }
    va0=ta0; vb0=tb0; ah0=th0; bh0=tg0; cf0=tc0;
    va1=ta1; vb1=tb1; ah1=th1; bh1=tg1; cf1=tc1;
  }
  HU o; o.h[0] = sat16(ax_); o.h[1] = sat16(ay_);
  orow[t] = o.u;
  if (t < 16){
    HU o2; o2.h[0] = (t == 0) ? sat16(ex) : (_Float16)0.f; o2.h[1] = (_Float16)0.f;
    orow[128 + t] = o2.u;
  }
}

__global__ void k_bnstats(const _Float16* __restrict__ opre, float* __restrict__ bns){
  int col = threadIdx.x;
  int r0 = blockIdx.x*64, r1 = r0 + 64; if (r1 > NN) r1 = NN;
  float s1 = 0.f, s2 = 0.f;
  for (int r = r0; r < r1; ++r){
    float v = (float)opre[(size_t)r*256 + col];
    s1 += v; s2 += v*v;
  }
  atomAddF(&bns[col], s1);
  atomAddF(&bns[256 + col], s2);
}

__global__ void k_bnfinal(float* __restrict__ bns, const float* __restrict__ gamma,
                          const float* __restrict__ beta){
  int col = threadIdx.x;
  float mean = bns[col] * (1.f/NN);
  float var  = bns[256 + col] * (1.f/NN) - mean*mean;
  var = fmaxf(var, 0.f);
  // BN of (acc/3 + bias) == (acc-mean_acc)/sqrt(var_acc + 9*eps); bias cancels
  float g = gamma[col] * rsqrtf(var + 9e-5f);
  float b = beta[col] - mean*g;
  bns[512 + col] = sanit(g);
  bns[768 + col] = sanit(b);
}

// fused epilogue: blocks [0,6250) ent-BN-tanh ; [6250,6750) rel_out
__global__ void k_epi(const _Float16* __restrict__ opre, const float* __restrict__ bns,
                      const float* __restrict__ ral32, const float* __restrict__ w_rel,
                      float* __restrict__ out){
  int b = blockIdx.x;
  if (b < 6250){
    int t = b*256 + threadIdx.x;     // < NN*32 exactly
    f16x8 v = ((const f16x8*)opre)[t];
    int col = (t & 31)*8;
    float4 o0, o1;
    o0.x = sanit(tanhf((float)v[0]*bns[512+col+0] + bns[768+col+0]));
    o0.y = sanit(tanhf((float)v[1]*bns[512+col+1] + bns[768+col+1]));
    o0.z = sanit(tanhf((float)v[2]*bns[512+col+2] + bns[768+col+2]));
    o0.w = sanit(tanhf((float)v[3]*bns[512+col+3] + bns[768+col+3]));
    o1.x = sanit(tanhf((float)v[4]*bns[512+col+4] + bns[768+col+4]));
    o1.y = sanit(tanhf((float)v[5]*bns[512+col+5] + bns[768+col+5]));
    o1.z = sanit(tanhf((float)v[6]*bns[512+col+6] + bns[768+col+6]));
    o1.w = sanit(tanhf((float)v[7]*bns[512+col+7] + bns[768+col+7]));
    ((float4*)out)[(size_t)t*2]     = o0;
    ((float4*)out)[(size_t)t*2 + 1] = o1;
  } else {
    int r = b - 6250, n = threadIdx.x;
    float acc = 0.f;
    for (int k = 0; k < 256; ++k)
      acc += ral32[r*256 + k] * w_rel[k*256 + n];
    out[12800000 + r*256 + n] = sanit(acc);
  }
}

extern "C" void kernel_launch(void* const* d_in, const int* in_sizes, int n_in,
                              void* d_out, int out_size, void* d_ws, size_t ws_size,
                              hipStream_t stream){
  (void)in_sizes; (void)n_in;
  if (ws_size < WS_NEED){
    hipMemsetAsync(d_out, 0, (size_t)out_size*4, stream);
    return;
  }
  const float* x        = (const float*)d_in[0];
  const float* rel_emb  = (const float*)d_in[1];
  const float* w_in     = (const float*)d_in[2];
  const float* w_out_   = (const float*)d_in[3];
  const float* w_loop   = (const float*)d_in[4];
  const float* w_rel    = (const float*)d_in[5];
  const float* w_q      = (const float*)d_in[6];
  const float* loop_rel = (const float*)d_in[7];
  const float* gamma    = (const float*)d_in[9];
  const float* beta     = (const float*)d_in[10];
  const int* ei    = (const int*)d_in[11];
  const int* et    = (const int*)d_in[12];
  const int* quals = (const int*)d_in[13];
  float* out = (float*)d_out;
  char* W = (char*)d_ws;
  _Float16* xh    = (_Float16*)(W + O_XH);
  _Float16* AGGh  = (_Float16*)(W + O_XH);
  _Float16* Xhat  = (_Float16*)(W + O_XHAT);
  _Float16* Yhat  = (_Float16*)(W + O_YH);
  _Float16* opre  = (_Float16*)(W + O_OPRE);
  _Float16* FR    = (_Float16*)(W + O_FR);
  _Float16* FI2   = (_Float16*)(W + O_FI2);
  _Float16* T1    = (_Float16*)(W + O_T1);
  _Float16* G     = (_Float16*)(W + O_G);
  _Float16* WB    = (_Float16*)(W + O_WB);
  _Float16* wqn   = (_Float16*)(W + O_WQN);
  _Float16* wint  = (_Float16*)(W + O_WINT);
  _Float16* woutt = (_Float16*)(W + O_WOUT);
  _Float16* ral16 = (_Float16*)(W + O_RAL16);
  float*    ral32 = (float*)(W + O_RAL32);
  _Float16* Rhat  = (_Float16*)(W + O_RHAT);
  int*      deg   = (int*)(W + O_DEG);
  float*    dinv  = (float*)(W + O_DINV);
  float*    bns   = (float*)(W + O_BNS);
  int*      cnt   = (int*)(W + O_CNT);
  int*      ptr   = (int*)(W + O_PTR);
  int*      cur   = (int*)(W + O_CUR);
  int*      bsum  = (int*)(W + O_BSUM);
  int4*     recs  = (int4*)(W + O_RECS);

  hipMemsetAsync(deg, 0, 400000, stream);
  hipMemsetAsync(cnt, 0, 400000, stream);
  hipMemsetAsync(bns, 0, 4096, stream);

  k_pro<<<12764, 256, 0, stream>>>(FR, FI2, w_in, w_out_, w_q, rel_emb, loop_rel, w_loop,
                                   wqn, wint, woutt, ral32, ral16, WB, x, xh,
                                   ei, quals, deg, cnt);
  k_dinv_scan1<<<391 + SCB, 256, 0, stream>>>(deg, dinv, cnt, bsum);
  k_scan2<<<1, 64, 0, stream>>>(bsum, ptr);
  k_scan3<<<SCB, 256, 0, stream>>>(cnt, bsum, ptr, cur);
  k_fillrec<<<3125, 256, 0, stream>>>(ei, et, quals, dinv, cur, recs);

  // T1 = FR @ wqn^T ; G = T1 @ FI2^T   (G = Fr.Wq^T.Fi^T)
  k_gemm<_Float16,false><<<dim3(3,2), 256, 0, stream>>>(FR, 256, wqn, 256, T1, 256, 256, 256);
  k_gemm<_Float16,false><<<dim3(3,3), 256, 0, stream>>>(T1, 256, FI2, 256, G, 288, 288, 256);
  // WB[:,0:288] = (Fi.W_in)^T-pack ; WB[:,288:576] for w_out
  k_gemm<_Float16,false><<<dim3(2,3), 256, 0, stream>>>(wint, 256, FI2, 256, WB, 832, 288, 256);
  k_gemm<_Float16,false><<<dim3(2,3), 256, 0, stream>>>(woutt, 256, FI2, 256, WB + 288, 832, 288, 256);

  // Xhat = x @ FR^T ; Rhat = rel_all @ FR^T
  k_gemm<_Float16,false><<<dim3(391,3), 256, 0, stream>>>(xh, 256, FR, 256, Xhat, 288, 288, 256);
  k_gemm<_Float16,false><<<dim3(4,3),  256, 0, stream>>>(ral16, 256, FR, 256, Rhat, 288, 288, 256);

  // opre = x @ BW (self-loop); f16 output
  k_gemm<_Float16,false><<<dim3(391,2), 256, 0, stream>>>(xh, 256, WB + 576, 832, opre, 256, 256, 256);

  for (int d = 0; d < 2; ++d){
    k_qgemm<<<dim3(782,3), 256, 0, stream>>>(Xhat, Rhat, quals, d, G, Yhat);
    k_agg<<<NN, 128, 0, stream>>>(W, ptr, recs, d, AGGh);
    k_gemm<_Float16,true><<<dim3(391,2), 256, 0, stream>>>(AGGh, 288, WB + (size_t)d*288, 832,
                                                           opre, 256, 256, 288);
  }

  k_bnstats<<<782, 256, 0, stream>>>(opre, bns);
  k_bnfinal<<<1, 256, 0, stream>>>(bns, gamma, beta);
  k_epi<<<6750, 256, 0, stream>>>(opre, bns, ral32, w_rel, out);
}

// Round 11
// 649.665 us; speedup vs baseline: 1.0905x; 1.0106x over previous
//
#include <hip/hip_runtime.h>

typedef __attribute__((ext_vector_type(8))) _Float16 f16x8;
typedef __attribute__((ext_vector_type(4))) float f32x4;

#define NN   50000
#define EE   300000
#define TWOE 600000
#define TWOQ 200000
#define SCB  98     // scan blocks of 1024 ints covering 2*NN=100000

// ---- workspace layout (bytes), total 158,177,984 ----
static constexpr size_t O_XH   = 0;            // xh f16 [50048,256] + ral16 rows appended; AGGh f16 [50048,288] aliases
static constexpr size_t O_XHAT = 28827648;     // f16 [50560,288]: Xhat rows 0..50047, Rhat rows 50048..50559
static constexpr size_t O_YH   = 57950208;     // f16 [100096,288] per-direction Yhat
static constexpr size_t O_OPRE = 115605504;    // f16 [50048,256]
static constexpr size_t O_FR   = 141230080;    // f16 [384,256]
static constexpr size_t O_FI2  = 141426688;    // f16 [384,256]
static constexpr size_t O_T1   = 141623296;    // f16 [384,256]
static constexpr size_t O_G    = 141819904;    // f16 [384,288]
static constexpr size_t O_WB   = 142041088;    // f16 [256,832]
static constexpr size_t O_WQN  = 142467072;    // f16 [256,256]
static constexpr size_t O_WINT = 142598144;    // f16 [256,256]
static constexpr size_t O_WOUT = 142729216;    // f16 [256,256]
static constexpr size_t O_RAL32= 142860288;    // f32 [501,256]
static constexpr size_t O_DEG  = 143373312;    // int [2,N]
static constexpr size_t O_DINV = 143773312;    // f32 [2,N]
static constexpr size_t O_BNS  = 144173312;    // f32 [1024]
static constexpr size_t O_CNT  = 144177408;    // int [2N]
static constexpr size_t O_PTR  = 144577408;    // int [2N+1]
static constexpr size_t O_CUR  = 144977472;    // int [2N]
static constexpr size_t O_BSUM = 145377472;    // int [128]
static constexpr size_t O_RECS = 145377984;    // int4 [800000] = 12.8MB; also temp Circ16/wloopT
static constexpr size_t WS_NEED= 158177984;

__device__ __forceinline__ float sanit(float v){
  v = (v == v) ? v : 0.f;
  return fminf(60000.f, fmaxf(-60000.f, v));
}
__device__ __forceinline__ _Float16 sat16(float v){ return (_Float16)sanit(v); }
__device__ __forceinline__ int iclamp(int v, int lo, int hi){
  return v < lo ? lo : (v > hi ? hi : v);
}
__device__ __forceinline__ void atomAddF(float* p, float v){
  __hip_atomic_fetch_add(p, v, __ATOMIC_RELAXED, __HIP_MEMORY_SCOPE_AGENT);
}
union HU { unsigned int u; _Float16 h[2]; };

// native-f16 complex multiply (conj(a)*b), packed-math friendly
__device__ __forceinline__ unsigned int cmulh(unsigned int ua, unsigned int ub){
  HU a, b, o; a.u = ua; b.u = ub;
  o.h[0] = a.h[0]*b.h[0] + a.h[1]*b.h[1];
  o.h[1] = a.h[0]*b.h[1] - a.h[1]*b.h[0];
  return o.u;
}

// ---- fused prologue: block-range dispatch over 6 independent jobs ----
// [0,288) gen_dft | [288,800) misc+ral | [800,7050) cvt_x | [7050,9394) deg
// [9394,12519) cnt | [12519,12775) Circ16/wloopT staging
__global__ void k_pro(_Float16* __restrict__ FR, _Float16* __restrict__ FI2,
                      const float* __restrict__ w_in, const float* __restrict__ w_out,
                      const float* __restrict__ w_q, const float* __restrict__ rel_embed,
                      const float* __restrict__ loop_rel, const float* __restrict__ w_loop,
                      _Float16* __restrict__ wqn, _Float16* __restrict__ wint,
                      _Float16* __restrict__ woutt,
                      float* __restrict__ ral32, _Float16* __restrict__ ral16,
                      _Float16* __restrict__ circ16, _Float16* __restrict__ wloopT,
                      const float* __restrict__ x, _Float16* __restrict__ xh,
                      const int* __restrict__ ei, const int* __restrict__ quals,
                      int* __restrict__ deg, int* __restrict__ cnt){
  int b = blockIdx.x, tid = threadIdx.x;
  if (b < 288){
    int t = b*256 + tid;
    const float step = 0.024543692606170259f; // 2*pi/256
    {
      int f = t >> 8, tt = t & 255;
      float v = 0.f;
      if (f < 258){
        int m = f >> 1;
        float ang = (float)((tt*m) & 255) * step;
        v = (f & 1) ? -sinf(ang) : cosf(ang);
      }
      FR[t] = (_Float16)v;
    }
    {
      int k = t >> 8, j = t & 255;
      float v = 0.f;
      if (k < 258){
        int m = k >> 1;
        float w = (m==0 || m==128) ? (1.f/256.f) : (2.f/256.f);
        float ang = (float)((j*m) & 255) * step;
        v = (k & 1) ? -w*sinf(ang) : w*cosf(ang);
      }
      FI2[t] = (_Float16)v;
    }
  } else if (b < 800){
    int t = (b - 288)*256 + tid;   // < 131072
    if (t < 65536){
      int j = t >> 8, n = t & 255;
      wqn[t] = sat16(w_q[t]);
      wint[n*256 + j]  = sat16(w_in[t]);
      woutt[n*256 + j] = sat16(w_out[t]);
    }
    float rv = 0.f;
    if (t < 128000) rv = sanit(rel_embed[t]);
    else if (t < 128256) rv = sanit(loop_rel[t - 128000]);
    ral16[t] = (_Float16)rv;       // rows 501..511 zero pad
    if (t < 128256) ral32[t] = rv;
  } else if (b < 7050){
    int t = (b - 800)*256 + tid;   // < 1,600,000 exactly
    const float4* p = (const float4*)x + (size_t)t*2;
    float4 v0 = p[0], v1 = p[1];
    f16x8 o;
    o[0]=sat16(v0.x); o[1]=sat16(v0.y); o[2]=sat16(v0.z); o[3]=sat16(v0.w);
    o[4]=sat16(v1.x); o[5]=sat16(v1.y); o[6]=sat16(v1.z); o[7]=sat16(v1.w);
    ((f16x8*)xh)[t] = o;
  } else if (b < 9394){
    int t = (b - 7050)*256 + tid;
    if (t < TWOE){
      int d = (t >= EE) ? 1 : 0;
      atomicAdd(&deg[d*NN + iclamp(ei[t], 0, NN-1)], 1);
    }
  } else if (b < 12519){
    int t = (b - 9394)*256 + tid;  // < 800,000 exactly
    if (t < TWOE){
      int d = (t >= EE) ? 1 : 0;
      atomicAdd(&cnt[d*NN + iclamp(ei[TWOE + t], 0, NN-1)], 1);
    } else {
      int qg = t - TWOE;
      int d = (qg >= 100000) ? 1 : 0;
      int e = iclamp(quals[2*TWOQ + qg], 0, EE-1);
      int j = d*EE + e;
      atomicAdd(&cnt[d*NN + iclamp(ei[TWOE + j], 0, NN-1)], 1);
    }
  } else {
    int t = (b - 12519)*256 + tid; // < 65536 exactly
    int r = t >> 8, m = t & 255;
    circ16[t] = sat16(loop_rel[(r + m) & 255]);      // Circ16[j][m]
    wloopT[t] = sat16(w_loop[m*256 + r]);            // wloopT[n][m]
  }
}

// fused: blocks [0,391) dinv ; [391,489) scan1
__global__ void k_dinv_scan1(const int* __restrict__ deg, float* __restrict__ dinv,
                             const int* __restrict__ cnt, int* __restrict__ bsum){
  int b = blockIdx.x, t = threadIdx.x;
  if (b < 391){
    int i = b*256 + t;
    if (i < 2*NN){
      int c = deg[i];
      dinv[i] = (c > 0) ? rsqrtf((float)c) : 0.f;
    }
  } else {
    __shared__ int sh[256];
    int blk = b - 391;
    int base = blk*1024 + t*4;
    int s = 0;
    #pragma unroll
    for (int i = 0; i < 4; ++i){ int idx = base + i; if (idx < 2*NN) s += cnt[idx]; }
    sh[t] = s; __syncthreads();
    for (int off = 128; off > 0; off >>= 1){
      if (t < off) sh[t] += sh[t + off];
      __syncthreads();
    }
    if (t == 0) bsum[blk] = sh[0];
  }
}

__global__ void k_scan2(int* __restrict__ bsum, int* __restrict__ ptr){
  if (threadIdx.x == 0){
    int run = 0;
    for (int i = 0; i < SCB; ++i){ int v = bsum[i]; bsum[i] = run; run += v; }
    ptr[2*NN] = run;
  }
}

__global__ void k_scan3(const int* __restrict__ cnt, const int* __restrict__ bsum,
                        int* __restrict__ ptr, int* __restrict__ cur){
  __shared__ int sh[256];
  int b = blockIdx.x, t = threadIdx.x;
  int base = b*1024 + t*4;
  int v[4];
  int s = 0;
  #pragma unroll
  for (int i = 0; i < 4; ++i){
    int idx = base + i;
    v[i] = (idx < 2*NN) ? cnt[idx] : 0;
    s += v[i];
  }
  sh[t] = s; __syncthreads();
  for (int off = 1; off < 256; off <<= 1){
    int add = (t >= off) ? sh[t - off] : 0;
    __syncthreads();
    sh[t] += add;
    __syncthreads();
  }
  int off0 = bsum[b] + sh[t] - s;
  #pragma unroll
  for (int i = 0; i < 4; ++i){
    int idx = base + i;
    if (idx < 2*NN){ ptr[idx] = off0; cur[idx] = off0; }
    off0 += v[i];
  }
}

// per-item records: {xhat_byte_off, b_byte_off, coef_bits, 0}
__global__ void k_fillrec(const int* __restrict__ ei, const int* __restrict__ et,
                          const int* __restrict__ quals, const float* __restrict__ dinv,
                          int* __restrict__ cursor, int4* __restrict__ recs){
  int t = blockIdx.x*256 + threadIdx.x;
  if (t >= TWOE + TWOQ) return;
  int d, j, boff; float w;
  if (t < TWOE){
    d = (t >= EE) ? 1 : 0;
    j = t;
    boff = (int)O_XHAT + (50048 + iclamp(et[j], 0, 500))*576;   // Rhat rows
    w = 0.8f;
  } else {
    int qg = t - TWOE;
    d = (qg >= 100000) ? 1 : 0;
    int e = iclamp(quals[2*TWOQ + qg], 0, EE-1);
    j = d*EE + e;
    boff = (int)O_YH + (qg - d*100000)*576;
    w = 0.2f;
  }
  int src = iclamp(ei[j], 0, NN-1);
  int dst = iclamp(ei[TWOE + j], 0, NN-1);
  float coef = w * dinv[d*NN + src] * dinv[d*NN + dst];
  int pos = atomicAdd(&cursor[d*NN + dst], 1);
  pos = iclamp(pos, 0, 800000-1);
  int4 rc;
  rc.x = (int)O_XHAT + src*576;
  rc.y = boff;
  rc.z = __float_as_int(coef);
  rc.w = 0;
  recs[pos] = rc;
}

// C[M,N](ldc) = A[.,K](lda) @ Bt[.,K](ldb)^T; fp32 accum; UNGUARDED loads
template<typename OT, bool ACC>
__global__ __launch_bounds__(256) void k_gemm(const _Float16* __restrict__ A, int lda,
                                              const _Float16* __restrict__ Bt, int ldb,
                                              OT* __restrict__ C, int ldc,
                                              int N, int K){
  __shared__ __align__(16) _Float16 Ash[128*40];
  __shared__ __align__(16) _Float16 Bsh[128*40];
  const int tid = threadIdx.x;
  const int lane = tid & 63;
  const int wv = tid >> 6;
  const int bm = blockIdx.x*128, bn = blockIdx.y*128;
  const int wm = (wv >> 1)*64, wn = (wv & 1)*64;
  const int sr = tid >> 1;
  const int sc = (tid & 1)*16;
  const int fr = lane & 15;
  const int fk = (lane >> 4)*8;
  const _Float16* pa = A + (size_t)(bm+sr)*lda + sc;
  const _Float16* pb = Bt + (size_t)(bn+sr)*ldb + sc;
  f32x4 acc[4][4] = {};
  for (int kt = 0; kt < K; kt += 32){
    float4 a0 = *(const float4*)(pa);
    float4 a1 = *(const float4*)(pa + 8);
    float4 b0 = *(const float4*)(pb);
    float4 b1 = *(const float4*)(pb + 8);
    pa += 32; pb += 32;
    __syncthreads();
    *(float4*)&Ash[sr*40 + sc]     = a0;
    *(float4*)&Ash[sr*40 + sc + 8] = a1;
    *(float4*)&Bsh[sr*40 + sc]     = b0;
    *(float4*)&Bsh[sr*40 + sc + 8] = b1;
    __syncthreads();
    f16x8 af[4], bf_[4];
    #pragma unroll
    for (int i = 0; i < 4; ++i) af[i]  = *(const f16x8*)&Ash[(wm + i*16 + fr)*40 + fk];
    #pragma unroll
    for (int j = 0; j < 4; ++j) bf_[j] = *(const f16x8*)&Bsh[(wn + j*16 + fr)*40 + fk];
    #pragma unroll
    for (int i = 0; i < 4; ++i)
      #pragma unroll
      for (int j = 0; j < 4; ++j)
        acc[i][j] = __builtin_amdgcn_mfma_f32_16x16x32_f16(af[i], bf_[j], acc[i][j], 0, 0, 0);
  }
  const int cr = (lane >> 4)*4;
  const int cc = lane & 15;
  #pragma unroll
  for (int i = 0; i < 4; ++i)
    #pragma unroll
    for (int j = 0; j < 4; ++j){
      int col = bn + wn + j*16 + cc;
      if (col < N){
        #pragma unroll
        for (int r = 0; r < 4; ++r){
          size_t idx = (size_t)(bm + wm + i*16 + cr + r)*ldc + col;
          float v = acc[i][j][r];
          if (ACC) v += (float)C[idx];
          C[idx] = (OT)sanit(v);
        }
      }
    }
}

// Fused qual GEMM with register double-buffer pipeline:
// Yhat[q] = (conj(Xhat[ent_q]) .* Rhat[rel_q]) @ G^T ; grid (782,3)
__global__ __launch_bounds__(256) void k_qgemm(const _Float16* __restrict__ Xhat,
                                               const _Float16* __restrict__ Rhat,
                                               const int* __restrict__ quals, int d,
                                               const _Float16* __restrict__ G,
                                               _Float16* __restrict__ Yhat){
  __shared__ __align__(16) _Float16 Ash[128*40];
  __shared__ __align__(16) _Float16 Bsh[128*40];
  const int tid = threadIdx.x;
  const int lane = tid & 63;
  const int wv = tid >> 6;
  const int bm = blockIdx.x*128, bn = blockIdx.y*128;
  const int wm = (wv >> 1)*64, wn = (wv & 1)*64;
  const int sr = tid >> 1;
  const int h  = tid & 1;
  const int fr = lane & 15;
  const int fk = (lane >> 4)*8;
  int q = bm + sr; if (q > 99999) q = 99999;
  int qi = d*100000 + q;
  int rel = iclamp(quals[qi], 0, 500);
  int ent = iclamp(quals[TWOQ + qi], 0, NN-1);
  const unsigned int* xr = (const unsigned int*)(Xhat + (size_t)ent*288);
  const unsigned int* rr = (const unsigned int*)(Rhat + (size_t)rel*288);
  const _Float16* gbase = G + (size_t)(bn+sr)*288 + h*16;
  // prefetch kt=0
  int kb = h*8;
  uint4 nxa0 = *(const uint4*)(xr + kb);
  uint4 nxa1 = *(const uint4*)(xr + kb + 4);
  uint4 nra0 = *(const uint4*)(rr + kb);
  uint4 nra1 = *(const uint4*)(rr + kb + 4);
  float4 nb0 = *(const float4*)(gbase);
  float4 nb1 = *(const float4*)(gbase + 8);
  f32x4 acc[4][4] = {};
  for (int kt = 0; kt < 288; kt += 32){
    uint4 oa0, oa1;
    oa0.x = cmulh(nxa0.x, nra0.x); oa0.y = cmulh(nxa0.y, nra0.y);
    oa0.z = cmulh(nxa0.z, nra0.z); oa0.w = cmulh(nxa0.w, nra0.w);
    oa1.x = cmulh(nxa1.x, nra1.x); oa1.y = cmulh(nxa1.y, nra1.y);
    oa1.z = cmulh(nxa1.z, nra1.z); oa1.w = cmulh(nxa1.w, nra1.w);
    float4 b0 = nb0, b1 = nb1;
    __syncthreads();
    *(uint4*)&Ash[sr*40 + h*16]      = oa0;
    *(uint4*)&Ash[sr*40 + h*16 + 8]  = oa1;
    *(float4*)&Bsh[sr*40 + h*16]     = b0;
    *(float4*)&Bsh[sr*40 + h*16 + 8] = b1;
    __syncthreads();
    // prefetch next k-step (clamped; latency hidden under MFMA below)
    int kt2 = kt + 32; if (kt2 > 256) kt2 = 256;
    int kb2 = (kt2 >> 1) + h*8;
    nxa0 = *(const uint4*)(xr + kb2);
    nxa1 = *(const uint4*)(xr + kb2 + 4);
    nra0 = *(const uint4*)(rr + kb2);
    nra1 = *(const uint4*)(rr + kb2 + 4);
    const _Float16* gb2 = gbase + kt2;
    nb0 = *(const float4*)(gb2);
    nb1 = *(const float4*)(gb2 + 8);
    f16x8 af[4], bf_[4];
    #pragma unroll
    for (int i = 0; i < 4; ++i) af[i]  = *(const f16x8*)&Ash[(wm + i*16 + fr)*40 + fk];
    #pragma unroll
    for (int j = 0; j < 4; ++j) bf_[j] = *(const f16x8*)&Bsh[(wn + j*16 + fr)*40 + fk];
    #pragma unroll
    for (int i = 0; i < 4; ++i)
      #pragma unroll
      for (int j = 0; j < 4; ++j)
        acc[i][j] = __builtin_amdgcn_mfma_f32_16x16x32_f16(af[i], bf_[j], acc[i][j], 0, 0, 0);
  }
  const int cr = (lane >> 4)*4;
  const int cc = lane & 15;
  #pragma unroll
  for (int i = 0; i < 4; ++i)
    #pragma unroll
    for (int j = 0; j < 4; ++j){
      int col = bn + wn + j*16 + cc;
      if (col < 288){
        #pragma unroll
        for (int r = 0; r < 4; ++r){
          size_t idx = (size_t)(bm + wm + i*16 + cr + r)*288 + col;
          Yhat[idx] = sat16(acc[i][j][r]);
        }
      }
    }
}

// ---- gather-aggregate via records, depth-2 software pipeline ----
__global__ __launch_bounds__(128) void k_agg(const char* __restrict__ Wb,
                                             const int* __restrict__ ptr,
                                             const int4* __restrict__ recs,
                                             int d, _Float16* __restrict__ AGGh){
  int node = blockIdx.x;
  int t = threadIdx.x;
  int gnode = d*NN + node;
  int beg = ptr[gnode], end = ptr[gnode+1];
  unsigned int* orow = (unsigned int*)(AGGh + (size_t)node*288);
  if (end <= beg){
    orow[t] = 0;
    if (t < 16) orow[128 + t] = 0;
    return;
  }
  int last = end - 1;
  auto ld = [&](int idx, unsigned& va, unsigned& vb, float& ah, float& bh, float& cf){
    int ic = idx < last ? idx : last;
    int4 rc = recs[ic];
    const unsigned* xr = (const unsigned*)(Wb + rc.x);
    const unsigned* br = (const unsigned*)(Wb + rc.y);
    va = xr[t]; vb = br[t];
    ah = (float)((const _Float16*)xr)[256];
    bh = (float)((const _Float16*)br)[256];
    cf = (idx <= last) ? __int_as_float(rc.z) : 0.f;
  };
  float ax_ = 0.f, ay_ = 0.f, ex = 0.f;
  unsigned va0, vb0, va1, vb1; float ah0, bh0, ah1, bh1, cf0, cf1;
  ld(beg,     va0, vb0, ah0, bh0, cf0);
  ld(beg + 1, va1, vb1, ah1, bh1, cf1);
  for (int k = beg; k < end; k += 2){
    unsigned ta0, tb0, ta1, tb1; float th0, tg0, th1, tg1, tc0, tc1;
    ld(k + 2, ta0, tb0, th0, tg0, tc0);
    ld(k + 3, ta1, tb1, th1, tg1, tc1);
    {
      HU a, b; a.u = va0; b.u = vb0;
      float axv=(float)a.h[0], ayv=(float)a.h[1], bxv=(float)b.h[0], byv=(float)b.h[1];
      ax_ += cf0*(axv*bxv + ayv*byv);
      ay_ += cf0*(axv*byv - ayv*bxv);
      ex  += cf0*ah0*bh0;
    }
    {
      HU a, b; a.u = va1; b.u = vb1;
      float axv=(float)a.h[0], ayv=(float)a.h[1], bxv=(float)b.h[0], byv=(float)b.h[1];
      ax_ += cf1*(axv*bxv + ayv*byv);
      ay_ += cf1*(axv*byv - ayv*bxv);
      ex  += cf1*ah1*bh1;
    }
    va0=ta0; vb0=tb0; ah0=th0; bh0=tg0; cf0=tc0;
    va1=ta1; vb1=tb1; ah1=th1; bh1=tg1; cf1=tc1;
  }
  HU o; o.h[0] = sat16(ax_); o.h[1] = sat16(ay_);
  orow[t] = o.u;
  if (t < 16){
    HU o2; o2.h[0] = (t == 0) ? sat16(ex) : (_Float16)0.f; o2.h[1] = (_Float16)0.f;
    orow[128 + t] = o2.u;
  }
}

__global__ void k_bnstats(const _Float16* __restrict__ opre, float* __restrict__ bns){
  int col = threadIdx.x;
  int r0 = blockIdx.x*64, r1 = r0 + 64; if (r1 > NN) r1 = NN;
  float s1 = 0.f, s2 = 0.f;
  for (int r = r0; r < r1; ++r){
    float v = (float)opre[(size_t)r*256 + col];
    s1 += v; s2 += v*v;
  }
  atomAddF(&bns[col], s1);
  atomAddF(&bns[256 + col], s2);
}

__global__ void k_bnfinal(float* __restrict__ bns, const float* __restrict__ gamma,
                          const float* __restrict__ beta){
  int col = threadIdx.x;
  float mean = bns[col] * (1.f/NN);
  float var  = bns[256 + col] * (1.f/NN) - mean*mean;
  var = fmaxf(var, 0.f);
  // BN of (acc/3 + bias) == (acc-mean_acc)/sqrt(var_acc + 9*eps); bias cancels
  float g = gamma[col] * rsqrtf(var + 9e-5f);
  float b = beta[col] - mean*g;
  bns[512 + col] = sanit(g);
  bns[768 + col] = sanit(b);
}

// fused epilogue: blocks [0,6250) ent-BN-tanh ; [6250,6750) rel_out
__global__ void k_epi(const _Float16* __restrict__ opre, const float* __restrict__ bns,
                      const float* __restrict__ ral32, const float* __restrict__ w_rel,
                      float* __restrict__ out){
  int b = blockIdx.x;
  if (b < 6250){
    int t = b*256 + threadIdx.x;     // < NN*32 exactly
    f16x8 v = ((const f16x8*)opre)[t];
    int col = (t & 31)*8;
    float4 o0, o1;
    o0.x = sanit(tanhf((float)v[0]*bns[512+col+0] + bns[768+col+0]));
    o0.y = sanit(tanhf((float)v[1]*bns[512+col+1] + bns[768+col+1]));
    o0.z = sanit(tanhf((float)v[2]*bns[512+col+2] + bns[768+col+2]));
    o0.w = sanit(tanhf((float)v[3]*bns[512+col+3] + bns[768+col+3]));
    o1.x = sanit(tanhf((float)v[4]*bns[512+col+4] + bns[768+col+4]));
    o1.y = sanit(tanhf((float)v[5]*bns[512+col+5] + bns[768+col+5]));
    o1.z = sanit(tanhf((float)v[6]*bns[512+col+6] + bns[768+col+6]));
    o1.w = sanit(tanhf((float)v[7]*bns[512+col+7] + bns[768+col+7]));
    ((float4*)out)[(size_t)t*2]     = o0;
    ((float4*)out)[(size_t)t*2 + 1] = o1;
  } else {
    int r = b - 6250, n = threadIdx.x;
    float acc = 0.f;
    for (int k = 0; k < 256; ++k)
      acc += ral32[r*256 + k] * w_rel[k*256 + n];
    out[12800000 + r*256 + n] = sanit(acc);
  }
}

extern "C" void kernel_launch(void* const* d_in, const int* in_sizes, int n_in,
                              void* d_out, int out_size, void* d_ws, size_t ws_size,
                              hipStream_t stream){
  (void)in_sizes; (void)n_in;
  if (ws_size < WS_NEED){
    hipMemsetAsync(d_out, 0, (size_t)out_size*4, stream);
    return;
  }
  const float* x        = (const float*)d_in[0];
  const float* rel_emb  = (const float*)d_in[1];
  const float* w_in     = (const float*)d_in[2];
  const float* w_out_   = (const float*)d_in[3];
  const float* w_loop   = (const float*)d_in[4];
  const float* w_rel    = (const float*)d_in[5];
  const float* w_q      = (const float*)d_in[6];
  const float* loop_rel = (const float*)d_in[7];
  const float* gamma    = (const float*)d_in[9];
  const float* beta     = (const float*)d_in[10];
  const int* ei    = (const int*)d_in[11];
  const int* et    = (const int*)d_in[12];
  const int* quals = (const int*)d_in[13];
  float* out = (float*)d_out;
  char* W = (char*)d_ws;
  _Float16* xh    = (_Float16*)(W + O_XH);
  _Float16* AGGh  = (_Float16*)(W + O_XH);
  _Float16* ral16 = xh + (size_t)50048*256;          // rows appended to xh
  _Float16* Xhat  = (_Float16*)(W + O_XHAT);
  _Float16* Rhat  = Xhat + (size_t)50048*288;        // rows appended to Xhat
  _Float16* Yhat  = (_Float16*)(W + O_YH);
  _Float16* opre  = (_Float16*)(W + O_OPRE);
  _Float16* FR    = (_Float16*)(W + O_FR);
  _Float16* FI2   = (_Float16*)(W + O_FI2);
  _Float16* T1    = (_Float16*)(W + O_T1);
  _Float16* G     = (_Float16*)(W + O_G);
  _Float16* WB    = (_Float16*)(W + O_WB);
  _Float16* wqn   = (_Float16*)(W + O_WQN);
  _Float16* wint  = (_Float16*)(W + O_WINT);
  _Float16* woutt = (_Float16*)(W + O_WOUT);
  float*    ral32 = (float*)(W + O_RAL32);
  int*      deg   = (int*)(W + O_DEG);
  float*    dinv  = (float*)(W + O_DINV);
  float*    bns   = (float*)(W + O_BNS);
  int*      cnt   = (int*)(W + O_CNT);
  int*      ptr   = (int*)(W + O_PTR);
  int*      cur   = (int*)(W + O_CUR);
  int*      bsum  = (int*)(W + O_BSUM);
  int4*     recs  = (int4*)(W + O_RECS);
  _Float16* circ16= (_Float16*)(W + O_RECS);           // temp, dead before fillrec
  _Float16* wloopT= (_Float16*)(W + O_RECS + 131072);

  hipMemsetAsync(deg, 0, 400000, stream);
  hipMemsetAsync(cnt, 0, 400000, stream);
  hipMemsetAsync(bns, 0, 4096, stream);

  k_pro<<<12775, 256, 0, stream>>>(FR, FI2, w_in, w_out_, w_q, rel_emb, loop_rel, w_loop,
                                   wqn, wint, woutt, ral32, ral16, circ16, wloopT,
                                   x, xh, ei, quals, deg, cnt);
  // WB[:,576:832] = (Circ @ w_loop)^T  via GEMM (replaces serial gen_bw)
  k_gemm<_Float16,false><<<dim3(2,2), 256, 0, stream>>>(wloopT, 256, circ16, 256,
                                                        WB + 576, 832, 256, 256);
  k_dinv_scan1<<<391 + SCB, 256, 0, stream>>>(deg, dinv, cnt, bsum);
  k_scan2<<<1, 64, 0, stream>>>(bsum, ptr);
  k_scan3<<<SCB, 256, 0, stream>>>(cnt, bsum, ptr, cur);
  k_fillrec<<<3125, 256, 0, stream>>>(ei, et, quals, dinv, cur, recs);

  // T1 = FR @ wqn^T ; G = T1 @ FI2^T   (G = Fr.Wq^T.Fi^T)
  k_gemm<_Float16,false><<<dim3(3,2), 256, 0, stream>>>(FR, 256, wqn, 256, T1, 256, 256, 256);
  k_gemm<_Float16,false><<<dim3(3,3), 256, 0, stream>>>(T1, 256, FI2, 256, G, 288, 288, 256);
  // WB[:,0:288] = (Fi.W_in)^T-pack ; WB[:,288:576] for w_out
  k_gemm<_Float16,false><<<dim3(2,3), 256, 0, stream>>>(wint, 256, FI2, 256, WB, 832, 288, 256);
  k_gemm<_Float16,false><<<dim3(2,3), 256, 0, stream>>>(woutt, 256, FI2, 256, WB + 288, 832, 288, 256);

  // [Xhat ; Rhat] = [x ; rel_all] @ FR^T  (one GEMM, 50560 rows)
  k_gemm<_Float16,false><<<dim3(395,3), 256, 0, stream>>>(xh, 256, FR, 256, Xhat, 288, 288, 256);

  // opre = x @ BW (self-loop); f16 output
  k_gemm<_Float16,false><<<dim3(391,2), 256, 0, stream>>>(xh, 256, WB + 576, 832, opre, 256, 256, 256);

  for (int d = 0; d < 2; ++d){
    k_qgemm<<<dim3(782,3), 256, 0, stream>>>(Xhat, Rhat, quals, d, G, Yhat);
    k_agg<<<NN, 128, 0, stream>>>(W, ptr, recs, d, AGGh);
    k_gemm<_Float16,true><<<dim3(391,2), 256, 0, stream>>>(AGGh, 288, WB + (size_t)d*288, 832,
                                                           opre, 256, 256, 288);
  }

  k_bnstats<<<782, 256, 0, stream>>>(opre, bns);
  k_bnfinal<<<1, 256, 0, stream>>>(bns, gamma, beta);
  k_epi<<<6750, 256, 0, stream>>>(opre, bns, ral32, w_rel, out);
}

// Round 12
// 543.527 us; speedup vs baseline: 1.3035x; 1.1953x over previous
//
#include <hip/hip_runtime.h>

typedef __attribute__((ext_vector_type(8))) _Float16 f16x8;
typedef __attribute__((ext_vector_type(4))) float f32x4;

#define NN   50000
#define EE   300000
#define TWOE 600000
#define TWOQ 200000
#define SCB  98     // scan blocks of 1024 ints covering 2*NN=100000

// ---- workspace layout (bytes), total 181,457,600 (<= proven 184,089,664) ----
static constexpr size_t O_XCAT = 0;            // f16 [50560][832]: cols 0:256 x / ral16 rows 50048+, 256:544 AGG0, 544:832 AGG1
static constexpr size_t O_XHAT = 84131840;     // f16 [50560][288]: rows 0..50047 Xhat, 50048..50559 Rhat
static constexpr size_t O_YH   = 113254400;    // f16 [100096][288] Yhat (per-dir); later opre f16 [50048][256] aliases
static constexpr size_t O_FR   = 170909696;    // f16 [384,256]
static constexpr size_t O_FI2  = 171106304;    // f16 [384,256]
static constexpr size_t O_T1   = 171302912;    // f16 [384,256]
static constexpr size_t O_G    = 171499520;    // f16 [384,288]
static constexpr size_t O_WB   = 171720704;    // f16 [256,832]: [0:256]=BW, [256:544]=FiWin, [544:832]=FiWout
static constexpr size_t O_WQN  = 172146688;    // f16 [256,256]
static constexpr size_t O_WINT = 172277760;    // f16 [256,256]
static constexpr size_t O_WOUT = 172408832;    // f16 [256,256]
static constexpr size_t O_RAL32= 172539904;    // f32 [501,256]
static constexpr size_t O_DEG  = 173052928;    // int [2,N]   (deg+cnt adjacent: one memset)
static constexpr size_t O_CNT  = 173452928;    // int [2N]
static constexpr size_t O_BNS  = 173852928;    // f32 [1024]
static constexpr size_t O_DINV = 173857024;    // f32 [2,N]
static constexpr size_t O_PTR  = 174257024;    // int [2N+1]
static constexpr size_t O_CUR  = 174657088;    // int [2N]
static constexpr size_t O_BSUM = 175057088;    // int [128]
static constexpr size_t O_RECS = 175057600;    // int2 [800000] = 6.4MB; temp circ16/wloopT alias
static constexpr size_t WS_NEED= 181457600;

__device__ __forceinline__ float sanit(float v){
  v = (v == v) ? v : 0.f;
  return fminf(60000.f, fmaxf(-60000.f, v));
}
__device__ __forceinline__ _Float16 sat16(float v){ return (_Float16)sanit(v); }
__device__ __forceinline__ int iclamp(int v, int lo, int hi){
  return v < lo ? lo : (v > hi ? hi : v);
}
__device__ __forceinline__ void atomAddF(float* p, float v){
  __hip_atomic_fetch_add(p, v, __ATOMIC_RELAXED, __HIP_MEMORY_SCOPE_AGENT);
}
union HU { unsigned int u; _Float16 h[2]; };

// native-f16 complex multiply (conj(a)*b)
__device__ __forceinline__ unsigned int cmulh(unsigned int ua, unsigned int ub){
  HU a, b, o; a.u = ua; b.u = ub;
  o.h[0] = a.h[0]*b.h[0] + a.h[1]*b.h[1];
  o.h[1] = a.h[0]*b.h[1] - a.h[1]*b.h[0];
  return o.u;
}

// ---- fused prologue ----
// [0,288) gen_dft | [288,800) misc+ral | [800,7050) cvt_x->XCAT | [7050,9394) deg
// [9394,12519) cnt | [12519,12775) circ16/wloopT
__global__ void k_pro(_Float16* __restrict__ FR, _Float16* __restrict__ FI2,
                      const float* __restrict__ w_in, const float* __restrict__ w_out,
                      const float* __restrict__ w_q, const float* __restrict__ rel_embed,
                      const float* __restrict__ loop_rel, const float* __restrict__ w_loop,
                      _Float16* __restrict__ wqn, _Float16* __restrict__ wint,
                      _Float16* __restrict__ woutt,
                      float* __restrict__ ral32,
                      _Float16* __restrict__ circ16, _Float16* __restrict__ wloopT,
                      const float* __restrict__ x, _Float16* __restrict__ XC,
                      const int* __restrict__ ei, const int* __restrict__ quals,
                      int* __restrict__ deg, int* __restrict__ cnt){
  int b = blockIdx.x, tid = threadIdx.x;
  if (b < 288){
    int t = b*256 + tid;
    const float step = 0.024543692606170259f; // 2*pi/256
    {
      int f = t >> 8, tt = t & 255;
      float v = 0.f;
      if (f < 258){
        int m = f >> 1;
        float ang = (float)((tt*m) & 255) * step;
        v = (f & 1) ? -sinf(ang) : cosf(ang);
      }
      FR[t] = (_Float16)v;
    }
    {
      int k = t >> 8, j = t & 255;
      float v = 0.f;
      if (k < 258){
        int m = k >> 1;
        float w = (m==0 || m==128) ? (1.f/256.f) : (2.f/256.f);
        float ang = (float)((j*m) & 255) * step;
        v = (k & 1) ? -w*sinf(ang) : w*cosf(ang);
      }
      FI2[t] = (_Float16)v;
    }
  } else if (b < 800){
    int t = (b - 288)*256 + tid;   // < 131072
    if (t < 65536){
      int j = t >> 8, n = t & 255;
      wqn[t] = sat16(w_q[t]);
      wint[n*256 + j]  = sat16(w_in[t]);
      woutt[n*256 + j] = sat16(w_out[t]);
    }
    float rv = 0.f;
    if (t < 128000) rv = sanit(rel_embed[t]);
    else if (t < 128256) rv = sanit(loop_rel[t - 128000]);
    int row = t >> 8, c = t & 255;
    XC[(size_t)(50048 + row)*832 + c] = (_Float16)rv;   // ral16 rows (pad rows zero)
    if (t < 128256) ral32[t] = rv;
  } else if (b < 7050){
    int t = (b - 800)*256 + tid;   // < 1,600,000 exactly (50000 rows x 32 chunks)
    const float4* p = (const float4*)x + (size_t)t*2;
    float4 v0 = p[0], v1 = p[1];
    f16x8 o;
    o[0]=sat16(v0.x); o[1]=sat16(v0.y); o[2]=sat16(v0.z); o[3]=sat16(v0.w);
    o[4]=sat16(v1.x); o[5]=sat16(v1.y); o[6]=sat16(v1.z); o[7]=sat16(v1.w);
    int row = t >> 5, c8 = (t & 31)*8;
    *(f16x8*)(XC + (size_t)row*832 + c8) = o;
  } else if (b < 9394){
    int t = (b - 7050)*256 + tid;
    if (t < TWOE){
      int d = (t >= EE) ? 1 : 0;
      atomicAdd(&deg[d*NN + iclamp(ei[t], 0, NN-1)], 1);
    }
  } else if (b < 12519){
    int t = (b - 9394)*256 + tid;  // < 800,000 exactly
    if (t < TWOE){
      int d = (t >= EE) ? 1 : 0;
      atomicAdd(&cnt[d*NN + iclamp(ei[TWOE + t], 0, NN-1)], 1);
    } else {
      int qg = t - TWOE;
      int d = (qg >= 100000) ? 1 : 0;
      int e = iclamp(quals[2*TWOQ + qg], 0, EE-1);
      int j = d*EE + e;
      atomicAdd(&cnt[d*NN + iclamp(ei[TWOE + j], 0, NN-1)], 1);
    }
  } else {
    int t = (b - 12519)*256 + tid; // < 65536 exactly
    int r = t >> 8, m = t & 255;
    circ16[t] = sat16(loop_rel[(r + m) & 255]);      // Circ16[j][m]
    wloopT[t] = sat16(w_loop[m*256 + r]);            // wloopT[n][m]
  }
}

// fused: blocks [0,391) dinv ; [391,489) scan1
__global__ void k_dinv_scan1(const int* __restrict__ deg, float* __restrict__ dinv,
                             const int* __restrict__ cnt, int* __restrict__ bsum){
  int b = blockIdx.x, t = threadIdx.x;
  if (b < 391){
    int i = b*256 + t;
    if (i < 2*NN){
      int c = deg[i];
      dinv[i] = (c > 0) ? rsqrtf((float)c) : 0.f;
    }
  } else {
    __shared__ int sh[256];
    int blk = b - 391;
    int base = blk*1024 + t*4;
    int s = 0;
    #pragma unroll
    for (int i = 0; i < 4; ++i){ int idx = base + i; if (idx < 2*NN) s += cnt[idx]; }
    sh[t] = s; __syncthreads();
    for (int off = 128; off > 0; off >>= 1){
      if (t < off) sh[t] += sh[t + off];
      __syncthreads();
    }
    if (t == 0) bsum[blk] = sh[0];
  }
}

__global__ void k_scan2(int* __restrict__ bsum, int* __restrict__ ptr){
  if (threadIdx.x == 0){
    int run = 0;
    for (int i = 0; i < SCB; ++i){ int v = bsum[i]; bsum[i] = run; run += v; }
    ptr[2*NN] = run;
  }
}

__global__ void k_scan3(const int* __restrict__ cnt, const int* __restrict__ bsum,
                        int* __restrict__ ptr, int* __restrict__ cur){
  __shared__ int sh[256];
  int b = blockIdx.x, t = threadIdx.x;
  int base = b*1024 + t*4;
  int v[4];
  int s = 0;
  #pragma unroll
  for (int i = 0; i < 4; ++i){
    int idx = base + i;
    v[i] = (idx < 2*NN) ? cnt[idx] : 0;
    s += v[i];
  }
  sh[t] = s; __syncthreads();
  for (int off = 1; off < 256; off <<= 1){
    int add = (t >= off) ? sh[t - off] : 0;
    __syncthreads();
    sh[t] += add;
    __syncthreads();
  }
  int off0 = bsum[b] + sh[t] - s;
  #pragma unroll
  for (int i = 0; i < 4; ++i){
    int idx = base + i;
    if (idx < 2*NN){ ptr[idx] = off0; cur[idx] = off0; }
    off0 += v[i];
  }
}

// packed per-item records int2: x.lo16=xrow, x.hi16=brow.lo16;
// y: bit0=brow.bit16, bit1=isqual, bits31:16=coef f16
__global__ void k_fillrec(const int* __restrict__ ei, const int* __restrict__ et,
                          const int* __restrict__ quals, const float* __restrict__ dinv,
                          int* __restrict__ cursor, int2* __restrict__ recs){
  int t = blockIdx.x*256 + threadIdx.x;
  if (t >= TWOE + TWOQ) return;
  int d, j, brow, isq; float w;
  if (t < TWOE){
    d = (t >= EE) ? 1 : 0;
    j = t;
    brow = 50048 + iclamp(et[j], 0, 500);   // Rhat row within XHAT region
    isq = 0; w = 0.8f;
  } else {
    int qg = t - TWOE;
    d = (qg >= 100000) ? 1 : 0;
    int e = iclamp(quals[2*TWOQ + qg], 0, EE-1);
    j = d*EE + e;
    brow = qg - d*100000;                   // Yhat row (per-direction)
    isq = 1; w = 0.2f;
  }
  int src = iclamp(ei[j], 0, NN-1);
  int dst = iclamp(ei[TWOE + j], 0, NN-1);
  float coef = w * dinv[d*NN + src] * dinv[d*NN + dst];
  int pos = atomicAdd(&cursor[d*NN + dst], 1);
  pos = iclamp(pos, 0, 800000-1);
  HU cu; cu.h[0] = (_Float16)coef; cu.h[1] = (_Float16)0.f;
  int2 rc;
  rc.x = src | ((brow & 0xffff) << 16);
  rc.y = ((brow >> 16) & 1) | (isq << 1) | ((int)(cu.u & 0xffffu) << 16);
  recs[pos] = rc;
}

// ---- shared GEMM body: C[.,N](ldc) = A[.,K](lda) @ Bt[.,K](ldb)^T; UNGUARDED loads ----
template<typename OT, bool ACC>
__device__ __forceinline__ void gemm_body(const _Float16* __restrict__ A, int lda,
                                          const _Float16* __restrict__ Bt, int ldb,
                                          OT* __restrict__ C, int ldc,
                                          int N, int K, int bx, int by){
  __shared__ __align__(16) _Float16 Ash[128*40];
  __shared__ __align__(16) _Float16 Bsh[128*40];
  const int tid = threadIdx.x;
  const int lane = tid & 63;
  const int wv = tid >> 6;
  const int bm = bx*128, bn = by*128;
  const int wm = (wv >> 1)*64, wn = (wv & 1)*64;
  const int sr = tid >> 1;
  const int sc = (tid & 1)*16;
  const int fr = lane & 15;
  const int fk = (lane >> 4)*8;
  const _Float16* pa = A + (size_t)(bm+sr)*lda + sc;
  const _Float16* pb = Bt + (size_t)(bn+sr)*ldb + sc;
  f32x4 acc[4][4] = {};
  for (int kt = 0; kt < K; kt += 32){
    float4 a0 = *(const float4*)(pa);
    float4 a1 = *(const float4*)(pa + 8);
    float4 b0 = *(const float4*)(pb);
    float4 b1 = *(const float4*)(pb + 8);
    pa += 32; pb += 32;
    __syncthreads();
    *(float4*)&Ash[sr*40 + sc]     = a0;
    *(float4*)&Ash[sr*40 + sc + 8] = a1;
    *(float4*)&Bsh[sr*40 + sc]     = b0;
    *(float4*)&Bsh[sr*40 + sc + 8] = b1;
    __syncthreads();
    f16x8 af[4], bf_[4];
    #pragma unroll
    for (int i = 0; i < 4; ++i) af[i]  = *(const f16x8*)&Ash[(wm + i*16 + fr)*40 + fk];
    #pragma unroll
    for (int j = 0; j < 4; ++j) bf_[j] = *(const f16x8*)&Bsh[(wn + j*16 + fr)*40 + fk];
    #pragma unroll
    for (int i = 0; i < 4; ++i)
      #pragma unroll
      for (int j = 0; j < 4; ++j)
        acc[i][j] = __builtin_amdgcn_mfma_f32_16x16x32_f16(af[i], bf_[j], acc[i][j], 0, 0, 0);
  }
  const int cr = (lane >> 4)*4;
  const int cc = lane & 15;
  #pragma unroll
  for (int i = 0; i < 4; ++i)
    #pragma unroll
    for (int j = 0; j < 4; ++j){
      int col = bn + wn + j*16 + cc;
      if (col < N){
        #pragma unroll
        for (int r = 0; r < 4; ++r){
          size_t idx = (size_t)(bm + wm + i*16 + cr + r)*ldc + col;
          float v = acc[i][j][r];
          if (ACC) v += (float)C[idx];
          C[idx] = (OT)sanit(v);
        }
      }
    }
}

template<typename OT, bool ACC>
__global__ __launch_bounds__(256) void k_gemm(const _Float16* __restrict__ A, int lda,
                                              const _Float16* __restrict__ Bt, int ldb,
                                              OT* __restrict__ C, int ldc,
                                              int N, int K){
  gemm_body<OT,ACC>(A, lda, Bt, ldb, C, ldc, N, K, blockIdx.x, blockIdx.y);
}

// batch of 4 independent small setup GEMMs (22 blocks total)
__global__ __launch_bounds__(256) void k_setup(const _Float16* __restrict__ FR,
                                               const _Float16* __restrict__ wqn,
                                               _Float16* __restrict__ T1,
                                               const _Float16* __restrict__ wint,
                                               const _Float16* __restrict__ woutt,
                                               const _Float16* __restrict__ FI2,
                                               _Float16* __restrict__ WB,
                                               const _Float16* __restrict__ wloopT,
                                               const _Float16* __restrict__ circ16){
  int b = blockIdx.x;
  if (b < 6)       gemm_body<_Float16,false>(FR, 256, wqn, 256, T1, 256, 256, 256, b % 3, b / 3);
  else if (b < 12){ int i = b - 6;  gemm_body<_Float16,false>(wint, 256, FI2, 256, WB + 256, 832, 288, 256, i % 2, i / 2); }
  else if (b < 18){ int i = b - 12; gemm_body<_Float16,false>(woutt, 256, FI2, 256, WB + 544, 832, 288, 256, i % 2, i / 2); }
  else            { int i = b - 18; gemm_body<_Float16,false>(wloopT, 256, circ16, 256, WB, 832, 256, 256, i % 2, i / 2); }
}

// Fused qual GEMM, XCD-triple swizzled (grid 2352, 1-D):
// Yhat[q] = (conj(Xhat[ent_q]) .* Rhat[rel_q]) @ G^T
__global__ __launch_bounds__(256) void k_qgemm(const _Float16* __restrict__ Xhat,
                                               const int* __restrict__ quals, int d,
                                               const _Float16* __restrict__ G,
                                               _Float16* __restrict__ Yhat){
  int L = blockIdx.x;
  int xcd = L & 7, w = L >> 3;
  int t3 = (w / 3)*8 + xcd;          // row-block (triple) id: 3 col-tiles share XCD
  if (t3 >= 782) return;
  int bn = (w % 3)*128;
  int bm = t3*128;
  __shared__ __align__(16) _Float16 Ash[128*40];
  __shared__ __align__(16) _Float16 Bsh[128*40];
  const int tid = threadIdx.x;
  const int lane = tid & 63;
  const int wv = tid >> 6;
  const int wm = (wv >> 1)*64, wn = (wv & 1)*64;
  const int sr = tid >> 1;
  const int h  = tid & 1;
  const int fr = lane & 15;
  const int fk = (lane >> 4)*8;
  int q = bm + sr; if (q > 99999) q = 99999;
  int qi = d*100000 + q;
  int rel = iclamp(quals[qi], 0, 500);
  int ent = iclamp(quals[TWOQ + qi], 0, NN-1);
  const unsigned int* xr = (const unsigned int*)(Xhat + (size_t)ent*288);
  const unsigned int* rr = (const unsigned int*)(Xhat + (size_t)(50048 + rel)*288);
  const _Float16* gbase = G + (size_t)(bn+sr)*288 + h*16;
  int kb = h*8;
  uint4 nxa0 = *(const uint4*)(xr + kb);
  uint4 nxa1 = *(const uint4*)(xr + kb + 4);
  uint4 nra0 = *(const uint4*)(rr + kb);
  uint4 nra1 = *(const uint4*)(rr + kb + 4);
  float4 nb0 = *(const float4*)(gbase);
  float4 nb1 = *(const float4*)(gbase + 8);
  f32x4 acc[4][4] = {};
  for (int kt = 0; kt < 288; kt += 32){
    uint4 oa0, oa1;
    oa0.x = cmulh(nxa0.x, nra0.x); oa0.y = cmulh(nxa0.y, nra0.y);
    oa0.z = cmulh(nxa0.z, nra0.z); oa0.w = cmulh(nxa0.w, nra0.w);
    oa1.x = cmulh(nxa1.x, nra1.x); oa1.y = cmulh(nxa1.y, nra1.y);
    oa1.z = cmulh(nxa1.z, nra1.z); oa1.w = cmulh(nxa1.w, nra1.w);
    float4 b0 = nb0, b1 = nb1;
    __syncthreads();
    *(uint4*)&Ash[sr*40 + h*16]      = oa0;
    *(uint4*)&Ash[sr*40 + h*16 + 8]  = oa1;
    *(float4*)&Bsh[sr*40 + h*16]     = b0;
    *(float4*)&Bsh[sr*40 + h*16 + 8] = b1;
    __syncthreads();
    int kt2 = kt + 32; if (kt2 > 256) kt2 = 256;
    int kb2 = (kt2 >> 1) + h*8;
    nxa0 = *(const uint4*)(xr + kb2);
    nxa1 = *(const uint4*)(xr + kb2 + 4);
    nra0 = *(const uint4*)(rr + kb2);
    nra1 = *(const uint4*)(rr + kb2 + 4);
    const _Float16* gb2 = gbase + kt2;
    nb0 = *(const float4*)(gb2);
    nb1 = *(const float4*)(gb2 + 8);
    f16x8 af[4], bf_[4];
    #pragma unroll
    for (int i = 0; i < 4; ++i) af[i]  = *(const f16x8*)&Ash[(wm + i*16 + fr)*40 + fk];
    #pragma unroll
    for (int j = 0; j < 4; ++j) bf_[j] = *(const f16x8*)&Bsh[(wn + j*16 + fr)*40 + fk];
    #pragma unroll
    for (int i = 0; i < 4; ++i)
      #pragma unroll
      for (int j = 0; j < 4; ++j)
        acc[i][j] = __builtin_amdgcn_mfma_f32_16x16x32_f16(af[i], bf_[j], acc[i][j], 0, 0, 0);
  }
  const int cr = (lane >> 4)*4;
  const int cc = lane & 15;
  #pragma unroll
  for (int i = 0; i < 4; ++i)
    #pragma unroll
    for (int j = 0; j < 4; ++j){
      int col = bn + wn + j*16 + cc;
      if (col < 288){
        #pragma unroll
        for (int r = 0; r < 4; ++r){
          size_t idx = (size_t)(bm + wm + i*16 + cr + r)*288 + col;
          Yhat[idx] = sat16(acc[i][j][r]);
        }
      }
    }
}

// ---- gather-aggregate via packed records, depth-2 pipeline; writes XCAT cols ----
__global__ __launch_bounds__(128) void k_agg(const char* __restrict__ Wb,
                                             const int* __restrict__ ptr,
                                             const int2* __restrict__ recs,
                                             int d, _Float16* __restrict__ XC){
  int node = blockIdx.x;
  int t = threadIdx.x;
  int gnode = d*NN + node;
  int beg = ptr[gnode], end = ptr[gnode+1];
  unsigned int* orow = (unsigned int*)(XC + (size_t)node*832 + 256 + d*288);
  if (end <= beg){
    orow[t] = 0;
    if (t < 16) orow[128 + t] = 0;
    return;
  }
  int last = end - 1;
  auto ld = [&](int idx, unsigned& va, unsigned& vb, float& ah, float& bh, float& cf){
    int ic = idx < last ? idx : last;
    int2 rc = recs[ic];
    int xrow = rc.x & 0xffff;
    int brow = ((rc.x >> 16) & 0xffff) | ((rc.y & 1) << 16);
    const char* xb = Wb + O_XHAT + (size_t)xrow*576;
    const char* bb = Wb + ((rc.y & 2) ? O_YH : O_XHAT) + (size_t)brow*576;
    va = ((const unsigned*)xb)[t]; vb = ((const unsigned*)bb)[t];
    ah = (float)((const _Float16*)xb)[256];
    bh = (float)((const _Float16*)bb)[256];
    HU cu; cu.u = ((unsigned)rc.y) >> 16;
    cf = (idx <= last) ? (float)cu.h[0] : 0.f;
  };
  float ax_ = 0.f, ay_ = 0.f, ex = 0.f;
  unsigned va0, vb0, va1, vb1; float ah0, bh0, ah1, bh1, cf0, cf1;
  ld(beg,     va0, vb0, ah0, bh0, cf0);
  ld(beg + 1, va1, vb1, ah1, bh1, cf1);
  for (int k = beg; k < end; k += 2){
    unsigned ta0, tb0, ta1, tb1; float th0, tg0, th1, tg1, tc0, tc1;
    ld(k + 2, ta0, tb0, th0, tg0, tc0);
    ld(k + 3, ta1, tb1, th1, tg1, tc1);
    {
      HU a, b; a.u = va0; b.u = vb0;
      float axv=(float)a.h[0], ayv=(float)a.h[1], bxv=(float)b.h[0], byv=(float)b.h[1];
      ax_ += cf0*(axv*bxv + ayv*byv);
      ay_ += cf0*(axv*byv - ayv*bxv);
      ex  += cf0*ah0*bh0;
    }
    {
      HU a, b; a.u = va1; b.u = vb1;
      float axv=(float)a.h[0], ayv=(float)a.h[1], bxv=(float)b.h[0], byv=(float)b.h[1];
      ax_ += cf1*(axv*bxv + ayv*byv);
      ay_ += cf1*(axv*byv - ayv*bxv);
      ex  += cf1*ah1*bh1;
    }
    va0=ta0; vb0=tb0; ah0=th0; bh0=tg0; cf0=tc0;
    va1=ta1; vb1=tb1; ah1=th1; bh1=tg1; cf1=tc1;
  }
  HU o; o.h[0] = sat16(ax_); o.h[1] = sat16(ay_);
  orow[t] = o.u;
  if (t < 16){
    HU o2; o2.h[0] = (t == 0) ? sat16(ex) : (_Float16)0.f; o2.h[1] = (_Float16)0.f;
    orow[128 + t] = o2.u;
  }
}

__global__ void k_bnstats(const _Float16* __restrict__ opre, float* __restrict__ bns){
  int col = threadIdx.x;
  int r0 = blockIdx.x*64, r1 = r0 + 64; if (r1 > NN) r1 = NN;
  float s1 = 0.f, s2 = 0.f;
  for (int r = r0; r < r1; ++r){
    float v = (float)opre[(size_t)r*256 + col];
    s1 += v; s2 += v*v;
  }
  atomAddF(&bns[col], s1);
  atomAddF(&bns[256 + col], s2);
}

__global__ void k_bnfinal(float* __restrict__ bns, const float* __restrict__ gamma,
                          const float* __restrict__ beta){
  int col = threadIdx.x;
  float mean = bns[col] * (1.f/NN);
  float var  = bns[256 + col] * (1.f/NN) - mean*mean;
  var = fmaxf(var, 0.f);
  // BN of (acc/3 + bias) == (acc-mean_acc)/sqrt(var_acc + 9*eps); bias cancels
  float g = gamma[col] * rsqrtf(var + 9e-5f);
  float b = beta[col] - mean*g;
  bns[512 + col] = sanit(g);
  bns[768 + col] = sanit(b);
}

// fused epilogue: blocks [0,6250) ent-BN-tanh ; [6250,6750) rel_out
__global__ void k_epi(const _Float16* __restrict__ opre, const float* __restrict__ bns,
                      const float* __restrict__ ral32, const float* __restrict__ w_rel,
                      float* __restrict__ out){
  int b = blockIdx.x;
  if (b < 6250){
    int t = b*256 + threadIdx.x;     // < NN*32 exactly
    f16x8 v = ((const f16x8*)opre)[t];
    int col = (t & 31)*8;
    float4 o0, o1;
    o0.x = sanit(tanhf((float)v[0]*bns[512+col+0] + bns[768+col+0]));
    o0.y = sanit(tanhf((float)v[1]*bns[512+col+1] + bns[768+col+1]));
    o0.z = sanit(tanhf((float)v[2]*bns[512+col+2] + bns[768+col+2]));
    o0.w = sanit(tanhf((float)v[3]*bns[512+col+3] + bns[768+col+3]));
    o1.x = sanit(tanhf((float)v[4]*bns[512+col+4] + bns[768+col+4]));
    o1.y = sanit(tanhf((float)v[5]*bns[512+col+5] + bns[768+col+5]));
    o1.z = sanit(tanhf((float)v[6]*bns[512+col+6] + bns[768+col+6]));
    o1.w = sanit(tanhf((float)v[7]*bns[512+col+7] + bns[768+col+7]));
    ((float4*)out)[(size_t)t*2]     = o0;
    ((float4*)out)[(size_t)t*2 + 1] = o1;
  } else {
    int r = b - 6250, n = threadIdx.x;
    float acc = 0.f;
    for (int k = 0; k < 256; ++k)
      acc += ral32[r*256 + k] * w_rel[k*256 + n];
    out[12800000 + r*256 + n] = sanit(acc);
  }
}

extern "C" void kernel_launch(void* const* d_in, const int* in_sizes, int n_in,
                              void* d_out, int out_size, void* d_ws, size_t ws_size,
                              hipStream_t stream){
  (void)in_sizes; (void)n_in;
  if (ws_size < WS_NEED){
    hipMemsetAsync(d_out, 0, (size_t)out_size*4, stream);
    return;
  }
  const float* x        = (const float*)d_in[0];
  const float* rel_emb  = (const float*)d_in[1];
  const float* w_in     = (const float*)d_in[2];
  const float* w_out_   = (const float*)d_in[3];
  const float* w_loop   = (const float*)d_in[4];
  const float* w_rel    = (const float*)d_in[5];
  const float* w_q      = (const float*)d_in[6];
  const float* loop_rel = (const float*)d_in[7];
  const float* gamma    = (const float*)d_in[9];
  const float* beta     = (const float*)d_in[10];
  const int* ei    = (const int*)d_in[11];
  const int* et    = (const int*)d_in[12];
  const int* quals = (const int*)d_in[13];
  float* out = (float*)d_out;
  char* W = (char*)d_ws;
  _Float16* XC    = (_Float16*)(W + O_XCAT);
  _Float16* Xhat  = (_Float16*)(W + O_XHAT);
  _Float16* Yhat  = (_Float16*)(W + O_YH);
  _Float16* opre  = (_Float16*)(W + O_YH);     // aliases Yhat (dead by then)
  _Float16* FR    = (_Float16*)(W + O_FR);
  _Float16* FI2   = (_Float16*)(W + O_FI2);
  _Float16* T1    = (_Float16*)(W + O_T1);
  _Float16* G     = (_Float16*)(W + O_G);
  _Float16* WB    = (_Float16*)(W + O_WB);
  _Float16* wqn   = (_Float16*)(W + O_WQN);
  _Float16* wint  = (_Float16*)(W + O_WINT);
  _Float16* woutt = (_Float16*)(W + O_WOUT);
  float*    ral32 = (float*)(W + O_RAL32);
  int*      deg   = (int*)(W + O_DEG);
  int*      cnt   = (int*)(W + O_CNT);
  float*    bns   = (float*)(W + O_BNS);
  float*    dinv  = (float*)(W + O_DINV);
  int*      ptr   = (int*)(W + O_PTR);
  int*      cur   = (int*)(W + O_CUR);
  int*      bsum  = (int*)(W + O_BSUM);
  int2*     recs  = (int2*)(W + O_RECS);
  _Float16* circ16= (_Float16*)(W + O_RECS);           // temp, dead before fillrec
  _Float16* wloopT= (_Float16*)(W + O_RECS + 131072);

  hipMemsetAsync(deg, 0, 800000, stream);   // deg + cnt (adjacent)
  hipMemsetAsync(bns, 0, 4096, stream);

  k_pro<<<12775, 256, 0, stream>>>(FR, FI2, w_in, w_out_, w_q, rel_emb, loop_rel, w_loop,
                                   wqn, wint, woutt, ral32, circ16, wloopT,
                                   x, XC, ei, quals, deg, cnt);
  // T1=FR@wqn^T ; WB[256:544]=FiWin ; WB[544:832]=FiWout ; WB[0:256]=BW
  k_setup<<<22, 256, 0, stream>>>(FR, wqn, T1, wint, woutt, FI2, WB, wloopT, circ16);
  // G = T1 @ FI2^T
  k_gemm<_Float16,false><<<dim3(3,3), 256, 0, stream>>>(T1, 256, FI2, 256, G, 288, 288, 256);
  k_dinv_scan1<<<391 + SCB, 256, 0, stream>>>(deg, dinv, cnt, bsum);
  k_scan2<<<1, 64, 0, stream>>>(bsum, ptr);
  k_scan3<<<SCB, 256, 0, stream>>>(cnt, bsum, ptr, cur);
  k_fillrec<<<3125, 256, 0, stream>>>(ei, et, quals, dinv, cur, recs);

  // [Xhat ; Rhat] = XCAT[:,0:256] @ FR^T  (rows 0..50559)
  k_gemm<_Float16,false><<<dim3(395,3), 256, 0, stream>>>(XC, 832, FR, 256, Xhat, 288, 288, 256);

  for (int d = 0; d < 2; ++d){
    k_qgemm<<<2352, 256, 0, stream>>>(Xhat, quals, d, G, Yhat);
    k_agg<<<NN, 128, 0, stream>>>(W, ptr, recs, d, XC);
  }

  // opre = XCAT @ WB^T   (K=832: self-loop + both directions in one GEMM)
  k_gemm<_Float16,false><<<dim3(391,2), 256, 0, stream>>>(XC, 832, WB, 832, opre, 256, 256, 832);

  k_bnstats<<<782, 256, 0, stream>>>(opre, bns);
  k_bnfinal<<<1, 256, 0, stream>>>(bns, gamma, beta);
  k_epi<<<6750, 256, 0, stream>>>(opre, bns, ral32, w_rel, out);
}

// Round 13
// 523.908 us; speedup vs baseline: 1.3523x; 1.0374x over previous
//
#include <hip/hip_runtime.h>

typedef __attribute__((ext_vector_type(8))) _Float16 f16x8;
typedef __attribute__((ext_vector_type(4))) float f32x4;

#define NN   50000
#define EE   300000
#define TWOE 600000
#define TWOQ 200000
#define SCB  98     // scan blocks of 1024 ints covering 2*NN=100000

// ---- workspace layout (bytes), total 181,457,600 (<= proven 184,089,664) ----
static constexpr size_t O_XCAT = 0;            // f16 [50560][832]: cols 0:256 x / ral16 rows 50048+, 256:544 AGG0, 544:832 AGG1
static constexpr size_t O_XHAT = 84131840;     // f16 [50560][288]: rows 0..50047 Xhat, 50048..50559 Rhat
static constexpr size_t O_YH   = 113254400;    // f16 [100096][288] Yhat (per-dir); later opre f16 [50048][256] aliases
static constexpr size_t O_FR   = 170909696;    // f16 [384,256]
static constexpr size_t O_FI2  = 171106304;    // f16 [384,256]
static constexpr size_t O_T1   = 171302912;    // f16 [384,256]
static constexpr size_t O_G    = 171499520;    // f16 [384,288]
static constexpr size_t O_WB   = 171720704;    // f16 [256,832]: [0:256]=BW, [256:544]=FiWin, [544:832]=FiWout
static constexpr size_t O_WQN  = 172146688;    // f16 [256,256]
static constexpr size_t O_WINT = 172277760;    // f16 [256,256]
static constexpr size_t O_WOUT = 172408832;    // f16 [256,256]
static constexpr size_t O_RAL32= 172539904;    // f32 [501,256]
static constexpr size_t O_CNTE = 173052928;    // int [2N]  (edge counts; also degree source, swapped)
static constexpr size_t O_CNTQ = 173452928;    // int [2N]  (qual counts; adjacent: one memset)
static constexpr size_t O_BNS  = 173852928;    // f32 [1024]
static constexpr size_t O_DINV = 173857024;    // f32 [2,N]
static constexpr size_t O_PTR  = 174257024;    // int [2N+1]
static constexpr size_t O_CUR  = 174657088;    // int [2N]
static constexpr size_t O_BSUM = 175057088;    // int [128]
static constexpr size_t O_RECS = 175057600;    // int2 [800000] = 6.4MB; temp circ16/wloopT alias
static constexpr size_t WS_NEED= 181457600;

__device__ __forceinline__ float sanit(float v){
  v = (v == v) ? v : 0.f;
  return fminf(60000.f, fmaxf(-60000.f, v));
}
__device__ __forceinline__ _Float16 sat16(float v){ return (_Float16)sanit(v); }
__device__ __forceinline__ int iclamp(int v, int lo, int hi){
  return v < lo ? lo : (v > hi ? hi : v);
}
__device__ __forceinline__ void atomAddF(float* p, float v){
  __hip_atomic_fetch_add(p, v, __ATOMIC_RELAXED, __HIP_MEMORY_SCOPE_AGENT);
}
union HU { unsigned int u; _Float16 h[2]; };

// native-f16 complex multiply (conj(a)*b)
__device__ __forceinline__ unsigned int cmulh(unsigned int ua, unsigned int ub){
  HU a, b, o; a.u = ua; b.u = ub;
  o.h[0] = a.h[0]*b.h[0] + a.h[1]*b.h[1];
  o.h[1] = a.h[0]*b.h[1] - a.h[1]*b.h[0];
  return o.u;
}

// ---- fused prologue ----
// [0,288) gen_dft | [288,800) misc+ral | [800,7050) cvt_x->XCAT
// [7050,10175) cntE/cntQ | [10175,10431) circ16/wloopT
__global__ void k_pro(_Float16* __restrict__ FR, _Float16* __restrict__ FI2,
                      const float* __restrict__ w_in, const float* __restrict__ w_out,
                      const float* __restrict__ w_q, const float* __restrict__ rel_embed,
                      const float* __restrict__ loop_rel, const float* __restrict__ w_loop,
                      _Float16* __restrict__ wqn, _Float16* __restrict__ wint,
                      _Float16* __restrict__ woutt,
                      float* __restrict__ ral32,
                      _Float16* __restrict__ circ16, _Float16* __restrict__ wloopT,
                      const float* __restrict__ x, _Float16* __restrict__ XC,
                      const int* __restrict__ ei, const int* __restrict__ quals,
                      int* __restrict__ cntE, int* __restrict__ cntQ){
  int b = blockIdx.x, tid = threadIdx.x;
  if (b < 288){
    int t = b*256 + tid;
    const float step = 0.024543692606170259f; // 2*pi/256
    {
      int f = t >> 8, tt = t & 255;
      float v = 0.f;
      if (f < 258){
        int m = f >> 1;
        float ang = (float)((tt*m) & 255) * step;
        v = (f & 1) ? -sinf(ang) : cosf(ang);
      }
      FR[t] = (_Float16)v;
    }
    {
      int k = t >> 8, j = t & 255;
      float v = 0.f;
      if (k < 258){
        int m = k >> 1;
        float w = (m==0 || m==128) ? (1.f/256.f) : (2.f/256.f);
        float ang = (float)((j*m) & 255) * step;
        v = (k & 1) ? -w*sinf(ang) : w*cosf(ang);
      }
      FI2[t] = (_Float16)v;
    }
  } else if (b < 800){
    int t = (b - 288)*256 + tid;   // < 131072
    if (t < 65536){
      int j = t >> 8, n = t & 255;
      wqn[t] = sat16(w_q[t]);
      wint[n*256 + j]  = sat16(w_in[t]);
      woutt[n*256 + j] = sat16(w_out[t]);
    }
    float rv = 0.f;
    if (t < 128000) rv = sanit(rel_embed[t]);
    else if (t < 128256) rv = sanit(loop_rel[t - 128000]);
    int row = t >> 8, c = t & 255;
    XC[(size_t)(50048 + row)*832 + c] = (_Float16)rv;   // ral16 rows (pad rows zero)
    if (t < 128256) ral32[t] = rv;
  } else if (b < 7050){
    int t = (b - 800)*256 + tid;   // < 1,600,000 exactly (50000 rows x 32 chunks)
    const float4* p = (const float4*)x + (size_t)t*2;
    float4 v0 = p[0], v1 = p[1];
    f16x8 o;
    o[0]=sat16(v0.x); o[1]=sat16(v0.y); o[2]=sat16(v0.z); o[3]=sat16(v0.w);
    o[4]=sat16(v1.x); o[5]=sat16(v1.y); o[6]=sat16(v1.z); o[7]=sat16(v1.w);
    int row = t >> 5, c8 = (t & 31)*8;
    *(f16x8*)(XC + (size_t)row*832 + c8) = o;
  } else if (b < 10175){
    int t = (b - 7050)*256 + tid;  // < 800,000 exactly
    if (t < TWOE){
      int d = (t >= EE) ? 1 : 0;
      atomicAdd(&cntE[d*NN + iclamp(ei[TWOE + t], 0, NN-1)], 1);
    } else {
      int qg = t - TWOE;
      int d = (qg >= 100000) ? 1 : 0;
      int e = iclamp(quals[2*TWOQ + qg], 0, EE-1);
      int j = d*EE + e;
      atomicAdd(&cntQ[d*NN + iclamp(ei[TWOE + j], 0, NN-1)], 1);
    }
  } else {
    int t = (b - 10175)*256 + tid; // < 65536 exactly
    int r = t >> 8, m = t & 255;
    circ16[t] = sat16(loop_rel[(r + m) & 255]);      // Circ16[j][m]
    wloopT[t] = sat16(w_loop[m*256 + r]);            // wloopT[n][m]
  }
}

// fused: blocks [0,391) dinv (degrees = swapped cntE) ; [391,489) scan1 (cntE+cntQ)
__global__ void k_dinv_scan1(const int* __restrict__ cntE, const int* __restrict__ cntQ,
                             float* __restrict__ dinv, int* __restrict__ bsum){
  int b = blockIdx.x, t = threadIdx.x;
  if (b < 391){
    int i = b*256 + t;
    if (i < 2*NN){
      // deg[0][n] = #{src=n} = cntE[1][n] ; deg[1][n] = #{dst=n} = cntE[0][n]
      int part = (i < NN) ? i + NN : i - NN;
      int c = cntE[part];
      dinv[i] = (c > 0) ? rsqrtf((float)c) : 0.f;
    }
  } else {
    __shared__ int sh[256];
    int blk = b - 391;
    int base = blk*1024 + t*4;
    int s = 0;
    #pragma unroll
    for (int i = 0; i < 4; ++i){
      int idx = base + i;
      if (idx < 2*NN) s += cntE[idx] + cntQ[idx];
    }
    sh[t] = s; __syncthreads();
    for (int off = 128; off > 0; off >>= 1){
      if (t < off) sh[t] += sh[t + off];
      __syncthreads();
    }
    if (t == 0) bsum[blk] = sh[0];
  }
}

// self-contained: prefix raw bsum in-block, then scatter ptr/cur
__global__ void k_scan3(const int* __restrict__ cntE, const int* __restrict__ cntQ,
                        const int* __restrict__ bsum,
                        int* __restrict__ ptr, int* __restrict__ cur){
  __shared__ int sh[256];
  __shared__ int bs[128];
  int b = blockIdx.x, t = threadIdx.x;
  int base = b*1024 + t*4;
  int v[4];
  int s = 0;
  #pragma unroll
  for (int i = 0; i < 4; ++i){
    int idx = base + i;
    v[i] = (idx < 2*NN) ? (cntE[idx] + cntQ[idx]) : 0;
    s += v[i];
  }
  sh[t] = s;
  if (t < 128) bs[t] = (t < SCB) ? bsum[t] : 0;
  __syncthreads();
  // inclusive Hillis-Steele over thread sums
  for (int off = 1; off < 256; off <<= 1){
    int add = (t >= off) ? sh[t - off] : 0;
    __syncthreads();
    sh[t] += add;
    __syncthreads();
  }
  // inclusive prefix over block sums (128-wide)
  for (int off = 1; off < 128; off <<= 1){
    int add = (t >= off && t < 128) ? bs[t - off] : 0;
    __syncthreads();
    if (t < 128) bs[t] += add;
    __syncthreads();
  }
  int blockoff = (b > 0) ? bs[b - 1] : 0;
  if (b == 0 && t == 0) ptr[2*NN] = bs[SCB - 1];
  int off0 = blockoff + sh[t] - s;
  #pragma unroll
  for (int i = 0; i < 4; ++i){
    int idx = base + i;
    if (idx < 2*NN){ ptr[idx] = off0; cur[idx] = off0; }
    off0 += v[i];
  }
}

// packed per-item records int2: x.lo16=xrow, x.hi16=brow.lo16;
// y: bit0=brow.bit16, bit1=isqual, bits31:16=coef f16
__global__ void k_fillrec(const int* __restrict__ ei, const int* __restrict__ et,
                          const int* __restrict__ quals, const float* __restrict__ dinv,
                          int* __restrict__ cursor, int2* __restrict__ recs){
  int t = blockIdx.x*256 + threadIdx.x;
  if (t >= TWOE + TWOQ) return;
  int d, j, brow, isq; float w;
  if (t < TWOE){
    d = (t >= EE) ? 1 : 0;
    j = t;
    brow = 50048 + iclamp(et[j], 0, 500);   // Rhat row within XHAT region
    isq = 0; w = 0.8f;
  } else {
    int qg = t - TWOE;
    d = (qg >= 100000) ? 1 : 0;
    int e = iclamp(quals[2*TWOQ + qg], 0, EE-1);
    j = d*EE + e;
    brow = qg - d*100000;                   // Yhat row (per-direction)
    isq = 1; w = 0.2f;
  }
  int src = iclamp(ei[j], 0, NN-1);
  int dst = iclamp(ei[TWOE + j], 0, NN-1);
  float coef = w * dinv[d*NN + src] * dinv[d*NN + dst];
  int pos = atomicAdd(&cursor[d*NN + dst], 1);
  pos = iclamp(pos, 0, 800000-1);
  HU cu; cu.h[0] = (_Float16)coef; cu.h[1] = (_Float16)0.f;
  int2 rc;
  rc.x = src | ((brow & 0xffff) << 16);
  rc.y = ((brow >> 16) & 1) | (isq << 1) | ((int)(cu.u & 0xffffu) << 16);
  recs[pos] = rc;
}

// ---- shared GEMM body: C[.,N](ldc) = A[.,K](lda) @ Bt[.,K](ldb)^T; UNGUARDED loads ----
template<typename OT, bool ACC>
__device__ __forceinline__ void gemm_body(const _Float16* __restrict__ A, int lda,
                                          const _Float16* __restrict__ Bt, int ldb,
                                          OT* __restrict__ C, int ldc,
                                          int N, int K, int bx, int by){
  __shared__ __align__(16) _Float16 Ash[128*40];
  __shared__ __align__(16) _Float16 Bsh[128*40];
  const int tid = threadIdx.x;
  const int lane = tid & 63;
  const int wv = tid >> 6;
  const int bm = bx*128, bn = by*128;
  const int wm = (wv >> 1)*64, wn = (wv & 1)*64;
  const int sr = tid >> 1;
  const int sc = (tid & 1)*16;
  const int fr = lane & 15;
  const int fk = (lane >> 4)*8;
  const _Float16* pa = A + (size_t)(bm+sr)*lda + sc;
  const _Float16* pb = Bt + (size_t)(bn+sr)*ldb + sc;
  f32x4 acc[4][4] = {};
  for (int kt = 0; kt < K; kt += 32){
    float4 a0 = *(const float4*)(pa);
    float4 a1 = *(const float4*)(pa + 8);
    float4 b0 = *(const float4*)(pb);
    float4 b1 = *(const float4*)(pb + 8);
    pa += 32; pb += 32;
    __syncthreads();
    *(float4*)&Ash[sr*40 + sc]     = a0;
    *(float4*)&Ash[sr*40 + sc + 8] = a1;
    *(float4*)&Bsh[sr*40 + sc]     = b0;
    *(float4*)&Bsh[sr*40 + sc + 8] = b1;
    __syncthreads();
    f16x8 af[4], bf_[4];
    #pragma unroll
    for (int i = 0; i < 4; ++i) af[i]  = *(const f16x8*)&Ash[(wm + i*16 + fr)*40 + fk];
    #pragma unroll
    for (int j = 0; j < 4; ++j) bf_[j] = *(const f16x8*)&Bsh[(wn + j*16 + fr)*40 + fk];
    #pragma unroll
    for (int i = 0; i < 4; ++i)
      #pragma unroll
      for (int j = 0; j < 4; ++j)
        acc[i][j] = __builtin_amdgcn_mfma_f32_16x16x32_f16(af[i], bf_[j], acc[i][j], 0, 0, 0);
  }
  const int cr = (lane >> 4)*4;
  const int cc = lane & 15;
  #pragma unroll
  for (int i = 0; i < 4; ++i)
    #pragma unroll
    for (int j = 0; j < 4; ++j){
      int col = bn + wn + j*16 + cc;
      if (col < N){
        #pragma unroll
        for (int r = 0; r < 4; ++r){
          size_t idx = (size_t)(bm + wm + i*16 + cr + r)*ldc + col;
          float v = acc[i][j][r];
          if (ACC) v += (float)C[idx];
          C[idx] = (OT)sanit(v);
        }
      }
    }
}

template<typename OT, bool ACC>
__global__ __launch_bounds__(256) void k_gemm(const _Float16* __restrict__ A, int lda,
                                              const _Float16* __restrict__ Bt, int ldb,
                                              OT* __restrict__ C, int ldc,
                                              int N, int K){
  gemm_body<OT,ACC>(A, lda, Bt, ldb, C, ldc, N, K, blockIdx.x, blockIdx.y);
}

// batch of 4 independent small setup GEMMs (22 blocks total)
__global__ __launch_bounds__(256) void k_setup(const _Float16* __restrict__ FR,
                                               const _Float16* __restrict__ wqn,
                                               _Float16* __restrict__ T1,
                                               const _Float16* __restrict__ wint,
                                               const _Float16* __restrict__ woutt,
                                               const _Float16* __restrict__ FI2,
                                               _Float16* __restrict__ WB,
                                               const _Float16* __restrict__ wloopT,
                                               const _Float16* __restrict__ circ16){
  int b = blockIdx.x;
  if (b < 6)       gemm_body<_Float16,false>(FR, 256, wqn, 256, T1, 256, 256, 256, b % 3, b / 3);
  else if (b < 12){ int i = b - 6;  gemm_body<_Float16,false>(wint, 256, FI2, 256, WB + 256, 832, 288, 256, i % 2, i / 2); }
  else if (b < 18){ int i = b - 12; gemm_body<_Float16,false>(woutt, 256, FI2, 256, WB + 544, 832, 288, 256, i % 2, i / 2); }
  else            { int i = b - 18; gemm_body<_Float16,false>(wloopT, 256, circ16, 256, WB, 832, 256, 256, i % 2, i / 2); }
}

// Fused qual GEMM, XCD-triple swizzled (grid 2352, 1-D):
// Yhat[q] = (conj(Xhat[ent_q]) .* Rhat[rel_q]) @ G^T
__global__ __launch_bounds__(256) void k_qgemm(const _Float16* __restrict__ Xhat,
                                               const int* __restrict__ quals, int d,
                                               const _Float16* __restrict__ G,
                                               _Float16* __restrict__ Yhat){
  int L = blockIdx.x;
  int xcd = L & 7, w = L >> 3;
  int t3 = (w / 3)*8 + xcd;          // row-block (triple) id: 3 col-tiles share XCD
  if (t3 >= 782) return;
  int bn = (w % 3)*128;
  int bm = t3*128;
  __shared__ __align__(16) _Float16 Ash[128*40];
  __shared__ __align__(16) _Float16 Bsh[128*40];
  const int tid = threadIdx.x;
  const int lane = tid & 63;
  const int wv = tid >> 6;
  const int wm = (wv >> 1)*64, wn = (wv & 1)*64;
  const int sr = tid >> 1;
  const int h  = tid & 1;
  const int fr = lane & 15;
  const int fk = (lane >> 4)*8;
  int q = bm + sr; if (q > 99999) q = 99999;
  int qi = d*100000 + q;
  int rel = iclamp(quals[qi], 0, 500);
  int ent = iclamp(quals[TWOQ + qi], 0, NN-1);
  const unsigned int* xr = (const unsigned int*)(Xhat + (size_t)ent*288);
  const unsigned int* rr = (const unsigned int*)(Xhat + (size_t)(50048 + rel)*288);
  const _Float16* gbase = G + (size_t)(bn+sr)*288 + h*16;
  int kb = h*8;
  uint4 nxa0 = *(const uint4*)(xr + kb);
  uint4 nxa1 = *(const uint4*)(xr + kb + 4);
  uint4 nra0 = *(const uint4*)(rr + kb);
  uint4 nra1 = *(const uint4*)(rr + kb + 4);
  float4 nb0 = *(const float4*)(gbase);
  float4 nb1 = *(const float4*)(gbase + 8);
  f32x4 acc[4][4] = {};
  for (int kt = 0; kt < 288; kt += 32){
    uint4 oa0, oa1;
    oa0.x = cmulh(nxa0.x, nra0.x); oa0.y = cmulh(nxa0.y, nra0.y);
    oa0.z = cmulh(nxa0.z, nra0.z); oa0.w = cmulh(nxa0.w, nra0.w);
    oa1.x = cmulh(nxa1.x, nra1.x); oa1.y = cmulh(nxa1.y, nra1.y);
    oa1.z = cmulh(nxa1.z, nra1.z); oa1.w = cmulh(nxa1.w, nra1.w);
    float4 b0 = nb0, b1 = nb1;
    __syncthreads();
    *(uint4*)&Ash[sr*40 + h*16]      = oa0;
    *(uint4*)&Ash[sr*40 + h*16 + 8]  = oa1;
    *(float4*)&Bsh[sr*40 + h*16]     = b0;
    *(float4*)&Bsh[sr*40 + h*16 + 8] = b1;
    __syncthreads();
    int kt2 = kt + 32; if (kt2 > 256) kt2 = 256;
    int kb2 = (kt2 >> 1) + h*8;
    nxa0 = *(const uint4*)(xr + kb2);
    nxa1 = *(const uint4*)(xr + kb2 + 4);
    nra0 = *(const uint4*)(rr + kb2);
    nra1 = *(const uint4*)(rr + kb2 + 4);
    const _Float16* gb2 = gbase + kt2;
    nb0 = *(const float4*)(gb2);
    nb1 = *(const float4*)(gb2 + 8);
    f16x8 af[4], bf_[4];
    #pragma unroll
    for (int i = 0; i < 4; ++i) af[i]  = *(const f16x8*)&Ash[(wm + i*16 + fr)*40 + fk];
    #pragma unroll
    for (int j = 0; j < 4; ++j) bf_[j] = *(const f16x8*)&Bsh[(wn + j*16 + fr)*40 + fk];
    #pragma unroll
    for (int i = 0; i < 4; ++i)
      #pragma unroll
      for (int j = 0; j < 4; ++j)
        acc[i][j] = __builtin_amdgcn_mfma_f32_16x16x32_f16(af[i], bf_[j], acc[i][j], 0, 0, 0);
  }
  const int cr = (lane >> 4)*4;
  const int cc = lane & 15;
  #pragma unroll
  for (int i = 0; i < 4; ++i)
    #pragma unroll
    for (int j = 0; j < 4; ++j){
      int col = bn + wn + j*16 + cc;
      if (col < 288){
        #pragma unroll
        for (int r = 0; r < 4; ++r){
          size_t idx = (size_t)(bm + wm + i*16 + cr + r)*288 + col;
          Yhat[idx] = sat16(acc[i][j][r]);
        }
      }
    }
}

// ---- gather-aggregate via packed records, depth-2 pipeline; writes XCAT cols ----
__global__ __launch_bounds__(128) void k_agg(const char* __restrict__ Wb,
                                             const int* __restrict__ ptr,
                                             const int2* __restrict__ recs,
                                             int d, _Float16* __restrict__ XC){
  int node = blockIdx.x;
  int t = threadIdx.x;
  int gnode = d*NN + node;
  int beg = ptr[gnode], end = ptr[gnode+1];
  unsigned int* orow = (unsigned int*)(XC + (size_t)node*832 + 256 + d*288);
  if (end <= beg){
    orow[t] = 0;
    if (t < 16) orow[128 + t] = 0;
    return;
  }
  int last = end - 1;
  auto ld = [&](int idx, unsigned& va, unsigned& vb, float& ah, float& bh, float& cf){
    int ic = idx < last ? idx : last;
    int2 rc = recs[ic];
    int xrow = rc.x & 0xffff;
    int brow = ((rc.x >> 16) & 0xffff) | ((rc.y & 1) << 16);
    const char* xb = Wb + O_XHAT + (size_t)xrow*576;
    const char* bb = Wb + ((rc.y & 2) ? O_YH : O_XHAT) + (size_t)brow*576;
    va = ((const unsigned*)xb)[t]; vb = ((const unsigned*)bb)[t];
    ah = (float)((const _Float16*)xb)[256];
    bh = (float)((const _Float16*)bb)[256];
    HU cu; cu.u = ((unsigned)rc.y) >> 16;
    cf = (idx <= last) ? (float)cu.h[0] : 0.f;
  };
  float ax_ = 0.f, ay_ = 0.f, ex = 0.f;
  unsigned va0, vb0, va1, vb1; float ah0, bh0, ah1, bh1, cf0, cf1;
  ld(beg,     va0, vb0, ah0, bh0, cf0);
  ld(beg + 1, va1, vb1, ah1, bh1, cf1);
  for (int k = beg; k < end; k += 2){
    unsigned ta0, tb0, ta1, tb1; float th0, tg0, th1, tg1, tc0, tc1;
    ld(k + 2, ta0, tb0, th0, tg0, tc0);
    ld(k + 3, ta1, tb1, th1, tg1, tc1);
    {
      HU a, b; a.u = va0; b.u = vb0;
      float axv=(float)a.h[0], ayv=(float)a.h[1], bxv=(float)b.h[0], byv=(float)b.h[1];
      ax_ += cf0*(axv*bxv + ayv*byv);
      ay_ += cf0*(axv*byv - ayv*bxv);
      ex  += cf0*ah0*bh0;
    }
    {
      HU a, b; a.u = va1; b.u = vb1;
      float axv=(float)a.h[0], ayv=(float)a.h[1], bxv=(float)b.h[0], byv=(float)b.h[1];
      ax_ += cf1*(axv*bxv + ayv*byv);
      ay_ += cf1*(axv*byv - ayv*bxv);
      ex  += cf1*ah1*bh1;
    }
    va0=ta0; vb0=tb0; ah0=th0; bh0=tg0; cf0=tc0;
    va1=ta1; vb1=tb1; ah1=th1; bh1=tg1; cf1=tc1;
  }
  HU o; o.h[0] = sat16(ax_); o.h[1] = sat16(ay_);
  orow[t] = o.u;
  if (t < 16){
    HU o2; o2.h[0] = (t == 0) ? sat16(ex) : (_Float16)0.f; o2.h[1] = (_Float16)0.f;
    orow[128 + t] = o2.u;
  }
}

__global__ void k_bnstats(const _Float16* __restrict__ opre, float* __restrict__ bns){
  int col = threadIdx.x;
  int r0 = blockIdx.x*64, r1 = r0 + 64; if (r1 > NN) r1 = NN;
  float s1 = 0.f, s2 = 0.f;
  for (int r = r0; r < r1; ++r){
    float v = (float)opre[(size_t)r*256 + col];
    s1 += v; s2 += v*v;
  }
  atomAddF(&bns[col], s1);
  atomAddF(&bns[256 + col], s2);
}

__global__ void k_bnfinal(float* __restrict__ bns, const float* __restrict__ gamma,
                          const float* __restrict__ beta){
  int col = threadIdx.x;
  float mean = bns[col] * (1.f/NN);
  float var  = bns[256 + col] * (1.f/NN) - mean*mean;
  var = fmaxf(var, 0.f);
  // BN of (acc/3 + bias) == (acc-mean_acc)/sqrt(var_acc + 9*eps); bias cancels
  float g = gamma[col] * rsqrtf(var + 9e-5f);
  float b = beta[col] - mean*g;
  bns[512 + col] = sanit(g);
  bns[768 + col] = sanit(b);
}

// fused epilogue: blocks [0,6250) ent-BN-tanh ; [6250,6750) rel_out
__global__ void k_epi(const _Float16* __restrict__ opre, const float* __restrict__ bns,
                      const float* __restrict__ ral32, const float* __restrict__ w_rel,
                      float* __restrict__ out){
  int b = blockIdx.x;
  if (b < 6250){
    int t = b*256 + threadIdx.x;     // < NN*32 exactly
    f16x8 v = ((const f16x8*)opre)[t];
    int col = (t & 31)*8;
    float4 o0, o1;
    o0.x = sanit(tanhf((float)v[0]*bns[512+col+0] + bns[768+col+0]));
    o0.y = sanit(tanhf((float)v[1]*bns[512+col+1] + bns[768+col+1]));
    o0.z = sanit(tanhf((float)v[2]*bns[512+col+2] + bns[768+col+2]));
    o0.w = sanit(tanhf((float)v[3]*bns[512+col+3] + bns[768+col+3]));
    o1.x = sanit(tanhf((float)v[4]*bns[512+col+4] + bns[768+col+4]));
    o1.y = sanit(tanhf((float)v[5]*bns[512+col+5] + bns[768+col+5]));
    o1.z = sanit(tanhf((float)v[6]*bns[512+col+6] + bns[768+col+6]));
    o1.w = sanit(tanhf((float)v[7]*bns[512+col+7] + bns[768+col+7]));
    ((float4*)out)[(size_t)t*2]     = o0;
    ((float4*)out)[(size_t)t*2 + 1] = o1;
  } else {
    int r = b - 6250, n = threadIdx.x;
    float acc = 0.f;
    for (int k = 0; k < 256; ++k)
      acc += ral32[r*256 + k] * w_rel[k*256 + n];
    out[12800000 + r*256 + n] = sanit(acc);
  }
}

extern "C" void kernel_launch(void* const* d_in, const int* in_sizes, int n_in,
                              void* d_out, int out_size, void* d_ws, size_t ws_size,
                              hipStream_t stream){
  (void)in_sizes; (void)n_in;
  if (ws_size < WS_NEED){
    hipMemsetAsync(d_out, 0, (size_t)out_size*4, stream);
    return;
  }
  const float* x        = (const float*)d_in[0];
  const float* rel_emb  = (const float*)d_in[1];
  const float* w_in     = (const float*)d_in[2];
  const float* w_out_   = (const float*)d_in[3];
  const float* w_loop   = (const float*)d_in[4];
  const float* w_rel    = (const float*)d_in[5];
  const float* w_q      = (const float*)d_in[6];
  const float* loop_rel = (const float*)d_in[7];
  const float* gamma    = (const float*)d_in[9];
  const float* beta     = (const float*)d_in[10];
  const int* ei    = (const int*)d_in[11];
  const int* et    = (const int*)d_in[12];
  const int* quals = (const int*)d_in[13];
  float* out = (float*)d_out;
  char* W = (char*)d_ws;
  _Float16* XC    = (_Float16*)(W + O_XCAT);
  _Float16* Xhat  = (_Float16*)(W + O_XHAT);
  _Float16* Yhat  = (_Float16*)(W + O_YH);
  _Float16* opre  = (_Float16*)(W + O_YH);     // aliases Yhat (dead by then)
  _Float16* FR    = (_Float16*)(W + O_FR);
  _Float16* FI2   = (_Float16*)(W + O_FI2);
  _Float16* T1    = (_Float16*)(W + O_T1);
  _Float16* G     = (_Float16*)(W + O_G);
  _Float16* WB    = (_Float16*)(W + O_WB);
  _Float16* wqn   = (_Float16*)(W + O_WQN);
  _Float16* wint  = (_Float16*)(W + O_WINT);
  _Float16* woutt = (_Float16*)(W + O_WOUT);
  float*    ral32 = (float*)(W + O_RAL32);
  int*      cntE  = (int*)(W + O_CNTE);
  int*      cntQ  = (int*)(W + O_CNTQ);
  float*    bns   = (float*)(W + O_BNS);
  float*    dinv  = (float*)(W + O_DINV);
  int*      ptr   = (int*)(W + O_PTR);
  int*      cur   = (int*)(W + O_CUR);
  int*      bsum  = (int*)(W + O_BSUM);
  int2*     recs  = (int2*)(W + O_RECS);
  _Float16* circ16= (_Float16*)(W + O_RECS);           // temp, dead before fillrec
  _Float16* wloopT= (_Float16*)(W + O_RECS + 131072);

  hipMemsetAsync(cntE, 0, 800000, stream);   // cntE + cntQ (adjacent)
  hipMemsetAsync(bns, 0, 4096, stream);

  k_pro<<<10431, 256, 0, stream>>>(FR, FI2, w_in, w_out_, w_q, rel_emb, loop_rel, w_loop,
                                   wqn, wint, woutt, ral32, circ16, wloopT,
                                   x, XC, ei, quals, cntE, cntQ);
  // T1=FR@wqn^T ; WB[256:544]=FiWin ; WB[544:832]=FiWout ; WB[0:256]=BW
  k_setup<<<22, 256, 0, stream>>>(FR, wqn, T1, wint, woutt, FI2, WB, wloopT, circ16);
  // G = T1 @ FI2^T
  k_gemm<_Float16,false><<<dim3(3,3), 256, 0, stream>>>(T1, 256, FI2, 256, G, 288, 288, 256);
  k_dinv_scan1<<<391 + SCB, 256, 0, stream>>>(cntE, cntQ, dinv, bsum);
  k_scan3<<<SCB, 256, 0, stream>>>(cntE, cntQ, bsum, ptr, cur);
  k_fillrec<<<3125, 256, 0, stream>>>(ei, et, quals, dinv, cur, recs);

  // [Xhat ; Rhat] = XCAT[:,0:256] @ FR^T  (rows 0..50559)
  k_gemm<_Float16,false><<<dim3(395,3), 256, 0, stream>>>(XC, 832, FR, 256, Xhat, 288, 288, 256);

  for (int d = 0; d < 2; ++d){
    k_qgemm<<<2352, 256, 0, stream>>>(Xhat, quals, d, G, Yhat);
    k_agg<<<NN, 128, 0, stream>>>(W, ptr, recs, d, XC);
  }

  // opre = XCAT @ WB^T   (K=832: self-loop + both directions in one GEMM)
  k_gemm<_Float16,false><<<dim3(391,2), 256, 0, stream>>>(XC, 832, WB, 832, opre, 256, 256, 832);

  k_bnstats<<<782, 256, 0, stream>>>(opre, bns);
  k_bnfinal<<<1, 256, 0, stream>>>(bns, gamma, beta);
  k_epi<<<6750, 256, 0, stream>>>(opre, bns, ral32, w_rel, out);
}

// Round 14
// 482.389 us; speedup vs baseline: 1.4687x; 1.0861x over previous
//
#include <hip/hip_runtime.h>

typedef __attribute__((ext_vector_type(8))) _Float16 f16x8;
typedef __attribute__((ext_vector_type(4))) float f32x4;

#define NN   50000
#define EE   300000
#define TWOE 600000
#define TWOQ 200000
#define SCB  98     // scan blocks of 1024 ints covering 2*NN=100000

// ---- workspace layout (bytes), total 181,457,600 (<= proven 184,089,664) ----
static constexpr size_t O_XCAT = 0;            // f16 [50560][832]: cols 0:256 x / ral16 rows 50048+, 256:544 AGG0, 544:832 AGG1
static constexpr size_t O_XHAT = 84131840;     // f16 [50560][288]: rows 0..50047 Xhat, 50048..50559 Rhat
static constexpr size_t O_YH   = 113254400;    // f16 [100096][288] Yhat (per-dir); later opre f16 [50048][256] aliases
static constexpr size_t O_FR   = 170909696;    // f16 [384,256]
static constexpr size_t O_FI2  = 171106304;    // f16 [384,256]
static constexpr size_t O_T1   = 171302912;    // f16 [384,256]
static constexpr size_t O_G    = 171499520;    // f16 [384,288]
static constexpr size_t O_WB   = 171720704;    // f16 [256,832]: [0:256]=BW, [256:544]=FiWin, [544:832]=FiWout
static constexpr size_t O_WQN  = 172146688;    // f16 [256,256]
static constexpr size_t O_WINT = 172277760;    // f16 [256,256]
static constexpr size_t O_WOUT = 172408832;    // f16 [256,256]
static constexpr size_t O_RAL32= 172539904;    // f32 [501,256]
static constexpr size_t O_CNTE = 173052928;    // int [2N]  (edge counts; also degree source, swapped)
static constexpr size_t O_CNTQ = 173452928;    // int [2N]  (qual counts; adjacent: one memset)
static constexpr size_t O_BNS  = 173852928;    // f32 [1024]
static constexpr size_t O_DINV = 173857024;    // f32 [2,N]
static constexpr size_t O_PTR  = 174257024;    // int [2N+1]
static constexpr size_t O_CUR  = 174657088;    // int [2N]
static constexpr size_t O_BSUM = 175057088;    // int [128]
static constexpr size_t O_RECS = 175057600;    // int2 [800000] = 6.4MB; temp circ16/wloopT alias
static constexpr size_t WS_NEED= 181457600;

__device__ __forceinline__ float sanit(float v){
  v = (v == v) ? v : 0.f;
  return fminf(60000.f, fmaxf(-60000.f, v));
}
__device__ __forceinline__ _Float16 sat16(float v){ return (_Float16)sanit(v); }
__device__ __forceinline__ int iclamp(int v, int lo, int hi){
  return v < lo ? lo : (v > hi ? hi : v);
}
__device__ __forceinline__ void atomAddF(float* p, float v){
  __hip_atomic_fetch_add(p, v, __ATOMIC_RELAXED, __HIP_MEMORY_SCOPE_AGENT);
}
union HU { unsigned int u; _Float16 h[2]; };

// fast branchless tanh: (e^2x - 1)/(e^2x + 1), clamped; err <= ~1e-4
__device__ __forceinline__ float ftanh(float x){
  float e2 = __expf(fminf(fmaxf(2.f*x, -20.f), 20.f));
  return (e2 - 1.f) * __builtin_amdgcn_rcpf(e2 + 1.f);
}

// native-f16 complex multiply (conj(a)*b)
__device__ __forceinline__ unsigned int cmulh(unsigned int ua, unsigned int ub){
  HU a, b, o; a.u = ua; b.u = ub;
  o.h[0] = a.h[0]*b.h[0] + a.h[1]*b.h[1];
  o.h[1] = a.h[0]*b.h[1] - a.h[1]*b.h[0];
  return o.u;
}

// ---- fused prologue ----
// [0,288) gen_dft | [288,800) misc+ral | [800,7050) cvt_x->XCAT
// [7050,10175) cntE/cntQ | [10175,10431) circ16/wloopT
__global__ void k_pro(_Float16* __restrict__ FR, _Float16* __restrict__ FI2,
                      const float* __restrict__ w_in, const float* __restrict__ w_out,
                      const float* __restrict__ w_q, const float* __restrict__ rel_embed,
                      const float* __restrict__ loop_rel, const float* __restrict__ w_loop,
                      _Float16* __restrict__ wqn, _Float16* __restrict__ wint,
                      _Float16* __restrict__ woutt,
                      float* __restrict__ ral32,
                      _Float16* __restrict__ circ16, _Float16* __restrict__ wloopT,
                      const float* __restrict__ x, _Float16* __restrict__ XC,
                      const int* __restrict__ ei, const int* __restrict__ quals,
                      int* __restrict__ cntE, int* __restrict__ cntQ){
  int b = blockIdx.x, tid = threadIdx.x;
  if (b < 288){
    int t = b*256 + tid;
    const float step = 0.024543692606170259f; // 2*pi/256
    {
      int f = t >> 8, tt = t & 255;
      float v = 0.f;
      if (f < 258){
        int m = f >> 1;
        float ang = (float)((tt*m) & 255) * step;
        v = (f & 1) ? -sinf(ang) : cosf(ang);
      }
      FR[t] = (_Float16)v;
    }
    {
      int k = t >> 8, j = t & 255;
      float v = 0.f;
      if (k < 258){
        int m = k >> 1;
        float w = (m==0 || m==128) ? (1.f/256.f) : (2.f/256.f);
        float ang = (float)((j*m) & 255) * step;
        v = (k & 1) ? -w*sinf(ang) : w*cosf(ang);
      }
      FI2[t] = (_Float16)v;
    }
  } else if (b < 800){
    int t = (b - 288)*256 + tid;   // < 131072
    if (t < 65536){
      int j = t >> 8, n = t & 255;
      wqn[t] = sat16(w_q[t]);
      wint[n*256 + j]  = sat16(w_in[t]);
      woutt[n*256 + j] = sat16(w_out[t]);
    }
    float rv = 0.f;
    if (t < 128000) rv = sanit(rel_embed[t]);
    else if (t < 128256) rv = sanit(loop_rel[t - 128000]);
    int row = t >> 8, c = t & 255;
    XC[(size_t)(50048 + row)*832 + c] = (_Float16)rv;   // ral16 rows (pad rows zero)
    if (t < 128256) ral32[t] = rv;
  } else if (b < 7050){
    int t = (b - 800)*256 + tid;   // < 1,600,000 exactly (50000 rows x 32 chunks)
    const float4* p = (const float4*)x + (size_t)t*2;
    float4 v0 = p[0], v1 = p[1];
    f16x8 o;
    o[0]=sat16(v0.x); o[1]=sat16(v0.y); o[2]=sat16(v0.z); o[3]=sat16(v0.w);
    o[4]=sat16(v1.x); o[5]=sat16(v1.y); o[6]=sat16(v1.z); o[7]=sat16(v1.w);
    int row = t >> 5, c8 = (t & 31)*8;
    *(f16x8*)(XC + (size_t)row*832 + c8) = o;
  } else if (b < 10175){
    int t = (b - 7050)*256 + tid;  // < 800,000 exactly
    if (t < TWOE){
      int d = (t >= EE) ? 1 : 0;
      atomicAdd(&cntE[d*NN + iclamp(ei[TWOE + t], 0, NN-1)], 1);
    } else {
      int qg = t - TWOE;
      int d = (qg >= 100000) ? 1 : 0;
      int e = iclamp(quals[2*TWOQ + qg], 0, EE-1);
      int j = d*EE + e;
      atomicAdd(&cntQ[d*NN + iclamp(ei[TWOE + j], 0, NN-1)], 1);
    }
  } else {
    int t = (b - 10175)*256 + tid; // < 65536 exactly
    int r = t >> 8, m = t & 255;
    circ16[t] = sat16(loop_rel[(r + m) & 255]);      // Circ16[j][m]
    wloopT[t] = sat16(w_loop[m*256 + r]);            // wloopT[n][m]
  }
}

// fused: blocks [0,391) dinv (degrees = swapped cntE) ; [391,489) scan1 (cntE+cntQ)
__global__ void k_dinv_scan1(const int* __restrict__ cntE, const int* __restrict__ cntQ,
                             float* __restrict__ dinv, int* __restrict__ bsum){
  int b = blockIdx.x, t = threadIdx.x;
  if (b < 391){
    int i = b*256 + t;
    if (i < 2*NN){
      // deg[0][n] = #{src=n} = cntE[1][n] ; deg[1][n] = #{dst=n} = cntE[0][n]
      int part = (i < NN) ? i + NN : i - NN;
      int c = cntE[part];
      dinv[i] = (c > 0) ? rsqrtf((float)c) : 0.f;
    }
  } else {
    __shared__ int sh[256];
    int blk = b - 391;
    int base = blk*1024 + t*4;
    int s = 0;
    #pragma unroll
    for (int i = 0; i < 4; ++i){
      int idx = base + i;
      if (idx < 2*NN) s += cntE[idx] + cntQ[idx];
    }
    sh[t] = s; __syncthreads();
    for (int off = 128; off > 0; off >>= 1){
      if (t < off) sh[t] += sh[t + off];
      __syncthreads();
    }
    if (t == 0) bsum[blk] = sh[0];
  }
}

// self-contained: prefix raw bsum in-block, then scatter ptr/cur
__global__ void k_scan3(const int* __restrict__ cntE, const int* __restrict__ cntQ,
                        const int* __restrict__ bsum,
                        int* __restrict__ ptr, int* __restrict__ cur){
  __shared__ int sh[256];
  __shared__ int bs[128];
  int b = blockIdx.x, t = threadIdx.x;
  int base = b*1024 + t*4;
  int v[4];
  int s = 0;
  #pragma unroll
  for (int i = 0; i < 4; ++i){
    int idx = base + i;
    v[i] = (idx < 2*NN) ? (cntE[idx] + cntQ[idx]) : 0;
    s += v[i];
  }
  sh[t] = s;
  if (t < 128) bs[t] = (t < SCB) ? bsum[t] : 0;
  __syncthreads();
  // inclusive Hillis-Steele over thread sums
  for (int off = 1; off < 256; off <<= 1){
    int add = (t >= off) ? sh[t - off] : 0;
    __syncthreads();
    sh[t] += add;
    __syncthreads();
  }
  // inclusive prefix over block sums (128-wide)
  for (int off = 1; off < 128; off <<= 1){
    int add = (t >= off && t < 128) ? bs[t - off] : 0;
    __syncthreads();
    if (t < 128) bs[t] += add;
    __syncthreads();
  }
  int blockoff = (b > 0) ? bs[b - 1] : 0;
  if (b == 0 && t == 0) ptr[2*NN] = bs[SCB - 1];
  int off0 = blockoff + sh[t] - s;
  #pragma unroll
  for (int i = 0; i < 4; ++i){
    int idx = base + i;
    if (idx < 2*NN){ ptr[idx] = off0; cur[idx] = off0; }
    off0 += v[i];
  }
}

// packed per-item records int2: x.lo16=xrow, x.hi16=brow.lo16;
// y: bit0=brow.bit16, bit1=isqual, bits31:16=coef f16
__global__ void k_fillrec(const int* __restrict__ ei, const int* __restrict__ et,
                          const int* __restrict__ quals, const float* __restrict__ dinv,
                          int* __restrict__ cursor, int2* __restrict__ recs){
  int t = blockIdx.x*256 + threadIdx.x;
  if (t >= TWOE + TWOQ) return;
  int d, j, brow, isq; float w;
  if (t < TWOE){
    d = (t >= EE) ? 1 : 0;
    j = t;
    brow = 50048 + iclamp(et[j], 0, 500);   // Rhat row within XHAT region
    isq = 0; w = 0.8f;
  } else {
    int qg = t - TWOE;
    d = (qg >= 100000) ? 1 : 0;
    int e = iclamp(quals[2*TWOQ + qg], 0, EE-1);
    j = d*EE + e;
    brow = qg - d*100000;                   // Yhat row (per-direction)
    isq = 1; w = 0.2f;
  }
  int src = iclamp(ei[j], 0, NN-1);
  int dst = iclamp(ei[TWOE + j], 0, NN-1);
  float coef = w * dinv[d*NN + src] * dinv[d*NN + dst];
  int pos = atomicAdd(&cursor[d*NN + dst], 1);
  pos = iclamp(pos, 0, 800000-1);
  HU cu; cu.h[0] = (_Float16)coef; cu.h[1] = (_Float16)0.f;
  int2 rc;
  rc.x = src | ((brow & 0xffff) << 16);
  rc.y = ((brow >> 16) & 1) | (isq << 1) | ((int)(cu.u & 0xffffu) << 16);
  recs[pos] = rc;
}

// ---- shared GEMM body: C[.,N](ldc) = A[.,K](lda) @ Bt[.,K](ldb)^T; UNGUARDED loads ----
template<typename OT, bool ACC>
__device__ __forceinline__ void gemm_body(const _Float16* __restrict__ A, int lda,
                                          const _Float16* __restrict__ Bt, int ldb,
                                          OT* __restrict__ C, int ldc,
                                          int N, int K, int bx, int by){
  __shared__ __align__(16) _Float16 Ash[128*40];
  __shared__ __align__(16) _Float16 Bsh[128*40];
  const int tid = threadIdx.x;
  const int lane = tid & 63;
  const int wv = tid >> 6;
  const int bm = bx*128, bn = by*128;
  const int wm = (wv >> 1)*64, wn = (wv & 1)*64;
  const int sr = tid >> 1;
  const int sc = (tid & 1)*16;
  const int fr = lane & 15;
  const int fk = (lane >> 4)*8;
  const _Float16* pa = A + (size_t)(bm+sr)*lda + sc;
  const _Float16* pb = Bt + (size_t)(bn+sr)*ldb + sc;
  f32x4 acc[4][4] = {};
  for (int kt = 0; kt < K; kt += 32){
    float4 a0 = *(const float4*)(pa);
    float4 a1 = *(const float4*)(pa + 8);
    float4 b0 = *(const float4*)(pb);
    float4 b1 = *(const float4*)(pb + 8);
    pa += 32; pb += 32;
    __syncthreads();
    *(float4*)&Ash[sr*40 + sc]     = a0;
    *(float4*)&Ash[sr*40 + sc + 8] = a1;
    *(float4*)&Bsh[sr*40 + sc]     = b0;
    *(float4*)&Bsh[sr*40 + sc + 8] = b1;
    __syncthreads();
    f16x8 af[4], bf_[4];
    #pragma unroll
    for (int i = 0; i < 4; ++i) af[i]  = *(const f16x8*)&Ash[(wm + i*16 + fr)*40 + fk];
    #pragma unroll
    for (int j = 0; j < 4; ++j) bf_[j] = *(const f16x8*)&Bsh[(wn + j*16 + fr)*40 + fk];
    #pragma unroll
    for (int i = 0; i < 4; ++i)
      #pragma unroll
      for (int j = 0; j < 4; ++j)
        acc[i][j] = __builtin_amdgcn_mfma_f32_16x16x32_f16(af[i], bf_[j], acc[i][j], 0, 0, 0);
  }
  const int cr = (lane >> 4)*4;
  const int cc = lane & 15;
  #pragma unroll
  for (int i = 0; i < 4; ++i)
    #pragma unroll
    for (int j = 0; j < 4; ++j){
      int col = bn + wn + j*16 + cc;
      if (col < N){
        #pragma unroll
        for (int r = 0; r < 4; ++r){
          size_t idx = (size_t)(bm + wm + i*16 + cr + r)*ldc + col;
          float v = acc[i][j][r];
          if (ACC) v += (float)C[idx];
          C[idx] = (OT)sanit(v);
        }
      }
    }
}

template<typename OT, bool ACC>
__global__ __launch_bounds__(256) void k_gemm(const _Float16* __restrict__ A, int lda,
                                              const _Float16* __restrict__ Bt, int ldb,
                                              OT* __restrict__ C, int ldc,
                                              int N, int K){
  gemm_body<OT,ACC>(A, lda, Bt, ldb, C, ldc, N, K, blockIdx.x, blockIdx.y);
}

// batch of 4 independent small setup GEMMs (22 blocks total)
__global__ __launch_bounds__(256) void k_setup(const _Float16* __restrict__ FR,
                                               const _Float16* __restrict__ wqn,
                                               _Float16* __restrict__ T1,
                                               const _Float16* __restrict__ wint,
                                               const _Float16* __restrict__ woutt,
                                               const _Float16* __restrict__ FI2,
                                               _Float16* __restrict__ WB,
                                               const _Float16* __restrict__ wloopT,
                                               const _Float16* __restrict__ circ16){
  int b = blockIdx.x;
  if (b < 6)       gemm_body<_Float16,false>(FR, 256, wqn, 256, T1, 256, 256, 256, b % 3, b / 3);
  else if (b < 12){ int i = b - 6;  gemm_body<_Float16,false>(wint, 256, FI2, 256, WB + 256, 832, 288, 256, i % 2, i / 2); }
  else if (b < 18){ int i = b - 12; gemm_body<_Float16,false>(woutt, 256, FI2, 256, WB + 544, 832, 288, 256, i % 2, i / 2); }
  else            { int i = b - 18; gemm_body<_Float16,false>(wloopT, 256, circ16, 256, WB, 832, 256, 256, i % 2, i / 2); }
}

// Fused qual GEMM, XCD-triple swizzled (grid 2352, 1-D):
// Yhat[q] = (conj(Xhat[ent_q]) .* Rhat[rel_q]) @ G^T
__global__ __launch_bounds__(256) void k_qgemm(const _Float16* __restrict__ Xhat,
                                               const int* __restrict__ quals, int d,
                                               const _Float16* __restrict__ G,
                                               _Float16* __restrict__ Yhat){
  int L = blockIdx.x;
  int xcd = L & 7, w = L >> 3;
  int t3 = (w / 3)*8 + xcd;          // row-block (triple) id: 3 col-tiles share XCD
  if (t3 >= 782) return;
  int bn = (w % 3)*128;
  int bm = t3*128;
  __shared__ __align__(16) _Float16 Ash[128*40];
  __shared__ __align__(16) _Float16 Bsh[128*40];
  const int tid = threadIdx.x;
  const int lane = tid & 63;
  const int wv = tid >> 6;
  const int wm = (wv >> 1)*64, wn = (wv & 1)*64;
  const int sr = tid >> 1;
  const int h  = tid & 1;
  const int fr = lane & 15;
  const int fk = (lane >> 4)*8;
  int q = bm + sr; if (q > 99999) q = 99999;
  int qi = d*100000 + q;
  int rel = iclamp(quals[qi], 0, 500);
  int ent = iclamp(quals[TWOQ + qi], 0, NN-1);
  const unsigned int* xr = (const unsigned int*)(Xhat + (size_t)ent*288);
  const unsigned int* rr = (const unsigned int*)(Xhat + (size_t)(50048 + rel)*288);
  const _Float16* gbase = G + (size_t)(bn+sr)*288 + h*16;
  int kb = h*8;
  uint4 nxa0 = *(const uint4*)(xr + kb);
  uint4 nxa1 = *(const uint4*)(xr + kb + 4);
  uint4 nra0 = *(const uint4*)(rr + kb);
  uint4 nra1 = *(const uint4*)(rr + kb + 4);
  float4 nb0 = *(const float4*)(gbase);
  float4 nb1 = *(const float4*)(gbase + 8);
  f32x4 acc[4][4] = {};
  for (int kt = 0; kt < 288; kt += 32){
    uint4 oa0, oa1;
    oa0.x = cmulh(nxa0.x, nra0.x); oa0.y = cmulh(nxa0.y, nra0.y);
    oa0.z = cmulh(nxa0.z, nra0.z); oa0.w = cmulh(nxa0.w, nra0.w);
    oa1.x = cmulh(nxa1.x, nra1.x); oa1.y = cmulh(nxa1.y, nra1.y);
    oa1.z = cmulh(nxa1.z, nra1.z); oa1.w = cmulh(nxa1.w, nra1.w);
    float4 b0 = nb0, b1 = nb1;
    __syncthreads();
    *(uint4*)&Ash[sr*40 + h*16]      = oa0;
    *(uint4*)&Ash[sr*40 + h*16 + 8]  = oa1;
    *(float4*)&Bsh[sr*40 + h*16]     = b0;
    *(float4*)&Bsh[sr*40 + h*16 + 8] = b1;
    __syncthreads();
    int kt2 = kt + 32; if (kt2 > 256) kt2 = 256;
    int kb2 = (kt2 >> 1) + h*8;
    nxa0 = *(const uint4*)(xr + kb2);
    nxa1 = *(const uint4*)(xr + kb2 + 4);
    nra0 = *(const uint4*)(rr + kb2);
    nra1 = *(const uint4*)(rr + kb2 + 4);
    const _Float16* gb2 = gbase + kt2;
    nb0 = *(const float4*)(gb2);
    nb1 = *(const float4*)(gb2 + 8);
    f16x8 af[4], bf_[4];
    #pragma unroll
    for (int i = 0; i < 4; ++i) af[i]  = *(const f16x8*)&Ash[(wm + i*16 + fr)*40 + fk];
    #pragma unroll
    for (int j = 0; j < 4; ++j) bf_[j] = *(const f16x8*)&Bsh[(wn + j*16 + fr)*40 + fk];
    #pragma unroll
    for (int i = 0; i < 4; ++i)
      #pragma unroll
      for (int j = 0; j < 4; ++j)
        acc[i][j] = __builtin_amdgcn_mfma_f32_16x16x32_f16(af[i], bf_[j], acc[i][j], 0, 0, 0);
  }
  const int cr = (lane >> 4)*4;
  const int cc = lane & 15;
  #pragma unroll
  for (int i = 0; i < 4; ++i)
    #pragma unroll
    for (int j = 0; j < 4; ++j){
      int col = bn + wn + j*16 + cc;
      if (col < 288){
        #pragma unroll
        for (int r = 0; r < 4; ++r){
          size_t idx = (size_t)(bm + wm + i*16 + cr + r)*288 + col;
          Yhat[idx] = sat16(acc[i][j][r]);
        }
      }
    }
}

// ---- gather-aggregate via packed records, depth-2 pipeline; writes XCAT cols ----
__global__ __launch_bounds__(128) void k_agg(const char* __restrict__ Wb,
                                             const int* __restrict__ ptr,
                                             const int2* __restrict__ recs,
                                             int d, _Float16* __restrict__ XC){
  int node = blockIdx.x;
  int t = threadIdx.x;
  int gnode = d*NN + node;
  int beg = ptr[gnode], end = ptr[gnode+1];
  unsigned int* orow = (unsigned int*)(XC + (size_t)node*832 + 256 + d*288);
  if (end <= beg){
    orow[t] = 0;
    if (t < 16) orow[128 + t] = 0;
    return;
  }
  int last = end - 1;
  auto ld = [&](int idx, unsigned& va, unsigned& vb, float& ah, float& bh, float& cf){
    int ic = idx < last ? idx : last;
    int2 rc = recs[ic];
    int xrow = rc.x & 0xffff;
    int brow = ((rc.x >> 16) & 0xffff) | ((rc.y & 1) << 16);
    const char* xb = Wb + O_XHAT + (size_t)xrow*576;
    const char* bb = Wb + ((rc.y & 2) ? O_YH : O_XHAT) + (size_t)brow*576;
    va = ((const unsigned*)xb)[t]; vb = ((const unsigned*)bb)[t];
    ah = (float)((const _Float16*)xb)[256];
    bh = (float)((const _Float16*)bb)[256];
    HU cu; cu.u = ((unsigned)rc.y) >> 16;
    cf = (idx <= last) ? (float)cu.h[0] : 0.f;
  };
  float ax_ = 0.f, ay_ = 0.f, ex = 0.f;
  unsigned va0, vb0, va1, vb1; float ah0, bh0, ah1, bh1, cf0, cf1;
  ld(beg,     va0, vb0, ah0, bh0, cf0);
  ld(beg + 1, va1, vb1, ah1, bh1, cf1);
  for (int k = beg; k < end; k += 2){
    unsigned ta0, tb0, ta1, tb1; float th0, tg0, th1, tg1, tc0, tc1;
    ld(k + 2, ta0, tb0, th0, tg0, tc0);
    ld(k + 3, ta1, tb1, th1, tg1, tc1);
    {
      HU a, b; a.u = va0; b.u = vb0;
      float axv=(float)a.h[0], ayv=(float)a.h[1], bxv=(float)b.h[0], byv=(float)b.h[1];
      ax_ += cf0*(axv*bxv + ayv*byv);
      ay_ += cf0*(axv*byv - ayv*bxv);
      ex  += cf0*ah0*bh0;
    }
    {
      HU a, b; a.u = va1; b.u = vb1;
      float axv=(float)a.h[0], ayv=(float)a.h[1], bxv=(float)b.h[0], byv=(float)b.h[1];
      ax_ += cf1*(axv*bxv + ayv*byv);
      ay_ += cf1*(axv*byv - ayv*bxv);
      ex  += cf1*ah1*bh1;
    }
    va0=ta0; vb0=tb0; ah0=th0; bh0=tg0; cf0=tc0;
    va1=ta1; vb1=tb1; ah1=th1; bh1=tg1; cf1=tc1;
  }
  HU o; o.h[0] = sat16(ax_); o.h[1] = sat16(ay_);
  orow[t] = o.u;
  if (t < 16){
    HU o2; o2.h[0] = (t == 0) ? sat16(ex) : (_Float16)0.f; o2.h[1] = (_Float16)0.f;
    orow[128 + t] = o2.u;
  }
}

__global__ void k_bnstats(const _Float16* __restrict__ opre, float* __restrict__ bns){
  int col = threadIdx.x;
  int r0 = blockIdx.x*64, r1 = r0 + 64; if (r1 > NN) r1 = NN;
  float s1 = 0.f, s2 = 0.f;
  for (int r = r0; r < r1; ++r){
    float v = (float)opre[(size_t)r*256 + col];
    s1 += v; s2 += v*v;
  }
  atomAddF(&bns[col], s1);
  atomAddF(&bns[256 + col], s2);
}

__global__ void k_bnfinal(float* __restrict__ bns, const float* __restrict__ gamma,
                          const float* __restrict__ beta){
  int col = threadIdx.x;
  float mean = bns[col] * (1.f/NN);
  float var  = bns[256 + col] * (1.f/NN) - mean*mean;
  var = fmaxf(var, 0.f);
  // BN of (acc/3 + bias) == (acc-mean_acc)/sqrt(var_acc + 9*eps); bias cancels
  float g = gamma[col] * rsqrtf(var + 9e-5f);
  float b = beta[col] - mean*g;
  bns[512 + col] = sanit(g);
  bns[768 + col] = sanit(b);
}

// fused epilogue: blocks [0,500) rel_out (early, overlaps) ; [500,6750) ent-BN-tanh
__global__ void k_epi(const _Float16* __restrict__ opre, const float* __restrict__ bns,
                      const float* __restrict__ ral32, const float* __restrict__ w_rel,
                      float* __restrict__ out){
  int b = blockIdx.x;
  if (b < 500){
    int r = b, n = threadIdx.x;
    const float* rr = ral32 + r*256;
    const float* wr = w_rel + n;
    float a0 = 0.f, a1 = 0.f, a2 = 0.f, a3 = 0.f;
    for (int k = 0; k < 256; k += 4){
      a0 += rr[k]     * wr[(size_t)k*256];
      a1 += rr[k + 1] * wr[(size_t)(k + 1)*256];
      a2 += rr[k + 2] * wr[(size_t)(k + 2)*256];
      a3 += rr[k + 3] * wr[(size_t)(k + 3)*256];
    }
    out[12800000 + r*256 + n] = sanit((a0 + a1) + (a2 + a3));
  } else {
    int t = (b - 500)*256 + threadIdx.x;   // < NN*32 exactly
    f16x8 v = ((const f16x8*)opre)[t];
    int col = (t & 31)*8;
    float4 o0, o1;
    o0.x = sanit(ftanh((float)v[0]*bns[512+col+0] + bns[768+col+0]));
    o0.y = sanit(ftanh((float)v[1]*bns[512+col+1] + bns[768+col+1]));
    o0.z = sanit(ftanh((float)v[2]*bns[512+col+2] + bns[768+col+2]));
    o0.w = sanit(ftanh((float)v[3]*bns[512+col+3] + bns[768+col+3]));
    o1.x = sanit(ftanh((float)v[4]*bns[512+col+4] + bns[768+col+4]));
    o1.y = sanit(ftanh((float)v[5]*bns[512+col+5] + bns[768+col+5]));
    o1.z = sanit(ftanh((float)v[6]*bns[512+col+6] + bns[768+col+6]));
    o1.w = sanit(ftanh((float)v[7]*bns[512+col+7] + bns[768+col+7]));
    ((float4*)out)[(size_t)t*2]     = o0;
    ((float4*)out)[(size_t)t*2 + 1] = o1;
  }
}

extern "C" void kernel_launch(void* const* d_in, const int* in_sizes, int n_in,
                              void* d_out, int out_size, void* d_ws, size_t ws_size,
                              hipStream_t stream){
  (void)in_sizes; (void)n_in;
  if (ws_size < WS_NEED){
    hipMemsetAsync(d_out, 0, (size_t)out_size*4, stream);
    return;
  }
  const float* x        = (const float*)d_in[0];
  const float* rel_emb  = (const float*)d_in[1];
  const float* w_in     = (const float*)d_in[2];
  const float* w_out_   = (const float*)d_in[3];
  const float* w_loop   = (const float*)d_in[4];
  const float* w_rel    = (const float*)d_in[5];
  const float* w_q      = (const float*)d_in[6];
  const float* loop_rel = (const float*)d_in[7];
  const float* gamma    = (const float*)d_in[9];
  const float* beta     = (const float*)d_in[10];
  const int* ei    = (const int*)d_in[11];
  const int* et    = (const int*)d_in[12];
  const int* quals = (const int*)d_in[13];
  float* out = (float*)d_out;
  char* W = (char*)d_ws;
  _Float16* XC    = (_Float16*)(W + O_XCAT);
  _Float16* Xhat  = (_Float16*)(W + O_XHAT);
  _Float16* Yhat  = (_Float16*)(W + O_YH);
  _Float16* opre  = (_Float16*)(W + O_YH);     // aliases Yhat (dead by then)
  _Float16* FR    = (_Float16*)(W + O_FR);
  _Float16* FI2   = (_Float16*)(W + O_FI2);
  _Float16* T1    = (_Float16*)(W + O_T1);
  _Float16* G     = (_Float16*)(W + O_G);
  _Float16* WB    = (_Float16*)(W + O_WB);
  _Float16* wqn   = (_Float16*)(W + O_WQN);
  _Float16* wint  = (_Float16*)(W + O_WINT);
  _Float16* woutt = (_Float16*)(W + O_WOUT);
  float*    ral32 = (float*)(W + O_RAL32);
  int*      cntE  = (int*)(W + O_CNTE);
  int*      cntQ  = (int*)(W + O_CNTQ);
  float*    bns   = (float*)(W + O_BNS);
  float*    dinv  = (float*)(W + O_DINV);
  int*      ptr   = (int*)(W + O_PTR);
  int*      cur   = (int*)(W + O_CUR);
  int*      bsum  = (int*)(W + O_BSUM);
  int2*     recs  = (int2*)(W + O_RECS);
  _Float16* circ16= (_Float16*)(W + O_RECS);           // temp, dead before fillrec
  _Float16* wloopT= (_Float16*)(W + O_RECS + 131072);

  hipMemsetAsync(cntE, 0, 800000, stream);   // cntE + cntQ (adjacent)
  hipMemsetAsync(bns, 0, 4096, stream);

  k_pro<<<10431, 256, 0, stream>>>(FR, FI2, w_in, w_out_, w_q, rel_emb, loop_rel, w_loop,
                                   wqn, wint, woutt, ral32, circ16, wloopT,
                                   x, XC, ei, quals, cntE, cntQ);
  // T1=FR@wqn^T ; WB[256:544]=FiWin ; WB[544:832]=FiWout ; WB[0:256]=BW
  k_setup<<<22, 256, 0, stream>>>(FR, wqn, T1, wint, woutt, FI2, WB, wloopT, circ16);
  // G = T1 @ FI2^T
  k_gemm<_Float16,false><<<dim3(3,3), 256, 0, stream>>>(T1, 256, FI2, 256, G, 288, 288, 256);
  k_dinv_scan1<<<391 + SCB, 256, 0, stream>>>(cntE, cntQ, dinv, bsum);
  k_scan3<<<SCB, 256, 0, stream>>>(cntE, cntQ, bsum, ptr, cur);
  k_fillrec<<<3125, 256, 0, stream>>>(ei, et, quals, dinv, cur, recs);

  // [Xhat ; Rhat] = XCAT[:,0:256] @ FR^T  (rows 0..50559)
  k_gemm<_Float16,false><<<dim3(395,3), 256, 0, stream>>>(XC, 832, FR, 256, Xhat, 288, 288, 256);

  for (int d = 0; d < 2; ++d){
    k_qgemm<<<2352, 256, 0, stream>>>(Xhat, quals, d, G, Yhat);
    k_agg<<<NN, 128, 0, stream>>>(W, ptr, recs, d, XC);
  }

  // opre = XCAT @ WB^T   (K=832: self-loop + both directions in one GEMM)
  k_gemm<_Float16,false><<<dim3(391,2), 256, 0, stream>>>(XC, 832, WB, 832, opre, 256, 256, 832);

  k_bnstats<<<782, 256, 0, stream>>>(opre, bns);
  k_bnfinal<<<1, 256, 0, stream>>>(bns, gamma, beta);
  k_epi<<<6750, 256, 0, stream>>>(opre, bns, ral32, w_rel, out);
}

// Round 15
// 466.723 us; speedup vs baseline: 1.5180x; 1.0336x over previous
//
#include <hip/hip_runtime.h>

typedef __attribute__((ext_vector_type(8))) _Float16 f16x8;
typedef __attribute__((ext_vector_type(4))) float f32x4;

#define NN   50000
#define EE   300000
#define TWOE 600000
#define TWOQ 200000
#define SCB  98     // scan blocks of 1024 ints covering 2*NN=100000

// ---- workspace layout (bytes), total 181,457,600 (<= proven 184,089,664) ----
static constexpr size_t O_XCAT = 0;            // f16 [50560][832]: cols 0:256 x / ral16 rows 50048+, 256:544 AGG0, 544:832 AGG1
static constexpr size_t O_XHAT = 84131840;     // f16 [50560][288]: rows 0..50047 Xhat, 50048..50559 Rhat
static constexpr size_t O_YH   = 113254400;    // f16 [100096][288] Yhat (per-dir); later opre f16 [50048][256] aliases
static constexpr size_t O_FR   = 170909696;    // f16 [384,256]
static constexpr size_t O_FI2  = 171106304;    // f16 [384,256]
static constexpr size_t O_T1   = 171302912;    // f16 [384,256]
static constexpr size_t O_G    = 171499520;    // f16 [384,288]
static constexpr size_t O_WB   = 171720704;    // f16 [256,832]: [0:256]=BW, [256:544]=FiWin, [544:832]=FiWout
static constexpr size_t O_WQN  = 172146688;    // f16 [256,256]
static constexpr size_t O_WINT = 172277760;    // f16 [256,256]
static constexpr size_t O_WOUT = 172408832;    // f16 [256,256]
static constexpr size_t O_RAL32= 172539904;    // f32 [501,256]
static constexpr size_t O_CNTE = 173052928;    // int [2N]  (edge counts; also degree source, swapped)
static constexpr size_t O_CNTQ = 173452928;    // int [2N]  (qual counts; adjacent: one memset)
static constexpr size_t O_BNS  = 173852928;    // f32 [1024]
static constexpr size_t O_DINV = 173857024;    // f32 [2,N]
static constexpr size_t O_PTR  = 174257024;    // int [2N+1]
static constexpr size_t O_CUR  = 174657088;    // int [2N]
static constexpr size_t O_BSUM = 175057088;    // int [128]
static constexpr size_t O_RECS = 175057600;    // int2 [800000] = 6.4MB; temp circ16/wloopT alias
static constexpr size_t WS_NEED= 181457600;

__device__ __forceinline__ float sanit(float v){
  v = (v == v) ? v : 0.f;
  return fminf(60000.f, fmaxf(-60000.f, v));
}
__device__ __forceinline__ _Float16 sat16(float v){ return (_Float16)sanit(v); }
__device__ __forceinline__ int iclamp(int v, int lo, int hi){
  return v < lo ? lo : (v > hi ? hi : v);
}
__device__ __forceinline__ void atomAddF(float* p, float v){
  __hip_atomic_fetch_add(p, v, __ATOMIC_RELAXED, __HIP_MEMORY_SCOPE_AGENT);
}
union HU { unsigned int u; _Float16 h[2]; };

// fast branchless tanh: (e^2x - 1)/(e^2x + 1), clamped; err <= ~1e-4
__device__ __forceinline__ float ftanh(float x){
  float e2 = __expf(fminf(fmaxf(2.f*x, -20.f), 20.f));
  return (e2 - 1.f) * __builtin_amdgcn_rcpf(e2 + 1.f);
}

// native-f16 complex multiply (conj(a)*b)
__device__ __forceinline__ unsigned int cmulh(unsigned int ua, unsigned int ub){
  HU a, b, o; a.u = ua; b.u = ub;
  o.h[0] = a.h[0]*b.h[0] + a.h[1]*b.h[1];
  o.h[1] = a.h[0]*b.h[1] - a.h[1]*b.h[0];
  return o.u;
}

// ---- fused prologue ----
// [0,288) gen_dft | [288,800) misc+ral | [800,7050) cvt_x->XCAT
// [7050,10175) cntE/cntQ | [10175,10431) circ16/wloopT
__global__ void k_pro(_Float16* __restrict__ FR, _Float16* __restrict__ FI2,
                      const float* __restrict__ w_in, const float* __restrict__ w_out,
                      const float* __restrict__ w_q, const float* __restrict__ rel_embed,
                      const float* __restrict__ loop_rel, const float* __restrict__ w_loop,
                      _Float16* __restrict__ wqn, _Float16* __restrict__ wint,
                      _Float16* __restrict__ woutt,
                      float* __restrict__ ral32,
                      _Float16* __restrict__ circ16, _Float16* __restrict__ wloopT,
                      const float* __restrict__ x, _Float16* __restrict__ XC,
                      const int* __restrict__ ei, const int* __restrict__ quals,
                      int* __restrict__ cntE, int* __restrict__ cntQ){
  int b = blockIdx.x, tid = threadIdx.x;
  if (b < 288){
    int t = b*256 + tid;
    const float step = 0.024543692606170259f; // 2*pi/256
    {
      int f = t >> 8, tt = t & 255;
      float v = 0.f;
      if (f < 258){
        int m = f >> 1;
        float ang = (float)((tt*m) & 255) * step;
        v = (f & 1) ? -sinf(ang) : cosf(ang);
      }
      FR[t] = (_Float16)v;
    }
    {
      int k = t >> 8, j = t & 255;
      float v = 0.f;
      if (k < 258){
        int m = k >> 1;
        float w = (m==0 || m==128) ? (1.f/256.f) : (2.f/256.f);
        float ang = (float)((j*m) & 255) * step;
        v = (k & 1) ? -w*sinf(ang) : w*cosf(ang);
      }
      FI2[t] = (_Float16)v;
    }
  } else if (b < 800){
    int t = (b - 288)*256 + tid;   // < 131072
    if (t < 65536){
      int j = t >> 8, n = t & 255;
      wqn[t] = sat16(w_q[t]);
      wint[n*256 + j]  = sat16(w_in[t]);
      woutt[n*256 + j] = sat16(w_out[t]);
    }
    float rv = 0.f;
    if (t < 128000) rv = sanit(rel_embed[t]);
    else if (t < 128256) rv = sanit(loop_rel[t - 128000]);
    int row = t >> 8, c = t & 255;
    XC[(size_t)(50048 + row)*832 + c] = (_Float16)rv;   // ral16 rows (pad rows zero)
    if (t < 128256) ral32[t] = rv;
  } else if (b < 7050){
    int t = (b - 800)*256 + tid;   // < 1,600,000 exactly (50000 rows x 32 chunks)
    const float4* p = (const float4*)x + (size_t)t*2;
    float4 v0 = p[0], v1 = p[1];
    f16x8 o;
    o[0]=sat16(v0.x); o[1]=sat16(v0.y); o[2]=sat16(v0.z); o[3]=sat16(v0.w);
    o[4]=sat16(v1.x); o[5]=sat16(v1.y); o[6]=sat16(v1.z); o[7]=sat16(v1.w);
    int row = t >> 5, c8 = (t & 31)*8;
    *(f16x8*)(XC + (size_t)row*832 + c8) = o;
  } else if (b < 10175){
    int t = (b - 7050)*256 + tid;  // < 800,000 exactly
    if (t < TWOE){
      int d = (t >= EE) ? 1 : 0;
      atomicAdd(&cntE[d*NN + iclamp(ei[TWOE + t], 0, NN-1)], 1);
    } else {
      int qg = t - TWOE;
      int d = (qg >= 100000) ? 1 : 0;
      int e = iclamp(quals[2*TWOQ + qg], 0, EE-1);
      int j = d*EE + e;
      atomicAdd(&cntQ[d*NN + iclamp(ei[TWOE + j], 0, NN-1)], 1);
    }
  } else {
    int t = (b - 10175)*256 + tid; // < 65536 exactly
    int r = t >> 8, m = t & 255;
    circ16[t] = sat16(loop_rel[(r + m) & 255]);      // Circ16[j][m]
    wloopT[t] = sat16(w_loop[m*256 + r]);            // wloopT[n][m]
  }
}

// fused: blocks [0,391) dinv (degrees = swapped cntE) ; [391,489) scan1 (cntE+cntQ)
__global__ void k_dinv_scan1(const int* __restrict__ cntE, const int* __restrict__ cntQ,
                             float* __restrict__ dinv, int* __restrict__ bsum){
  int b = blockIdx.x, t = threadIdx.x;
  if (b < 391){
    int i = b*256 + t;
    if (i < 2*NN){
      // deg[0][n] = #{src=n} = cntE[1][n] ; deg[1][n] = #{dst=n} = cntE[0][n]
      int part = (i < NN) ? i + NN : i - NN;
      int c = cntE[part];
      dinv[i] = (c > 0) ? rsqrtf((float)c) : 0.f;
    }
  } else {
    __shared__ int sh[256];
    int blk = b - 391;
    int base = blk*1024 + t*4;
    int s = 0;
    #pragma unroll
    for (int i = 0; i < 4; ++i){
      int idx = base + i;
      if (idx < 2*NN) s += cntE[idx] + cntQ[idx];
    }
    sh[t] = s; __syncthreads();
    for (int off = 128; off > 0; off >>= 1){
      if (t < off) sh[t] += sh[t + off];
      __syncthreads();
    }
    if (t == 0) bsum[blk] = sh[0];
  }
}

// self-contained: prefix raw bsum in-block, then scatter ptr/cur
__global__ void k_scan3(const int* __restrict__ cntE, const int* __restrict__ cntQ,
                        const int* __restrict__ bsum,
                        int* __restrict__ ptr, int* __restrict__ cur){
  __shared__ int sh[256];
  __shared__ int bs[128];
  int b = blockIdx.x, t = threadIdx.x;
  int base = b*1024 + t*4;
  int v[4];
  int s = 0;
  #pragma unroll
  for (int i = 0; i < 4; ++i){
    int idx = base + i;
    v[i] = (idx < 2*NN) ? (cntE[idx] + cntQ[idx]) : 0;
    s += v[i];
  }
  sh[t] = s;
  if (t < 128) bs[t] = (t < SCB) ? bsum[t] : 0;
  __syncthreads();
  // inclusive Hillis-Steele over thread sums
  for (int off = 1; off < 256; off <<= 1){
    int add = (t >= off) ? sh[t - off] : 0;
    __syncthreads();
    sh[t] += add;
    __syncthreads();
  }
  // inclusive prefix over block sums (128-wide)
  for (int off = 1; off < 128; off <<= 1){
    int add = (t >= off && t < 128) ? bs[t - off] : 0;
    __syncthreads();
    if (t < 128) bs[t] += add;
    __syncthreads();
  }
  int blockoff = (b > 0) ? bs[b - 1] : 0;
  if (b == 0 && t == 0) ptr[2*NN] = bs[SCB - 1];
  int off0 = blockoff + sh[t] - s;
  #pragma unroll
  for (int i = 0; i < 4; ++i){
    int idx = base + i;
    if (idx < 2*NN){ ptr[idx] = off0; cur[idx] = off0; }
    off0 += v[i];
  }
}

// packed per-item records int2: x.lo16=xrow, x.hi16=brow.lo16;
// y: bit0=brow.bit16, bit1=isqual, bits31:16=coef f16
__global__ void k_fillrec(const int* __restrict__ ei, const int* __restrict__ et,
                          const int* __restrict__ quals, const float* __restrict__ dinv,
                          int* __restrict__ cursor, int2* __restrict__ recs){
  int t = blockIdx.x*256 + threadIdx.x;
  if (t >= TWOE + TWOQ) return;
  int d, j, brow, isq; float w;
  if (t < TWOE){
    d = (t >= EE) ? 1 : 0;
    j = t;
    brow = 50048 + iclamp(et[j], 0, 500);   // Rhat row within XHAT region
    isq = 0; w = 0.8f;
  } else {
    int qg = t - TWOE;
    d = (qg >= 100000) ? 1 : 0;
    int e = iclamp(quals[2*TWOQ + qg], 0, EE-1);
    j = d*EE + e;
    brow = qg - d*100000;                   // Yhat row (per-direction)
    isq = 1; w = 0.2f;
  }
  int src = iclamp(ei[j], 0, NN-1);
  int dst = iclamp(ei[TWOE + j], 0, NN-1);
  float coef = w * dinv[d*NN + src] * dinv[d*NN + dst];
  int pos = atomicAdd(&cursor[d*NN + dst], 1);
  pos = iclamp(pos, 0, 800000-1);
  HU cu; cu.h[0] = (_Float16)coef; cu.h[1] = (_Float16)0.f;
  int2 rc;
  rc.x = src | ((brow & 0xffff) << 16);
  rc.y = ((brow >> 16) & 1) | (isq << 1) | ((int)(cu.u & 0xffffu) << 16);
  recs[pos] = rc;
}

// ---- shared GEMM body: C[.,N](ldc) = A[.,K](lda) @ Bt[.,K](ldb)^T; UNGUARDED loads ----
template<typename OT, bool ACC>
__device__ __forceinline__ void gemm_body(const _Float16* __restrict__ A, int lda,
                                          const _Float16* __restrict__ Bt, int ldb,
                                          OT* __restrict__ C, int ldc,
                                          int N, int K, int bx, int by){
  __shared__ __align__(16) _Float16 Ash[128*40];
  __shared__ __align__(16) _Float16 Bsh[128*40];
  const int tid = threadIdx.x;
  const int lane = tid & 63;
  const int wv = tid >> 6;
  const int bm = bx*128, bn = by*128;
  const int wm = (wv >> 1)*64, wn = (wv & 1)*64;
  const int sr = tid >> 1;
  const int sc = (tid & 1)*16;
  const int fr = lane & 15;
  const int fk = (lane >> 4)*8;
  const _Float16* pa = A + (size_t)(bm+sr)*lda + sc;
  const _Float16* pb = Bt + (size_t)(bn+sr)*ldb + sc;
  f32x4 acc[4][4] = {};
  for (int kt = 0; kt < K; kt += 32){
    float4 a0 = *(const float4*)(pa);
    float4 a1 = *(const float4*)(pa + 8);
    float4 b0 = *(const float4*)(pb);
    float4 b1 = *(const float4*)(pb + 8);
    pa += 32; pb += 32;
    __syncthreads();
    *(float4*)&Ash[sr*40 + sc]     = a0;
    *(float4*)&Ash[sr*40 + sc + 8] = a1;
    *(float4*)&Bsh[sr*40 + sc]     = b0;
    *(float4*)&Bsh[sr*40 + sc + 8] = b1;
    __syncthreads();
    f16x8 af[4], bf_[4];
    #pragma unroll
    for (int i = 0; i < 4; ++i) af[i]  = *(const f16x8*)&Ash[(wm + i*16 + fr)*40 + fk];
    #pragma unroll
    for (int j = 0; j < 4; ++j) bf_[j] = *(const f16x8*)&Bsh[(wn + j*16 + fr)*40 + fk];
    #pragma unroll
    for (int i = 0; i < 4; ++i)
      #pragma unroll
      for (int j = 0; j < 4; ++j)
        acc[i][j] = __builtin_amdgcn_mfma_f32_16x16x32_f16(af[i], bf_[j], acc[i][j], 0, 0, 0);
  }
  const int cr = (lane >> 4)*4;
  const int cc = lane & 15;
  #pragma unroll
  for (int i = 0; i < 4; ++i)
    #pragma unroll
    for (int j = 0; j < 4; ++j){
      int col = bn + wn + j*16 + cc;
      if (col < N){
        #pragma unroll
        for (int r = 0; r < 4; ++r){
          size_t idx = (size_t)(bm + wm + i*16 + cr + r)*ldc + col;
          float v = acc[i][j][r];
          if (ACC) v += (float)C[idx];
          C[idx] = (OT)sanit(v);
        }
      }
    }
}

template<typename OT, bool ACC>
__global__ __launch_bounds__(256) void k_gemm(const _Float16* __restrict__ A, int lda,
                                              const _Float16* __restrict__ Bt, int ldb,
                                              OT* __restrict__ C, int ldc,
                                              int N, int K){
  gemm_body<OT,ACC>(A, lda, Bt, ldb, C, ldc, N, K, blockIdx.x, blockIdx.y);
}

// batch of 4 independent small setup GEMMs (22 blocks total)
__global__ __launch_bounds__(256) void k_setup(const _Float16* __restrict__ FR,
                                               const _Float16* __restrict__ wqn,
                                               _Float16* __restrict__ T1,
                                               const _Float16* __restrict__ wint,
                                               const _Float16* __restrict__ woutt,
                                               const _Float16* __restrict__ FI2,
                                               _Float16* __restrict__ WB,
                                               const _Float16* __restrict__ wloopT,
                                               const _Float16* __restrict__ circ16){
  int b = blockIdx.x;
  if (b < 6)       gemm_body<_Float16,false>(FR, 256, wqn, 256, T1, 256, 256, 256, b % 3, b / 3);
  else if (b < 12){ int i = b - 6;  gemm_body<_Float16,false>(wint, 256, FI2, 256, WB + 256, 832, 288, 256, i % 2, i / 2); }
  else if (b < 18){ int i = b - 12; gemm_body<_Float16,false>(woutt, 256, FI2, 256, WB + 544, 832, 288, 256, i % 2, i / 2); }
  else            { int i = b - 18; gemm_body<_Float16,false>(wloopT, 256, circ16, 256, WB, 832, 256, 256, i % 2, i / 2); }
}

// Fused qual GEMM, XCD-pair swizzled (grid 1600, 1-D), cols 0..255 via MFMA,
// col 256 (real Nyquist) via in-loop side accumulation in bn==0 tiles.
// Yhat[q] = (conj(Xhat[ent_q]) .* Rhat[rel_q]) @ G^T
__global__ __launch_bounds__(256) void k_qgemm(const _Float16* __restrict__ Xhat,
                                               const int* __restrict__ quals, int d,
                                               const _Float16* __restrict__ G,
                                               _Float16* __restrict__ Yhat){
  int L = blockIdx.x;
  int xcd = L & 7, w = L >> 3;
  int pr = (w >> 1)*8 + xcd;         // pair id: the 2 col-tiles share an XCD
  if (pr >= 782) return;
  int bn = (w & 1)*128;
  int bm = pr*128;
  __shared__ __align__(16) _Float16 Ash[128*40];
  __shared__ __align__(16) _Float16 Bsh[128*40];
  __shared__ __align__(16) _Float16 g256[288];
  __shared__ float psum[128][2];
  const int tid = threadIdx.x;
  const int lane = tid & 63;
  const int wv = tid >> 6;
  const int wm = (wv >> 1)*64, wn = (wv & 1)*64;
  const int sr = tid >> 1;
  const int h  = tid & 1;
  const int fr = lane & 15;
  const int fk = (lane >> 4)*8;
  const bool do256 = (bn == 0);
  if (tid < 144) ((unsigned*)g256)[tid] = ((const unsigned*)(G + (size_t)256*288))[tid];
  int q = bm + sr; if (q > 99999) q = 99999;
  int qi = d*100000 + q;
  int rel = iclamp(quals[qi], 0, 500);
  int ent = iclamp(quals[TWOQ + qi], 0, NN-1);
  const unsigned int* xr = (const unsigned int*)(Xhat + (size_t)ent*288);
  const unsigned int* rr = (const unsigned int*)(Xhat + (size_t)(50048 + rel)*288);
  const _Float16* gbase = G + (size_t)(bn+sr)*288 + h*16;
  int kb = h*8;
  uint4 nxa0 = *(const uint4*)(xr + kb);
  uint4 nxa1 = *(const uint4*)(xr + kb + 4);
  uint4 nra0 = *(const uint4*)(rr + kb);
  uint4 nra1 = *(const uint4*)(rr + kb + 4);
  float4 nb0 = *(const float4*)(gbase);
  float4 nb1 = *(const float4*)(gbase + 8);
  f32x4 acc[4][4] = {};
  float p256 = 0.f;
  for (int kt = 0; kt < 288; kt += 32){
    uint4 oa0, oa1;
    oa0.x = cmulh(nxa0.x, nra0.x); oa0.y = cmulh(nxa0.y, nra0.y);
    oa0.z = cmulh(nxa0.z, nra0.z); oa0.w = cmulh(nxa0.w, nra0.w);
    oa1.x = cmulh(nxa1.x, nra1.x); oa1.y = cmulh(nxa1.y, nra1.y);
    oa1.z = cmulh(nxa1.z, nra1.z); oa1.w = cmulh(nxa1.w, nra1.w);
    if (do256){
      const _Float16* gp = g256 + kt + h*16;
      HU u0, u1, u2, u3;
      u0.u = oa0.x; u1.u = oa0.y; u2.u = oa0.z; u3.u = oa0.w;
      p256 += (float)u0.h[0]*(float)gp[0]  + (float)u0.h[1]*(float)gp[1]
            + (float)u1.h[0]*(float)gp[2]  + (float)u1.h[1]*(float)gp[3]
            + (float)u2.h[0]*(float)gp[4]  + (float)u2.h[1]*(float)gp[5]
            + (float)u3.h[0]*(float)gp[6]  + (float)u3.h[1]*(float)gp[7];
      u0.u = oa1.x; u1.u = oa1.y; u2.u = oa1.z; u3.u = oa1.w;
      p256 += (float)u0.h[0]*(float)gp[8]  + (float)u0.h[1]*(float)gp[9]
            + (float)u1.h[0]*(float)gp[10] + (float)u1.h[1]*(float)gp[11]
            + (float)u2.h[0]*(float)gp[12] + (float)u2.h[1]*(float)gp[13]
            + (float)u3.h[0]*(float)gp[14] + (float)u3.h[1]*(float)gp[15];
    }
    float4 b0 = nb0, b1 = nb1;
    __syncthreads();
    *(uint4*)&Ash[sr*40 + h*16]      = oa0;
    *(uint4*)&Ash[sr*40 + h*16 + 8]  = oa1;
    *(float4*)&Bsh[sr*40 + h*16]     = b0;
    *(float4*)&Bsh[sr*40 + h*16 + 8] = b1;
    __syncthreads();
    int kt2 = kt + 32; if (kt2 > 256) kt2 = 256;
    int kb2 = (kt2 >> 1) + h*8;
    nxa0 = *(const uint4*)(xr + kb2);
    nxa1 = *(const uint4*)(xr + kb2 + 4);
    nra0 = *(const uint4*)(rr + kb2);
    nra1 = *(const uint4*)(rr + kb2 + 4);
    const _Float16* gb2 = gbase + kt2;
    nb0 = *(const float4*)(gb2);
    nb1 = *(const float4*)(gb2 + 8);
    f16x8 af[4], bf_[4];
    #pragma unroll
    for (int i = 0; i < 4; ++i) af[i]  = *(const f16x8*)&Ash[(wm + i*16 + fr)*40 + fk];
    #pragma unroll
    for (int j = 0; j < 4; ++j) bf_[j] = *(const f16x8*)&Bsh[(wn + j*16 + fr)*40 + fk];
    #pragma unroll
    for (int i = 0; i < 4; ++i)
      #pragma unroll
      for (int j = 0; j < 4; ++j)
        acc[i][j] = __builtin_amdgcn_mfma_f32_16x16x32_f16(af[i], bf_[j], acc[i][j], 0, 0, 0);
  }
  if (do256){
    psum[sr][h] = p256;
  }
  const int cr = (lane >> 4)*4;
  const int cc = lane & 15;
  #pragma unroll
  for (int i = 0; i < 4; ++i)
    #pragma unroll
    for (int j = 0; j < 4; ++j){
      int col = bn + wn + j*16 + cc;
      #pragma unroll
      for (int r = 0; r < 4; ++r){
        size_t idx = (size_t)(bm + wm + i*16 + cr + r)*288 + col;
        Yhat[idx] = sat16(acc[i][j][r]);
      }
    }
  __syncthreads();
  if (do256 && h == 0){
    Yhat[(size_t)(bm + sr)*288 + 256] = sat16(psum[sr][0] + psum[sr][1]);
  }
}

// ---- gather-aggregate via packed records, depth-2 pipeline; writes XCAT cols ----
__global__ __launch_bounds__(128) void k_agg(const char* __restrict__ Wb,
                                             const int* __restrict__ ptr,
                                             const int2* __restrict__ recs,
                                             int d, _Float16* __restrict__ XC){
  int node = blockIdx.x;
  int t = threadIdx.x;
  int gnode = d*NN + node;
  int beg = ptr[gnode], end = ptr[gnode+1];
  unsigned int* orow = (unsigned int*)(XC + (size_t)node*832 + 256 + d*288);
  if (end <= beg){
    orow[t] = 0;
    if (t < 16) orow[128 + t] = 0;
    return;
  }
  int last = end - 1;
  auto ld = [&](int idx, unsigned& va, unsigned& vb, float& ah, float& bh, float& cf){
    int ic = idx < last ? idx : last;
    int2 rc = recs[ic];
    int xrow = rc.x & 0xffff;
    int brow = ((rc.x >> 16) & 0xffff) | ((rc.y & 1) << 16);
    const char* xb = Wb + O_XHAT + (size_t)xrow*576;
    const char* bb = Wb + ((rc.y & 2) ? O_YH : O_XHAT) + (size_t)brow*576;
    va = ((const unsigned*)xb)[t]; vb = ((const unsigned*)bb)[t];
    ah = (float)((const _Float16*)xb)[256];
    bh = (float)((const _Float16*)bb)[256];
    HU cu; cu.u = ((unsigned)rc.y) >> 16;
    cf = (idx <= last) ? (float)cu.h[0] : 0.f;
  };
  float ax_ = 0.f, ay_ = 0.f, ex = 0.f;
  unsigned va0, vb0, va1, vb1; float ah0, bh0, ah1, bh1, cf0, cf1;
  ld(beg,     va0, vb0, ah0, bh0, cf0);
  ld(beg + 1, va1, vb1, ah1, bh1, cf1);
  for (int k = beg; k < end; k += 2){
    unsigned ta0, tb0, ta1, tb1; float th0, tg0, th1, tg1, tc0, tc1;
    ld(k + 2, ta0, tb0, th0, tg0, tc0);
    ld(k + 3, ta1, tb1, th1, tg1, tc1);
    {
      HU a, b; a.u = va0; b.u = vb0;
      float axv=(float)a.h[0], ayv=(float)a.h[1], bxv=(float)b.h[0], byv=(float)b.h[1];
      ax_ += cf0*(axv*bxv + ayv*byv);
      ay_ += cf0*(axv*byv - ayv*bxv);
      ex  += cf0*ah0*bh0;
    }
    {
      HU a, b; a.u = va1; b.u = vb1;
      float axv=(float)a.h[0], ayv=(float)a.h[1], bxv=(float)b.h[0], byv=(float)b.h[1];
      ax_ += cf1*(axv*bxv + ayv*byv);
      ay_ += cf1*(axv*byv - ayv*bxv);
      ex  += cf1*ah1*bh1;
    }
    va0=ta0; vb0=tb0; ah0=th0; bh0=tg0; cf0=tc0;
    va1=ta1; vb1=tb1; ah1=th1; bh1=tg1; cf1=tc1;
  }
  HU o; o.h[0] = sat16(ax_); o.h[1] = sat16(ay_);
  orow[t] = o.u;
  if (t < 16){
    HU o2; o2.h[0] = (t == 0) ? sat16(ex) : (_Float16)0.f; o2.h[1] = (_Float16)0.f;
    orow[128 + t] = o2.u;
  }
}

__global__ void k_bnstats(const _Float16* __restrict__ opre, float* __restrict__ bns){
  int col = threadIdx.x;
  int r0 = blockIdx.x*64, r1 = r0 + 64; if (r1 > NN) r1 = NN;
  float s1 = 0.f, s2 = 0.f;
  for (int r = r0; r < r1; ++r){
    float v = (float)opre[(size_t)r*256 + col];
    s1 += v; s2 += v*v;
  }
  atomAddF(&bns[col], s1);
  atomAddF(&bns[256 + col], s2);
}

__global__ void k_bnfinal(float* __restrict__ bns, const float* __restrict__ gamma,
                          const float* __restrict__ beta){
  int col = threadIdx.x;
  float mean = bns[col] * (1.f/NN);
  float var  = bns[256 + col] * (1.f/NN) - mean*mean;
  var = fmaxf(var, 0.f);
  // BN of (acc/3 + bias) == (acc-mean_acc)/sqrt(var_acc + 9*eps); bias cancels
  float g = gamma[col] * rsqrtf(var + 9e-5f);
  float b = beta[col] - mean*g;
  bns[512 + col] = sanit(g);
  bns[768 + col] = sanit(b);
}

// fused epilogue: blocks [0,500) rel_out (early, overlaps) ; [500,6750) ent-BN-tanh
__global__ void k_epi(const _Float16* __restrict__ opre, const float* __restrict__ bns,
                      const float* __restrict__ ral32, const float* __restrict__ w_rel,
                      float* __restrict__ out){
  int b = blockIdx.x;
  if (b < 500){
    int r = b, n = threadIdx.x;
    const float* rr = ral32 + r*256;
    const float* wr = w_rel + n;
    float a0 = 0.f, a1 = 0.f, a2 = 0.f, a3 = 0.f;
    for (int k = 0; k < 256; k += 4){
      a0 += rr[k]     * wr[(size_t)k*256];
      a1 += rr[k + 1] * wr[(size_t)(k + 1)*256];
      a2 += rr[k + 2] * wr[(size_t)(k + 2)*256];
      a3 += rr[k + 3] * wr[(size_t)(k + 3)*256];
    }
    out[12800000 + r*256 + n] = sanit((a0 + a1) + (a2 + a3));
  } else {
    int t = (b - 500)*256 + threadIdx.x;   // < NN*32 exactly
    f16x8 v = ((const f16x8*)opre)[t];
    int col = (t & 31)*8;
    float4 o0, o1;
    o0.x = sanit(ftanh((float)v[0]*bns[512+col+0] + bns[768+col+0]));
    o0.y = sanit(ftanh((float)v[1]*bns[512+col+1] + bns[768+col+1]));
    o0.z = sanit(ftanh((float)v[2]*bns[512+col+2] + bns[768+col+2]));
    o0.w = sanit(ftanh((float)v[3]*bns[512+col+3] + bns[768+col+3]));
    o1.x = sanit(ftanh((float)v[4]*bns[512+col+4] + bns[768+col+4]));
    o1.y = sanit(ftanh((float)v[5]*bns[512+col+5] + bns[768+col+5]));
    o1.z = sanit(ftanh((float)v[6]*bns[512+col+6] + bns[768+col+6]));
    o1.w = sanit(ftanh((float)v[7]*bns[512+col+7] + bns[768+col+7]));
    ((float4*)out)[(size_t)t*2]     = o0;
    ((float4*)out)[(size_t)t*2 + 1] = o1;
  }
}

extern "C" void kernel_launch(void* const* d_in, const int* in_sizes, int n_in,
                              void* d_out, int out_size, void* d_ws, size_t ws_size,
                              hipStream_t stream){
  (void)in_sizes; (void)n_in;
  if (ws_size < WS_NEED){
    hipMemsetAsync(d_out, 0, (size_t)out_size*4, stream);
    return;
  }
  const float* x        = (const float*)d_in[0];
  const float* rel_emb  = (const float*)d_in[1];
  const float* w_in     = (const float*)d_in[2];
  const float* w_out_   = (const float*)d_in[3];
  const float* w_loop   = (const float*)d_in[4];
  const float* w_rel    = (const float*)d_in[5];
  const float* w_q      = (const float*)d_in[6];
  const float* loop_rel = (const float*)d_in[7];
  const float* gamma    = (const float*)d_in[9];
  const float* beta     = (const float*)d_in[10];
  const int* ei    = (const int*)d_in[11];
  const int* et    = (const int*)d_in[12];
  const int* quals = (const int*)d_in[13];
  float* out = (float*)d_out;
  char* W = (char*)d_ws;
  _Float16* XC    = (_Float16*)(W + O_XCAT);
  _Float16* Xhat  = (_Float16*)(W + O_XHAT);
  _Float16* Yhat  = (_Float16*)(W + O_YH);
  _Float16* opre  = (_Float16*)(W + O_YH);     // aliases Yhat (dead by then)
  _Float16* FR    = (_Float16*)(W + O_FR);
  _Float16* FI2   = (_Float16*)(W + O_FI2);
  _Float16* T1    = (_Float16*)(W + O_T1);
  _Float16* G     = (_Float16*)(W + O_G);
  _Float16* WB    = (_Float16*)(W + O_WB);
  _Float16* wqn   = (_Float16*)(W + O_WQN);
  _Float16* wint  = (_Float16*)(W + O_WINT);
  _Float16* woutt = (_Float16*)(W + O_WOUT);
  float*    ral32 = (float*)(W + O_RAL32);
  int*      cntE  = (int*)(W + O_CNTE);
  int*      cntQ  = (int*)(W + O_CNTQ);
  float*    bns   = (float*)(W + O_BNS);
  float*    dinv  = (float*)(W + O_DINV);
  int*      ptr   = (int*)(W + O_PTR);
  int*      cur   = (int*)(W + O_CUR);
  int*      bsum  = (int*)(W + O_BSUM);
  int2*     recs  = (int2*)(W + O_RECS);
  _Float16* circ16= (_Float16*)(W + O_RECS);           // temp, dead before fillrec
  _Float16* wloopT= (_Float16*)(W + O_RECS + 131072);

  hipMemsetAsync(cntE, 0, 800000, stream);   // cntE + cntQ (adjacent)
  hipMemsetAsync(bns, 0, 4096, stream);

  k_pro<<<10431, 256, 0, stream>>>(FR, FI2, w_in, w_out_, w_q, rel_emb, loop_rel, w_loop,
                                   wqn, wint, woutt, ral32, circ16, wloopT,
                                   x, XC, ei, quals, cntE, cntQ);
  // T1=FR@wqn^T ; WB[256:544]=FiWin ; WB[544:832]=FiWout ; WB[0:256]=BW
  k_setup<<<22, 256, 0, stream>>>(FR, wqn, T1, wint, woutt, FI2, WB, wloopT, circ16);
  // G = T1 @ FI2^T
  k_gemm<_Float16,false><<<dim3(3,3), 256, 0, stream>>>(T1, 256, FI2, 256, G, 288, 288, 256);
  k_dinv_scan1<<<391 + SCB, 256, 0, stream>>>(cntE, cntQ, dinv, bsum);
  k_scan3<<<SCB, 256, 0, stream>>>(cntE, cntQ, bsum, ptr, cur);
  k_fillrec<<<3125, 256, 0, stream>>>(ei, et, quals, dinv, cur, recs);

  // [Xhat ; Rhat] = XCAT[:,0:256] @ FR^T  (rows 0..50559)
  k_gemm<_Float16,false><<<dim3(395,3), 256, 0, stream>>>(XC, 832, FR, 256, Xhat, 288, 288, 256);

  for (int d = 0; d < 2; ++d){
    k_qgemm<<<1600, 256, 0, stream>>>(Xhat, quals, d, G, Yhat);
    k_agg<<<NN, 128, 0, stream>>>(W, ptr, recs, d, XC);
  }

  // opre = XCAT @ WB^T   (K=832: self-loop + both directions in one GEMM)
  k_gemm<_Float16,false><<<dim3(391,2), 256, 0, stream>>>(XC, 832, WB, 832, opre, 256, 256, 832);

  k_bnstats<<<782, 256, 0, stream>>>(opre, bns);
  k_bnfinal<<<1, 256, 0, stream>>>(bns, gamma, beta);
  k_epi<<<6750, 256, 0, stream>>>(opre, bns, ral32, w_rel, out);
}

// Round 16
// 460.241 us; speedup vs baseline: 1.5393x; 1.0141x over previous
//
#include <hip/hip_runtime.h>

typedef __attribute__((ext_vector_type(8))) _Float16 f16x8;
typedef __attribute__((ext_vector_type(4))) float f32x4;

#define NN   50000
#define EE   300000
#define TWOE 600000
#define TWOQ 200000
#define SCB  98     // scan blocks of 1024 ints covering 2*NN=100000

// ---- workspace layout (bytes), total 181,457,600 (<= proven 184,089,664) ----
static constexpr size_t O_XCAT = 0;            // f16 [50560][832]: cols 0:256 x / ral16 rows 50048+, 256:544 AGG0, 544:832 AGG1
static constexpr size_t O_XHAT = 84131840;     // f16 [50560][288]: rows 0..50047 Xhat, 50048..50559 Rhat
static constexpr size_t O_YH   = 113254400;    // f16 [100096][288] Yhat (per-dir); later opre f16 [50048][256] aliases
static constexpr size_t O_FR   = 170909696;    // f16 [384,256]
static constexpr size_t O_FI2  = 171106304;    // f16 [384,256]
static constexpr size_t O_T1   = 171302912;    // f16 [384,256]
static constexpr size_t O_G    = 171499520;    // f16 [384,288]
static constexpr size_t O_WB   = 171720704;    // f16 [256,832]: [0:256]=BW, [256:544]=FiWin, [544:832]=FiWout
static constexpr size_t O_WQN  = 172146688;    // f16 [256,256]
static constexpr size_t O_WINT = 172277760;    // f16 [256,256]
static constexpr size_t O_WOUT = 172408832;    // f16 [256,256]
static constexpr size_t O_RAL32= 172539904;    // f32 [501,256]
static constexpr size_t O_CNTE = 173052928;    // int [2N]  (edge counts; also degree source, swapped)
static constexpr size_t O_CNTQ = 173452928;    // int [2N]  (qual counts; adjacent: one memset)
static constexpr size_t O_BNS  = 173852928;    // f32 [1024]
static constexpr size_t O_DINV = 173857024;    // f32 [2,N]
static constexpr size_t O_PTR  = 174257024;    // int [2N+1]
static constexpr size_t O_CUR  = 174657088;    // int [2N]
static constexpr size_t O_BSUM = 175057088;    // int [128]
static constexpr size_t O_RECS = 175057600;    // int2 [800000] = 6.4MB; temp circ16/wloopT alias
static constexpr size_t WS_NEED= 181457600;

__device__ __forceinline__ float sanit(float v){
  v = (v == v) ? v : 0.f;
  return fminf(60000.f, fmaxf(-60000.f, v));
}
__device__ __forceinline__ _Float16 sat16(float v){ return (_Float16)sanit(v); }
__device__ __forceinline__ int iclamp(int v, int lo, int hi){
  return v < lo ? lo : (v > hi ? hi : v);
}
__device__ __forceinline__ void atomAddF(float* p, float v){
  __hip_atomic_fetch_add(p, v, __ATOMIC_RELAXED, __HIP_MEMORY_SCOPE_AGENT);
}
union HU { unsigned int u; _Float16 h[2]; };

// fast branchless tanh: (e^2x - 1)/(e^2x + 1), clamped; err <= ~1e-4
__device__ __forceinline__ float ftanh(float x){
  float e2 = __expf(fminf(fmaxf(2.f*x, -20.f), 20.f));
  return (e2 - 1.f) * __builtin_amdgcn_rcpf(e2 + 1.f);
}

// native-f16 complex multiply (conj(a)*b)
__device__ __forceinline__ unsigned int cmulh(unsigned int ua, unsigned int ub){
  HU a, b, o; a.u = ua; b.u = ub;
  o.h[0] = a.h[0]*b.h[0] + a.h[1]*b.h[1];
  o.h[1] = a.h[0]*b.h[1] - a.h[1]*b.h[0];
  return o.u;
}

// ---- fused prologue ----
// [0,288) gen_dft | [288,800) misc+ral | [800,7050) cvt_x->XCAT
// [7050,10175) cntE/cntQ | [10175,10431) circ16/wloopT
__global__ void k_pro(_Float16* __restrict__ FR, _Float16* __restrict__ FI2,
                      const float* __restrict__ w_in, const float* __restrict__ w_out,
                      const float* __restrict__ w_q, const float* __restrict__ rel_embed,
                      const float* __restrict__ loop_rel, const float* __restrict__ w_loop,
                      _Float16* __restrict__ wqn, _Float16* __restrict__ wint,
                      _Float16* __restrict__ woutt,
                      float* __restrict__ ral32,
                      _Float16* __restrict__ circ16, _Float16* __restrict__ wloopT,
                      const float* __restrict__ x, _Float16* __restrict__ XC,
                      const int* __restrict__ ei, const int* __restrict__ quals,
                      int* __restrict__ cntE, int* __restrict__ cntQ){
  int b = blockIdx.x, tid = threadIdx.x;
  if (b < 288){
    int t = b*256 + tid;
    const float step = 0.024543692606170259f; // 2*pi/256
    {
      int f = t >> 8, tt = t & 255;
      float v = 0.f;
      if (f < 258){
        int m = f >> 1;
        float ang = (float)((tt*m) & 255) * step;
        v = (f & 1) ? -sinf(ang) : cosf(ang);
      }
      FR[t] = (_Float16)v;
    }
    {
      int k = t >> 8, j = t & 255;
      float v = 0.f;
      if (k < 258){
        int m = k >> 1;
        float w = (m==0 || m==128) ? (1.f/256.f) : (2.f/256.f);
        float ang = (float)((j*m) & 255) * step;
        v = (k & 1) ? -w*sinf(ang) : w*cosf(ang);
      }
      FI2[t] = (_Float16)v;
    }
  } else if (b < 800){
    int t = (b - 288)*256 + tid;   // < 131072
    if (t < 65536){
      int j = t >> 8, n = t & 255;
      wqn[t] = sat16(w_q[t]);
      wint[n*256 + j]  = sat16(w_in[t]);
      woutt[n*256 + j] = sat16(w_out[t]);
    }
    float rv = 0.f;
    if (t < 128000) rv = sanit(rel_embed[t]);
    else if (t < 128256) rv = sanit(loop_rel[t - 128000]);
    int row = t >> 8, c = t & 255;
    XC[(size_t)(50048 + row)*832 + c] = (_Float16)rv;   // ral16 rows (pad rows zero)
    if (t < 128256) ral32[t] = rv;
  } else if (b < 7050){
    int t = (b - 800)*256 + tid;   // < 1,600,000 exactly (50000 rows x 32 chunks)
    const float4* p = (const float4*)x + (size_t)t*2;
    float4 v0 = p[0], v1 = p[1];
    f16x8 o;
    o[0]=sat16(v0.x); o[1]=sat16(v0.y); o[2]=sat16(v0.z); o[3]=sat16(v0.w);
    o[4]=sat16(v1.x); o[5]=sat16(v1.y); o[6]=sat16(v1.z); o[7]=sat16(v1.w);
    int row = t >> 5, c8 = (t & 31)*8;
    *(f16x8*)(XC + (size_t)row*832 + c8) = o;
  } else if (b < 10175){
    int t = (b - 7050)*256 + tid;  // < 800,000 exactly
    if (t < TWOE){
      int d = (t >= EE) ? 1 : 0;
      atomicAdd(&cntE[d*NN + iclamp(ei[TWOE + t], 0, NN-1)], 1);
    } else {
      int qg = t - TWOE;
      int d = (qg >= 100000) ? 1 : 0;
      int e = iclamp(quals[2*TWOQ + qg], 0, EE-1);
      int j = d*EE + e;
      atomicAdd(&cntQ[d*NN + iclamp(ei[TWOE + j], 0, NN-1)], 1);
    }
  } else {
    int t = (b - 10175)*256 + tid; // < 65536 exactly
    int r = t >> 8, m = t & 255;
    circ16[t] = sat16(loop_rel[(r + m) & 255]);      // Circ16[j][m]
    wloopT[t] = sat16(w_loop[m*256 + r]);            // wloopT[n][m]
  }
}

// fused: blocks [0,391) dinv (degrees = swapped cntE) ; [391,489) scan1 (cntE+cntQ)
__global__ void k_dinv_scan1(const int* __restrict__ cntE, const int* __restrict__ cntQ,
                             float* __restrict__ dinv, int* __restrict__ bsum){
  int b = blockIdx.x, t = threadIdx.x;
  if (b < 391){
    int i = b*256 + t;
    if (i < 2*NN){
      // deg[0][n] = #{src=n} = cntE[1][n] ; deg[1][n] = #{dst=n} = cntE[0][n]
      int part = (i < NN) ? i + NN : i - NN;
      int c = cntE[part];
      dinv[i] = (c > 0) ? rsqrtf((float)c) : 0.f;
    }
  } else {
    __shared__ int sh[256];
    int blk = b - 391;
    int base = blk*1024 + t*4;
    int s = 0;
    #pragma unroll
    for (int i = 0; i < 4; ++i){
      int idx = base + i;
      if (idx < 2*NN) s += cntE[idx] + cntQ[idx];
    }
    sh[t] = s; __syncthreads();
    for (int off = 128; off > 0; off >>= 1){
      if (t < off) sh[t] += sh[t + off];
      __syncthreads();
    }
    if (t == 0) bsum[blk] = sh[0];
  }
}

// self-contained: prefix raw bsum in-block, then scatter ptr/cur
__global__ void k_scan3(const int* __restrict__ cntE, const int* __restrict__ cntQ,
                        const int* __restrict__ bsum,
                        int* __restrict__ ptr, int* __restrict__ cur){
  __shared__ int sh[256];
  __shared__ int bs[128];
  int b = blockIdx.x, t = threadIdx.x;
  int base = b*1024 + t*4;
  int v[4];
  int s = 0;
  #pragma unroll
  for (int i = 0; i < 4; ++i){
    int idx = base + i;
    v[i] = (idx < 2*NN) ? (cntE[idx] + cntQ[idx]) : 0;
    s += v[i];
  }
  sh[t] = s;
  if (t < 128) bs[t] = (t < SCB) ? bsum[t] : 0;
  __syncthreads();
  // inclusive Hillis-Steele over thread sums
  for (int off = 1; off < 256; off <<= 1){
    int add = (t >= off) ? sh[t - off] : 0;
    __syncthreads();
    sh[t] += add;
    __syncthreads();
  }
  // inclusive prefix over block sums (128-wide)
  for (int off = 1; off < 128; off <<= 1){
    int add = (t >= off && t < 128) ? bs[t - off] : 0;
    __syncthreads();
    if (t < 128) bs[t] += add;
    __syncthreads();
  }
  int blockoff = (b > 0) ? bs[b - 1] : 0;
  if (b == 0 && t == 0) ptr[2*NN] = bs[SCB - 1];
  int off0 = blockoff + sh[t] - s;
  #pragma unroll
  for (int i = 0; i < 4; ++i){
    int idx = base + i;
    if (idx < 2*NN){ ptr[idx] = off0; cur[idx] = off0; }
    off0 += v[i];
  }
}

// packed per-item records int2: x.lo16=xrow, x.hi16=brow.lo16;
// y: bit0=brow.bit16, bit1=isqual, bits31:16=coef f16
__global__ void k_fillrec(const int* __restrict__ ei, const int* __restrict__ et,
                          const int* __restrict__ quals, const float* __restrict__ dinv,
                          int* __restrict__ cursor, int2* __restrict__ recs){
  int t = blockIdx.x*256 + threadIdx.x;
  if (t >= TWOE + TWOQ) return;
  int d, j, brow, isq; float w;
  if (t < TWOE){
    d = (t >= EE) ? 1 : 0;
    j = t;
    brow = 50048 + iclamp(et[j], 0, 500);   // Rhat row within XHAT region
    isq = 0; w = 0.8f;
  } else {
    int qg = t - TWOE;
    d = (qg >= 100000) ? 1 : 0;
    int e = iclamp(quals[2*TWOQ + qg], 0, EE-1);
    j = d*EE + e;
    brow = qg - d*100000;                   // Yhat row (per-direction)
    isq = 1; w = 0.2f;
  }
  int src = iclamp(ei[j], 0, NN-1);
  int dst = iclamp(ei[TWOE + j], 0, NN-1);
  float coef = w * dinv[d*NN + src] * dinv[d*NN + dst];
  int pos = atomicAdd(&cursor[d*NN + dst], 1);
  pos = iclamp(pos, 0, 800000-1);
  HU cu; cu.h[0] = (_Float16)coef; cu.h[1] = (_Float16)0.f;
  int2 rc;
  rc.x = src | ((brow & 0xffff) << 16);
  rc.y = ((brow >> 16) & 1) | (isq << 1) | ((int)(cu.u & 0xffffu) << 16);
  recs[pos] = rc;
}

// ---- shared GEMM body with register-prefetch pipeline ----
// C[.,N](ldc) = A[.,K](lda) @ Bt[.,K](ldb)^T; UNGUARDED loads (padded rows, K%32==0).
template<typename OT, bool ACC>
__device__ __forceinline__ void gemm_body(const _Float16* __restrict__ A, int lda,
                                          const _Float16* __restrict__ Bt, int ldb,
                                          OT* __restrict__ C, int ldc,
                                          int N, int K, int bx, int by){
  __shared__ __align__(16) _Float16 Ash[128*40];
  __shared__ __align__(16) _Float16 Bsh[128*40];
  const int tid = threadIdx.x;
  const int lane = tid & 63;
  const int wv = tid >> 6;
  const int bm = bx*128, bn = by*128;
  const int wm = (wv >> 1)*64, wn = (wv & 1)*64;
  const int sr = tid >> 1;
  const int sc = (tid & 1)*16;
  const int fr = lane & 15;
  const int fk = (lane >> 4)*8;
  const _Float16* pa = A + (size_t)(bm+sr)*lda + sc;
  const _Float16* pb = Bt + (size_t)(bn+sr)*ldb + sc;
  // preload kt=0
  float4 na0 = *(const float4*)(pa);
  float4 na1 = *(const float4*)(pa + 8);
  float4 nb0 = *(const float4*)(pb);
  float4 nb1 = *(const float4*)(pb + 8);
  f32x4 acc[4][4] = {};
  for (int kt = 0; kt < K; kt += 32){
    float4 a0 = na0, a1 = na1, b0 = nb0, b1 = nb1;
    __syncthreads();
    *(float4*)&Ash[sr*40 + sc]     = a0;
    *(float4*)&Ash[sr*40 + sc + 8] = a1;
    *(float4*)&Bsh[sr*40 + sc]     = b0;
    *(float4*)&Bsh[sr*40 + sc + 8] = b1;
    __syncthreads();
    // prefetch next k-step (clamped); latency hides under the MFMA cluster
    int kt2 = kt + 32; if (kt2 >= K) kt2 = kt;
    const _Float16* pa2 = pa + (kt2 - kt);
    const _Float16* pb2 = pb + (kt2 - kt);
    pa = pa2; pb = pb2;
    na0 = *(const float4*)(pa2);
    na1 = *(const float4*)(pa2 + 8);
    nb0 = *(const float4*)(pb2);
    nb1 = *(const float4*)(pb2 + 8);
    f16x8 af[4], bf_[4];
    #pragma unroll
    for (int i = 0; i < 4; ++i) af[i]  = *(const f16x8*)&Ash[(wm + i*16 + fr)*40 + fk];
    #pragma unroll
    for (int j = 0; j < 4; ++j) bf_[j] = *(const f16x8*)&Bsh[(wn + j*16 + fr)*40 + fk];
    #pragma unroll
    for (int i = 0; i < 4; ++i)
      #pragma unroll
      for (int j = 0; j < 4; ++j)
        acc[i][j] = __builtin_amdgcn_mfma_f32_16x16x32_f16(af[i], bf_[j], acc[i][j], 0, 0, 0);
  }
  const int cr = (lane >> 4)*4;
  const int cc = lane & 15;
  #pragma unroll
  for (int i = 0; i < 4; ++i)
    #pragma unroll
    for (int j = 0; j < 4; ++j){
      int col = bn + wn + j*16 + cc;
      if (col < N){
        #pragma unroll
        for (int r = 0; r < 4; ++r){
          size_t idx = (size_t)(bm + wm + i*16 + cr + r)*ldc + col;
          float v = acc[i][j][r];
          if (ACC) v += (float)C[idx];
          C[idx] = (OT)sanit(v);
        }
      }
    }
}

template<typename OT, bool ACC>
__global__ __launch_bounds__(256) void k_gemm(const _Float16* __restrict__ A, int lda,
                                              const _Float16* __restrict__ Bt, int ldb,
                                              OT* __restrict__ C, int ldc,
                                              int N, int K){
  gemm_body<OT,ACC>(A, lda, Bt, ldb, C, ldc, N, K, blockIdx.x, blockIdx.y);
}

// batch of 4 independent small setup GEMMs (22 blocks total)
__global__ __launch_bounds__(256) void k_setup(const _Float16* __restrict__ FR,
                                               const _Float16* __restrict__ wqn,
                                               _Float16* __restrict__ T1,
                                               const _Float16* __restrict__ wint,
                                               const _Float16* __restrict__ woutt,
                                               const _Float16* __restrict__ FI2,
                                               _Float16* __restrict__ WB,
                                               const _Float16* __restrict__ wloopT,
                                               const _Float16* __restrict__ circ16){
  int b = blockIdx.x;
  if (b < 6)       gemm_body<_Float16,false>(FR, 256, wqn, 256, T1, 256, 256, 256, b % 3, b / 3);
  else if (b < 12){ int i = b - 6;  gemm_body<_Float16,false>(wint, 256, FI2, 256, WB + 256, 832, 288, 256, i % 2, i / 2); }
  else if (b < 18){ int i = b - 12; gemm_body<_Float16,false>(woutt, 256, FI2, 256, WB + 544, 832, 288, 256, i % 2, i / 2); }
  else            { int i = b - 18; gemm_body<_Float16,false>(wloopT, 256, circ16, 256, WB, 832, 256, 256, i % 2, i / 2); }
}

// Fused qual GEMM, XCD-pair swizzled (grid 1600, 1-D), cols 0..255 via MFMA,
// col 256 (real Nyquist) via in-loop side accumulation in bn==0 tiles.
// Yhat[q] = (conj(Xhat[ent_q]) .* Rhat[rel_q]) @ G^T
__global__ __launch_bounds__(256) void k_qgemm(const _Float16* __restrict__ Xhat,
                                               const int* __restrict__ quals, int d,
                                               const _Float16* __restrict__ G,
                                               _Float16* __restrict__ Yhat){
  int L = blockIdx.x;
  int xcd = L & 7, w = L >> 3;
  int pr = (w >> 1)*8 + xcd;         // pair id: the 2 col-tiles share an XCD
  if (pr >= 782) return;
  int bn = (w & 1)*128;
  int bm = pr*128;
  __shared__ __align__(16) _Float16 Ash[128*40];
  __shared__ __align__(16) _Float16 Bsh[128*40];
  __shared__ __align__(16) _Float16 g256[288];
  __shared__ float psum[128][2];
  const int tid = threadIdx.x;
  const int lane = tid & 63;
  const int wv = tid >> 6;
  const int wm = (wv >> 1)*64, wn = (wv & 1)*64;
  const int sr = tid >> 1;
  const int h  = tid & 1;
  const int fr = lane & 15;
  const int fk = (lane >> 4)*8;
  const bool do256 = (bn == 0);
  if (tid < 144) ((unsigned*)g256)[tid] = ((const unsigned*)(G + (size_t)256*288))[tid];
  int q = bm + sr; if (q > 99999) q = 99999;
  int qi = d*100000 + q;
  int rel = iclamp(quals[qi], 0, 500);
  int ent = iclamp(quals[TWOQ + qi], 0, NN-1);
  const unsigned int* xr = (const unsigned int*)(Xhat + (size_t)ent*288);
  const unsigned int* rr = (const unsigned int*)(Xhat + (size_t)(50048 + rel)*288);
  const _Float16* gbase = G + (size_t)(bn+sr)*288 + h*16;
  int kb = h*8;
  uint4 nxa0 = *(const uint4*)(xr + kb);
  uint4 nxa1 = *(const uint4*)(xr + kb + 4);
  uint4 nra0 = *(const uint4*)(rr + kb);
  uint4 nra1 = *(const uint4*)(rr + kb + 4);
  float4 nb0 = *(const float4*)(gbase);
  float4 nb1 = *(const float4*)(gbase + 8);
  f32x4 acc[4][4] = {};
  float p256 = 0.f;
  for (int kt = 0; kt < 288; kt += 32){
    uint4 oa0, oa1;
    oa0.x = cmulh(nxa0.x, nra0.x); oa0.y = cmulh(nxa0.y, nra0.y);
    oa0.z = cmulh(nxa0.z, nra0.z); oa0.w = cmulh(nxa0.w, nra0.w);
    oa1.x = cmulh(nxa1.x, nra1.x); oa1.y = cmulh(nxa1.y, nra1.y);
    oa1.z = cmulh(nxa1.z, nra1.z); oa1.w = cmulh(nxa1.w, nra1.w);
    if (do256){
      const _Float16* gp = g256 + kt + h*16;
      HU u0, u1, u2, u3;
      u0.u = oa0.x; u1.u = oa0.y; u2.u = oa0.z; u3.u = oa0.w;
      p256 += (float)u0.h[0]*(float)gp[0]  + (float)u0.h[1]*(float)gp[1]
            + (float)u1.h[0]*(float)gp[2]  + (float)u1.h[1]*(float)gp[3]
            + (float)u2.h[0]*(float)gp[4]  + (float)u2.h[1]*(float)gp[5]
            + (float)u3.h[0]*(float)gp[6]  + (float)u3.h[1]*(float)gp[7];
      u0.u = oa1.x; u1.u = oa1.y; u2.u = oa1.z; u3.u = oa1.w;
      p256 += (float)u0.h[0]*(float)gp[8]  + (float)u0.h[1]*(float)gp[9]
            + (float)u1.h[0]*(float)gp[10] + (float)u1.h[1]*(float)gp[11]
            + (float)u2.h[0]*(float)gp[12] + (float)u2.h[1]*(float)gp[13]
            + (float)u3.h[0]*(float)gp[14] + (float)u3.h[1]*(float)gp[15];
    }
    float4 b0 = nb0, b1 = nb1;
    __syncthreads();
    *(uint4*)&Ash[sr*40 + h*16]      = oa0;
    *(uint4*)&Ash[sr*40 + h*16 + 8]  = oa1;
    *(float4*)&Bsh[sr*40 + h*16]     = b0;
    *(float4*)&Bsh[sr*40 + h*16 + 8] = b1;
    __syncthreads();
    int kt2 = kt + 32; if (kt2 > 256) kt2 = 256;
    int kb2 = (kt2 >> 1) + h*8;
    nxa0 = *(const uint4*)(xr + kb2);
    nxa1 = *(const uint4*)(xr + kb2 + 4);
    nra0 = *(const uint4*)(rr + kb2);
    nra1 = *(const uint4*)(rr + kb2 + 4);
    const _Float16* gb2 = gbase + kt2;
    nb0 = *(const float4*)(gb2);
    nb1 = *(const float4*)(gb2 + 8);
    f16x8 af[4], bf_[4];
    #pragma unroll
    for (int i = 0; i < 4; ++i) af[i]  = *(const f16x8*)&Ash[(wm + i*16 + fr)*40 + fk];
    #pragma unroll
    for (int j = 0; j < 4; ++j) bf_[j] = *(const f16x8*)&Bsh[(wn + j*16 + fr)*40 + fk];
    #pragma unroll
    for (int i = 0; i < 4; ++i)
      #pragma unroll
      for (int j = 0; j < 4; ++j)
        acc[i][j] = __builtin_amdgcn_mfma_f32_16x16x32_f16(af[i], bf_[j], acc[i][j], 0, 0, 0);
  }
  if (do256){
    psum[sr][h] = p256;
  }
  const int cr = (lane >> 4)*4;
  const int cc = lane & 15;
  #pragma unroll
  for (int i = 0; i < 4; ++i)
    #pragma unroll
    for (int j = 0; j < 4; ++j){
      int col = bn + wn + j*16 + cc;
      #pragma unroll
      for (int r = 0; r < 4; ++r){
        size_t idx = (size_t)(bm + wm + i*16 + cr + r)*288 + col;
        Yhat[idx] = sat16(acc[i][j][r]);
      }
    }
  __syncthreads();
  if (do256 && h == 0){
    Yhat[(size_t)(bm + sr)*288 + 256] = sat16(psum[sr][0] + psum[sr][1]);
  }
}

// ---- gather-aggregate via packed records, depth-2 pipeline; writes XCAT cols ----
__global__ __launch_bounds__(128) void k_agg(const char* __restrict__ Wb,
                                             const int* __restrict__ ptr,
                                             const int2* __restrict__ recs,
                                             int d, _Float16* __restrict__ XC){
  int node = blockIdx.x;
  int t = threadIdx.x;
  int gnode = d*NN + node;
  int beg = ptr[gnode], end = ptr[gnode+1];
  unsigned int* orow = (unsigned int*)(XC + (size_t)node*832 + 256 + d*288);
  if (end <= beg){
    orow[t] = 0;
    if (t < 16) orow[128 + t] = 0;
    return;
  }
  int last = end - 1;
  auto ld = [&](int idx, unsigned& va, unsigned& vb, float& ah, float& bh, float& cf){
    int ic = idx < last ? idx : last;
    int2 rc = recs[ic];
    int xrow = rc.x & 0xffff;
    int brow = ((rc.x >> 16) & 0xffff) | ((rc.y & 1) << 16);
    const char* xb = Wb + O_XHAT + (size_t)xrow*576;
    const char* bb = Wb + ((rc.y & 2) ? O_YH : O_XHAT) + (size_t)brow*576;
    va = ((const unsigned*)xb)[t]; vb = ((const unsigned*)bb)[t];
    ah = (float)((const _Float16*)xb)[256];
    bh = (float)((const _Float16*)bb)[256];
    HU cu; cu.u = ((unsigned)rc.y) >> 16;
    cf = (idx <= last) ? (float)cu.h[0] : 0.f;
  };
  float ax_ = 0.f, ay_ = 0.f, ex = 0.f;
  unsigned va0, vb0, va1, vb1; float ah0, bh0, ah1, bh1, cf0, cf1;
  ld(beg,     va0, vb0, ah0, bh0, cf0);
  ld(beg + 1, va1, vb1, ah1, bh1, cf1);
  for (int k = beg; k < end; k += 2){
    unsigned ta0, tb0, ta1, tb1; float th0, tg0, th1, tg1, tc0, tc1;
    ld(k + 2, ta0, tb0, th0, tg0, tc0);
    ld(k + 3, ta1, tb1, th1, tg1, tc1);
    {
      HU a, b; a.u = va0; b.u = vb0;
      float axv=(float)a.h[0], ayv=(float)a.h[1], bxv=(float)b.h[0], byv=(float)b.h[1];
      ax_ += cf0*(axv*bxv + ayv*byv);
      ay_ += cf0*(axv*byv - ayv*bxv);
      ex  += cf0*ah0*bh0;
    }
    {
      HU a, b; a.u = va1; b.u = vb1;
      float axv=(float)a.h[0], ayv=(float)a.h[1], bxv=(float)b.h[0], byv=(float)b.h[1];
      ax_ += cf1*(axv*bxv + ayv*byv);
      ay_ += cf1*(axv*byv - ayv*bxv);
      ex  += cf1*ah1*bh1;
    }
    va0=ta0; vb0=tb0; ah0=th0; bh0=tg0; cf0=tc0;
    va1=ta1; vb1=tb1; ah1=th1; bh1=tg1; cf1=tc1;
  }
  HU o; o.h[0] = sat16(ax_); o.h[1] = sat16(ay_);
  orow[t] = o.u;
  if (t < 16){
    HU o2; o2.h[0] = (t == 0) ? sat16(ex) : (_Float16)0.f; o2.h[1] = (_Float16)0.f;
    orow[128 + t] = o2.u;
  }
}

__global__ void k_bnstats(const _Float16* __restrict__ opre, float* __restrict__ bns){
  int col = threadIdx.x;
  int r0 = blockIdx.x*64, r1 = r0 + 64; if (r1 > NN) r1 = NN;
  float s1 = 0.f, s2 = 0.f;
  for (int r = r0; r < r1; ++r){
    float v = (float)opre[(size_t)r*256 + col];
    s1 += v; s2 += v*v;
  }
  atomAddF(&bns[col], s1);
  atomAddF(&bns[256 + col], s2);
}

__global__ void k_bnfinal(float* __restrict__ bns, const float* __restrict__ gamma,
                          const float* __restrict__ beta){
  int col = threadIdx.x;
  float mean = bns[col] * (1.f/NN);
  float var  = bns[256 + col] * (1.f/NN) - mean*mean;
  var = fmaxf(var, 0.f);
  // BN of (acc/3 + bias) == (acc-mean_acc)/sqrt(var_acc + 9*eps); bias cancels
  float g = gamma[col] * rsqrtf(var + 9e-5f);
  float b = beta[col] - mean*g;
  bns[512 + col] = sanit(g);
  bns[768 + col] = sanit(b);
}

// fused epilogue: blocks [0,500) rel_out (early, overlaps) ; [500,6750) ent-BN-tanh
__global__ void k_epi(const _Float16* __restrict__ opre, const float* __restrict__ bns,
                      const float* __restrict__ ral32, const float* __restrict__ w_rel,
                      float* __restrict__ out){
  int b = blockIdx.x;
  if (b < 500){
    int r = b, n = threadIdx.x;
    const float* rr = ral32 + r*256;
    const float* wr = w_rel + n;
    float a0 = 0.f, a1 = 0.f, a2 = 0.f, a3 = 0.f;
    for (int k = 0; k < 256; k += 4){
      a0 += rr[k]     * wr[(size_t)k*256];
      a1 += rr[k + 1] * wr[(size_t)(k + 1)*256];
      a2 += rr[k + 2] * wr[(size_t)(k + 2)*256];
      a3 += rr[k + 3] * wr[(size_t)(k + 3)*256];
    }
    out[12800000 + r*256 + n] = sanit((a0 + a1) + (a2 + a3));
  } else {
    int t = (b - 500)*256 + threadIdx.x;   // < NN*32 exactly
    f16x8 v = ((const f16x8*)opre)[t];
    int col = (t & 31)*8;
    float4 o0, o1;
    o0.x = sanit(ftanh((float)v[0]*bns[512+col+0] + bns[768+col+0]));
    o0.y = sanit(ftanh((float)v[1]*bns[512+col+1] + bns[768+col+1]));
    o0.z = sanit(ftanh((float)v[2]*bns[512+col+2] + bns[768+col+2]));
    o0.w = sanit(ftanh((float)v[3]*bns[512+col+3] + bns[768+col+3]));
    o1.x = sanit(ftanh((float)v[4]*bns[512+col+4] + bns[768+col+4]));
    o1.y = sanit(ftanh((float)v[5]*bns[512+col+5] + bns[768+col+5]));
    o1.z = sanit(ftanh((float)v[6]*bns[512+col+6] + bns[768+col+6]));
    o1.w = sanit(ftanh((float)v[7]*bns[512+col+7] + bns[768+col+7]));
    ((float4*)out)[(size_t)t*2]     = o0;
    ((float4*)out)[(size_t)t*2 + 1] = o1;
  }
}

extern "C" void kernel_launch(void* const* d_in, const int* in_sizes, int n_in,
                              void* d_out, int out_size, void* d_ws, size_t ws_size,
                              hipStream_t stream){
  (void)in_sizes; (void)n_in;
  if (ws_size < WS_NEED){
    hipMemsetAsync(d_out, 0, (size_t)out_size*4, stream);
    return;
  }
  const float* x        = (const float*)d_in[0];
  const float* rel_emb  = (const float*)d_in[1];
  const float* w_in     = (const float*)d_in[2];
  const float* w_out_   = (const float*)d_in[3];
  const float* w_loop   = (const float*)d_in[4];
  const float* w_rel    = (const float*)d_in[5];
  const float* w_q      = (const float*)d_in[6];
  const float* loop_rel = (const float*)d_in[7];
  const float* gamma    = (const float*)d_in[9];
  const float* beta     = (const float*)d_in[10];
  const int* ei    = (const int*)d_in[11];
  const int* et    = (const int*)d_in[12];
  const int* quals = (const int*)d_in[13];
  float* out = (float*)d_out;
  char* W = (char*)d_ws;
  _Float16* XC    = (_Float16*)(W + O_XCAT);
  _Float16* Xhat  = (_Float16*)(W + O_XHAT);
  _Float16* Yhat  = (_Float16*)(W + O_YH);
  _Float16* opre  = (_Float16*)(W + O_YH);     // aliases Yhat (dead by then)
  _Float16* FR    = (_Float16*)(W + O_FR);
  _Float16* FI2   = (_Float16*)(W + O_FI2);
  _Float16* T1    = (_Float16*)(W + O_T1);
  _Float16* G     = (_Float16*)(W + O_G);
  _Float16* WB    = (_Float16*)(W + O_WB);
  _Float16* wqn   = (_Float16*)(W + O_WQN);
  _Float16* wint  = (_Float16*)(W + O_WINT);
  _Float16* woutt = (_Float16*)(W + O_WOUT);
  float*    ral32 = (float*)(W + O_RAL32);
  int*      cntE  = (int*)(W + O_CNTE);
  int*      cntQ  = (int*)(W + O_CNTQ);
  float*    bns   = (float*)(W + O_BNS);
  float*    dinv  = (float*)(W + O_DINV);
  int*      ptr   = (int*)(W + O_PTR);
  int*      cur   = (int*)(W + O_CUR);
  int*      bsum  = (int*)(W + O_BSUM);
  int2*     recs  = (int2*)(W + O_RECS);
  _Float16* circ16= (_Float16*)(W + O_RECS);           // temp, dead before fillrec
  _Float16* wloopT= (_Float16*)(W + O_RECS + 131072);

  hipMemsetAsync(cntE, 0, 800000, stream);   // cntE + cntQ (adjacent)
  hipMemsetAsync(bns, 0, 4096, stream);

  k_pro<<<10431, 256, 0, stream>>>(FR, FI2, w_in, w_out_, w_q, rel_emb, loop_rel, w_loop,
                                   wqn, wint, woutt, ral32, circ16, wloopT,
                                   x, XC, ei, quals, cntE, cntQ);
  // T1=FR@wqn^T ; WB[256:544]=FiWin ; WB[544:832]=FiWout ; WB[0:256]=BW
  k_setup<<<22, 256, 0, stream>>>(FR, wqn, T1, wint, woutt, FI2, WB, wloopT, circ16);
  // G = T1 @ FI2^T
  k_gemm<_Float16,false><<<dim3(3,3), 256, 0, stream>>>(T1, 256, FI2, 256, G, 288, 288, 256);
  k_dinv_scan1<<<391 + SCB, 256, 0, stream>>>(cntE, cntQ, dinv, bsum);
  k_scan3<<<SCB, 256, 0, stream>>>(cntE, cntQ, bsum, ptr, cur);
  k_fillrec<<<3125, 256, 0, stream>>>(ei, et, quals, dinv, cur, recs);

  // [Xhat ; Rhat] = XCAT[:,0:256] @ FR^T  (rows 0..50559)
  k_gemm<_Float16,false><<<dim3(395,3), 256, 0, stream>>>(XC, 832, FR, 256, Xhat, 288, 288, 256);

  for (int d = 0; d < 2; ++d){
    k_qgemm<<<1600, 256, 0, stream>>>(Xhat, quals, d, G, Yhat);
    k_agg<<<NN, 128, 0, stream>>>(W, ptr, recs, d, XC);
  }

  // opre = XCAT @ WB^T   (K=832: self-loop + both directions in one GEMM)
  k_gemm<_Float16,false><<<dim3(391,2), 256, 0, stream>>>(XC, 832, WB, 832, opre, 256, 256, 832);

  k_bnstats<<<782, 256, 0, stream>>>(opre, bns);
  k_bnfinal<<<1, 256, 0, stream>>>(bns, gamma, beta);
  k_epi<<<6750, 256, 0, stream>>>(opre, bns, ral32, w_rel, out);
}